// Round 3
// baseline (847.027 us; speedup 1.0000x reference)
//
#include <hip/hip_runtime.h>
#include <hip/hip_bf16.h>
#include <math.h>

#define NNODES 10000
#define NT     80000
#define NE     1280000

typedef __bf16 bf16x8 __attribute__((ext_vector_type(8)));
typedef float  f32x4  __attribute__((ext_vector_type(4)));

__device__ __forceinline__ float frcp(float x){ return __builtin_amdgcn_rcpf(x); }
__device__ __forceinline__ float fsig(float x){ return frcp(1.0f + __expf(-x)); }
__device__ __forceinline__ float ftanh(float x){ return 1.0f - 2.0f*frcp(1.0f + __expf(2.0f*x)); }
__device__ __forceinline__ float u2f(unsigned int u){ union{unsigned int u; float f;} c; c.u=u; return c.f; }

// ---------------- weight prep: pack LSTM weights into MFMA B-fragment order ---
__global__ __launch_bounds__(256) void prep_w_kernel(
    const float* __restrict__ wih1, const float* __restrict__ whh1,
    const float* __restrict__ bih1, const float* __restrict__ bhh1,
    const float* __restrict__ wih2, const float* __restrict__ whh2,
    const float* __restrict__ bih2, const float* __restrict__ bhh2,
    unsigned int* __restrict__ W1f, unsigned int* __restrict__ W2f,
    float* __restrict__ bs1, float* __restrict__ bs2)
{
    int gid = blockIdx.x*256 + threadIdx.x;
    if (gid < 24576) {
        int i = gid & 3, lane = (gid>>2)&63, rest = gid>>8;
        int ks = rest % 6; rest /= 6;
        int nt = rest & 3, w = rest >> 2;
        int gate = nt*64 + w*16 + (lane & 15);
        int k = ks*32 + ((lane>>4)&3)*8 + 2*i;
        float v0 = (k     < 128) ? wih1[gate*128 + k]       : whh1[gate*64 + (k-128)];
        float v1 = (k + 1 < 128) ? wih1[gate*128 + k + 1]   : whh1[gate*64 + (k+1-128)];
        __hip_bfloat16 h0 = __float2bfloat16(v0), h1 = __float2bfloat16(v1);
        W1f[gid] = (unsigned int)*(unsigned short*)&h0 | ((unsigned int)*(unsigned short*)&h1 << 16);
    } else if (gid < 24576 + 16384) {
        int r = gid - 24576;
        int i = r & 3, lane = (r>>2)&63, rest = r>>8;
        int ks = rest & 3; rest >>= 2;
        int nt = rest & 3, w = rest >> 2;
        int gate = nt*64 + w*16 + (lane & 15);
        int k = ks*32 + ((lane>>4)&3)*8 + 2*i;
        float v0 = (k     < 64) ? wih2[gate*64 + k]     : whh2[gate*64 + (k-64)];
        float v1 = (k + 1 < 64) ? wih2[gate*64 + k + 1] : whh2[gate*64 + (k+1-64)];
        __hip_bfloat16 h0 = __float2bfloat16(v0), h1 = __float2bfloat16(v1);
        W2f[r] = (unsigned int)*(unsigned short*)&h0 | ((unsigned int)*(unsigned short*)&h1 << 16);
    } else if (gid < 24576 + 16384 + 256) {
        int j = gid - (24576 + 16384); bs1[j] = bih1[j] + bhh1[j];
    } else if (gid < 24576 + 16384 + 512) {
        int j = gid - (24576 + 16384 + 256); bs2[j] = bih2[j] + bhh2[j];
    }
}

// fused: deg[d] += ew ; count[d] += 1
__global__ __launch_bounds__(256) void histdeg_kernel(const int* __restrict__ dst,
                                                      const float* __restrict__ ew,
                                                      float* __restrict__ deg,
                                                      int* __restrict__ count)
{
    int gid = blockIdx.x*blockDim.x + threadIdx.x;
    int stride = gridDim.x*blockDim.x;
    for (int e = gid; e < NE; e += stride) {
        int d = dst[e];
        atomicAdd(&deg[d], ew[e]);
        atomicAdd(&count[d], 1);
    }
}

__global__ __launch_bounds__(256) void dinv_kernel(float* __restrict__ deg)
{
    int gid = blockIdx.x*256 + threadIdx.x;
    if (gid < NT) deg[gid] = rsqrtf(deg[gid] + 1.0f);
}

// single-block exclusive scan of count[NT] -> rowptr[NT+1], cursor[NT]
__global__ __launch_bounds__(1024) void scan_kernel(const int* __restrict__ count,
                                                    int* __restrict__ rowptr,
                                                    int* __restrict__ cursor)
{
    __shared__ int part[1024];
    const int CH = 79;                 // 79*1024 = 80896 >= NT
    int tid = threadIdx.x;
    int base = tid*CH;
    int s = 0;
    for (int j = 0; j < CH; ++j) {
        int idx = base + j;
        if (idx < NT) s += count[idx];
    }
    part[tid] = s;
    __syncthreads();
    for (int off = 1; off < 1024; off <<= 1) {
        int v = (tid >= off) ? part[tid-off] : 0;
        __syncthreads();
        part[tid] += v;
        __syncthreads();
    }
    int run = part[tid] - s;           // exclusive prefix of this chunk
    for (int j = 0; j < CH; ++j) {
        int idx = base + j;
        if (idx < NT) {
            rowptr[idx] = run;
            cursor[idx] = run;
            run += count[idx];
        }
    }
    if (tid == 1023) rowptr[NT] = run; // == NE
}

// bucket edges by dst: epack[pos] = (src, norm) with norm = ew*dinv[s]*dinv[d]
__global__ __launch_bounds__(256) void reorder_kernel(const int* __restrict__ src,
                                                      const int* __restrict__ dst,
                                                      const float* __restrict__ ew,
                                                      const float* __restrict__ dinv,
                                                      int* __restrict__ cursor,
                                                      uint2* __restrict__ epack)
{
    int gid = blockIdx.x*blockDim.x + threadIdx.x;
    int stride = gridDim.x*blockDim.x;
    for (int e = gid; e < NE; e += stride) {
        int d = dst[e], s = src[e];
        float nrm = ew[e] * dinv[s] * dinv[d];
        int pos = atomicAdd(&cursor[d], 1);
        uint2 p; p.x = (unsigned int)s;
        union{float f; unsigned int u;} c; c.f = nrm; p.y = c.u;
        epack[pos] = p;
    }
}

// h[n][j] = sum_k X[n][k] * w[k][j], K=8
__global__ __launch_bounds__(256) void gemm8_kernel(const float* __restrict__ X,
                                                    const float* __restrict__ w,
                                                    float* __restrict__ h)
{
    __shared__ float ws[512];
    for (int i = threadIdx.x; i < 512; i += 256) ws[i] = w[i];
    __syncthreads();
    int gid = blockIdx.x*256 + threadIdx.x;
    int n = gid >> 6, j = gid & 63;
    const float* xr = X + (size_t)n*8;
    float a = 0.f;
    #pragma unroll
    for (int k = 0; k < 8; ++k) a = fmaf(xr[k], ws[k*64 + j], a);
    h[gid] = a;
}

// h[n][j] = sum_k bf16(xcat[n][k]) * w[k][j], K=64 (xcat row stride 128)
__global__ __launch_bounds__(256) void gemm64bf_kernel(const unsigned short* __restrict__ xcat,
                                                       const float* __restrict__ w,
                                                       float* __restrict__ h)
{
    __shared__ float ws[4096];
    for (int i = threadIdx.x; i < 4096; i += 256) ws[i] = w[i];
    __syncthreads();
    int gid = blockIdx.x*256 + threadIdx.x;
    int n = gid >> 6, j = gid & 63;
    const uint4* xr = (const uint4*)(xcat + (size_t)n*128);
    float a = 0.f;
    #pragma unroll
    for (int kk = 0; kk < 8; ++kk) {
        uint4 xv = xr[kk];
        unsigned int um[4] = {xv.x, xv.y, xv.z, xv.w};
        #pragma unroll
        for (int m = 0; m < 4; ++m) {
            int k0 = kk*8 + m*2;
            a = fmaf(u2f(um[m] << 16),          ws[k0*64 + j],     a);
            a = fmaf(u2f(um[m] & 0xffff0000u),  ws[(k0+1)*64 + j], a);
        }
    }
    h[gid] = a;
}

// wave-per-dst gather: y = relu(sum norm*h[src] + h[d]*dinv^2 + b); BN stats
__global__ __launch_bounds__(256) void gather_kernel(const int* __restrict__ rowptr,
                                                     const uint2* __restrict__ epack,
                                                     const float* __restrict__ h,
                                                     const float* __restrict__ dinv,
                                                     const float* __restrict__ b,
                                                     float* __restrict__ y,
                                                     float* __restrict__ sums)
{
    int lane = threadIdx.x & 63;
    int gwave = blockIdx.x*4 + (threadIdx.x >> 6);
    int nwaves = gridDim.x*4;
    float bc = b[lane];
    float s = 0.f, q = 0.f;
    for (int d = gwave; d < NT; d += nwaves) {
        int beg = rowptr[d], end = rowptr[d+1];
        float acc = 0.f;
        int i = beg;
        uint2 p = (i < end) ? epack[i] : make_uint2(0u, 0u);
        while (i < end) {
            uint2 pn = (i + 1 < end) ? epack[i+1] : p;
            acc = fmaf(u2f(p.y), h[(size_t)p.x*64 + lane], acc);
            p = pn; ++i;
        }
        float dv = dinv[d];
        float v = acc + h[(size_t)d*64 + lane]*dv*dv + bc;
        v = fmaxf(v, 0.f);
        y[(size_t)d*64 + lane] = v;
        s += v; q += v*v;
    }
    __shared__ float sm[256], sq[256];
    sm[threadIdx.x] = s; sq[threadIdx.x] = q;
    __syncthreads();
    if (threadIdx.x < 64) {
        atomicAdd(&sums[lane],      sm[lane] + sm[lane+64] + sm[lane+128] + sm[lane+192]);
        atomicAdd(&sums[64 + lane], sq[lane] + sq[lane+64] + sq[lane+128] + sq[lane+192]);
    }
}

// BN apply -> bf16 xcat[node][coloff + c]
__global__ __launch_bounds__(256) void bnapply_kernel(const float* __restrict__ y,
                                                      unsigned short* __restrict__ xcat,
                                                      int coloff,
                                                      const float* __restrict__ sums,
                                                      const float* __restrict__ g,
                                                      const float* __restrict__ be)
{
    int gid = blockIdx.x*256 + threadIdx.x;
    int c = gid & 63;
    float mu  = sums[c] * (1.0f/NT);
    float var = sums[64 + c] * (1.0f/NT) - mu*mu;
    float v = (y[gid] - mu) * rsqrtf(var + 1e-5f) * g[c] + be[c];
    __hip_bfloat16 hb = __float2bfloat16(v);
    xcat[(size_t)(gid >> 6)*128 + coloff + c] = *(unsigned short*)&hb;
}

// ---------------- fused 2-layer 8-step LSTM on MFMA --------------------------
#define LROW 328
__global__ __launch_bounds__(256, 2) void lstm_mfma_kernel(
    const unsigned short* __restrict__ xcat,
    const unsigned int* __restrict__ W1f, const unsigned int* __restrict__ W2f,
    const float* __restrict__ bs1, const float* __restrict__ bs2,
    float* __restrict__ out)
{
    __shared__ __align__(16) unsigned short xb[16][LROW];
    const int tid  = threadIdx.x;
    const int w    = tid >> 6, lane = tid & 63;
    const int lr   = lane & 15;
    const int lg   = lane >> 4;
    const int nb0  = blockIdx.x * 16;

    uint4 w1f[4][6], w2f[4][4];
    {
        const uint4* p1 = (const uint4*)W1f;
        #pragma unroll
        for (int nt = 0; nt < 4; ++nt)
            #pragma unroll
            for (int ks = 0; ks < 6; ++ks)
                w1f[nt][ks] = p1[((w*4 + nt)*6 + ks)*64 + lane];
        const uint4* p2 = (const uint4*)W2f;
        #pragma unroll
        for (int nt = 0; nt < 4; ++nt)
            #pragma unroll
            for (int ks = 0; ks < 4; ++ks)
                w2f[nt][ks] = p2[((w*4 + nt)*4 + ks)*64 + lane];
    }
    float b1v[4], b2v[4];
    #pragma unroll
    for (int nt = 0; nt < 4; ++nt) {
        b1v[nt] = bs1[nt*64 + w*16 + lr];
        b2v[nt] = bs2[nt*64 + w*16 + lr];
    }

    {
        int n = tid >> 4, k0 = 128 + (tid & 15)*8;
        uint4 z; z.x = z.y = z.z = z.w = 0u;
        *(uint4*)&xb[n][k0] = z;
    }
    float c1[4] = {0.f,0.f,0.f,0.f}, c2[4] = {0.f,0.f,0.f,0.f};

    for (int step = 0; step < 8; ++step) {
        {
            int n = tid >> 4, k0 = (tid & 15)*8;
            *(uint4*)&xb[n][k0] =
                *(const uint4*)&xcat[((size_t)(step*NNODES + nb0 + n))*128 + k0];
        }
        __syncthreads();

        f32x4 acc[4];
        #pragma unroll
        for (int nt = 0; nt < 4; ++nt) { acc[nt][0]=0.f; acc[nt][1]=0.f; acc[nt][2]=0.f; acc[nt][3]=0.f; }
        #pragma unroll
        for (int ks = 0; ks < 6; ++ks) {
            bf16x8 a = *(const bf16x8*)&xb[lr][ks*32 + lg*8];
            #pragma unroll
            for (int nt = 0; nt < 4; ++nt) {
                union { uint4 u; bf16x8 v; } wb; wb.u = w1f[nt][ks];
                acc[nt] = __builtin_amdgcn_mfma_f32_16x16x32_bf16(a, wb.v, acc[nt], 0, 0, 0);
            }
        }
        __syncthreads();

        float h1v[4];
        #pragma unroll
        for (int r = 0; r < 4; ++r) {
            float zi = acc[0][r] + b1v[0];
            float zf = acc[1][r] + b1v[1];
            float zg = acc[2][r] + b1v[2];
            float zo = acc[3][r] + b1v[3];
            float c  = fsig(zf)*c1[r] + fsig(zi)*ftanh(zg);
            c1[r] = c;
            h1v[r] = fsig(zo)*ftanh(c);
            int node = lg*4 + r;
            __hip_bfloat16 hb = __float2bfloat16(h1v[r]);
            xb[node][128 + w*16 + lr] = *(unsigned short*)&hb;
            if (step == 7) out[(size_t)(nb0 + node)*143 + w*16 + lr] = h1v[r];
        }
        __syncthreads();

        #pragma unroll
        for (int nt = 0; nt < 4; ++nt) { acc[nt][0]=0.f; acc[nt][1]=0.f; acc[nt][2]=0.f; acc[nt][3]=0.f; }
        #pragma unroll
        for (int ks = 0; ks < 4; ++ks) {
            bf16x8 a = *(const bf16x8*)&xb[lr][128 + ks*32 + lg*8];
            #pragma unroll
            for (int nt = 0; nt < 4; ++nt) {
                union { uint4 u; bf16x8 v; } wb; wb.u = w2f[nt][ks];
                acc[nt] = __builtin_amdgcn_mfma_f32_16x16x32_bf16(a, wb.v, acc[nt], 0, 0, 0);
            }
        }
        __syncthreads();

        #pragma unroll
        for (int r = 0; r < 4; ++r) {
            float zi = acc[0][r] + b2v[0];
            float zf = acc[1][r] + b2v[1];
            float zg = acc[2][r] + b2v[2];
            float zo = acc[3][r] + b2v[3];
            float c  = fsig(zf)*c2[r] + fsig(zi)*ftanh(zg);
            c2[r] = c;
            float hv = fsig(zo)*ftanh(c);
            int node = lg*4 + r;
            __hip_bfloat16 hb = __float2bfloat16(hv);
            xb[node][192 + w*16 + lr] = *(unsigned short*)&hb;
            if (step == 7) out[(size_t)(nb0 + node)*143 + 64 + w*16 + lr] = hv;
        }
        __syncthreads();
    }
}

__global__ __launch_bounds__(256) void sfeat_kernel(const float* __restrict__ X,
                                                    float* __restrict__ out)
{
    int gid = blockIdx.x*256 + threadIdx.x;
    if (gid >= NNODES*15) return;
    int n = gid/15, i = gid%15;
    float v = (i < 8) ? X[(size_t)n*8 + i]
                      : X[((size_t)(i-7)*NNODES + n)*8 + 7];
    out[(size_t)n*143 + 128 + i] = v;
}

extern "C" void kernel_launch(void* const* d_in, const int* in_sizes, int n_in,
                              void* d_out, int out_size, void* d_ws, size_t ws_size,
                              hipStream_t stream)
{
    (void)in_sizes; (void)n_in; (void)out_size; (void)ws_size;
    const float* X    = (const float*)d_in[0];
    const int*   ei   = (const int*)d_in[1];
    const float* ew   = (const float*)d_in[2];
    const float* w1   = (const float*)d_in[3];
    const float* b1   = (const float*)d_in[4];
    const float* w2   = (const float*)d_in[5];
    const float* b2   = (const float*)d_in[6];
    const float* g1   = (const float*)d_in[7];
    const float* be1  = (const float*)d_in[8];
    const float* g2   = (const float*)d_in[9];
    const float* be2  = (const float*)d_in[10];
    const float* wih1 = (const float*)d_in[11];
    const float* whh1 = (const float*)d_in[12];
    const float* bih1 = (const float*)d_in[13];
    const float* bhh1 = (const float*)d_in[14];
    const float* wih2 = (const float*)d_in[15];
    const float* whh2 = (const float*)d_in[16];
    const float* bih2 = (const float*)d_in[17];
    const float* bhh2 = (const float*)d_in[18];
    float* out = (float*)d_out;
    float* ws  = (float*)d_ws;

    const int* src = ei;
    const int* dst = ei + NE;

    // workspace layout (word offsets)
    float* deg    = ws;                        // 80000 (becomes dinv)
    float* sums   = ws + 80000;                // 256
    int*   count  = (int*)(ws + 80256);        // 80000   [zeroed]
    int*   rowptr = count + 80000;             // 80001
    int*   cursor = rowptr + 80001;            // 80000
    float* h      = ws + 320260;               // NT*64 (16B aligned)
    float* y      = h + (size_t)NT*64;         // NT*64
    unsigned short* xcat = (unsigned short*)(y + (size_t)NT*64);   // NT*128 bf16
    uint2* epack  = (uint2*)(xcat + (size_t)NT*128);               // NE * 8B
    unsigned int* W1f = (unsigned int*)(epack + NE);               // 24576
    unsigned int* W2f = W1f + 24576;           // 16384
    float* bs1 = (float*)(W2f + 16384);        // 256
    float* bs2 = bs1 + 256;                    // 256

    // zero deg + sums + count
    hipMemsetAsync(ws, 0, (size_t)(80256 + 80000) * 4, stream);

    prep_w_kernel<<<162, 256, 0, stream>>>(wih1,whh1,bih1,bhh1,
                                           wih2,whh2,bih2,bhh2,
                                           W1f,W2f,bs1,bs2);
    histdeg_kernel<<<1024, 256, 0, stream>>>(dst, ew, deg, count);
    dinv_kernel<<<(NT+255)/256, 256, 0, stream>>>(deg);
    scan_kernel<<<1, 1024, 0, stream>>>(count, rowptr, cursor);
    reorder_kernel<<<1024, 256, 0, stream>>>(src, dst, ew, deg, cursor, epack);

    // GCN layer 1
    gemm8_kernel<<<NT*64/256, 256, 0, stream>>>(X, w1, h);
    gather_kernel<<<2048, 256, 0, stream>>>(rowptr, epack, h, deg, b1, y, sums);
    bnapply_kernel<<<NT*64/256, 256, 0, stream>>>(y, xcat, 0, sums, g1, be1);

    // GCN layer 2
    gemm64bf_kernel<<<NT*64/256, 256, 0, stream>>>(xcat, w2, h);
    gather_kernel<<<2048, 256, 0, stream>>>(rowptr, epack, h, deg, b2, y, sums + 128);
    bnapply_kernel<<<NT*64/256, 256, 0, stream>>>(y, xcat, 64, sums + 128, g2, be2);

    // fused MFMA LSTM + skip features
    lstm_mfma_kernel<<<NNODES/16, 256, 0, stream>>>(xcat, W1f, W2f, bs1, bs2, out);
    sfeat_kernel<<<(NNODES*15+255)/256, 256, 0, stream>>>(X, out);
}

// Round 4
// 639.746 us; speedup vs baseline: 1.3240x; 1.3240x over previous
//
#include <hip/hip_runtime.h>
#include <hip/hip_bf16.h>
#include <math.h>

#define NNODES 10000
#define NT     80000
#define NE     1280000

typedef __bf16 bf16x8 __attribute__((ext_vector_type(8)));
typedef float  f32x4  __attribute__((ext_vector_type(4)));

__device__ __forceinline__ float frcp(float x){ return __builtin_amdgcn_rcpf(x); }
__device__ __forceinline__ float fsig(float x){ return frcp(1.0f + __expf(-x)); }
__device__ __forceinline__ float ftanh(float x){ return 1.0f - 2.0f*frcp(1.0f + __expf(2.0f*x)); }
__device__ __forceinline__ float u2f(unsigned int u){ union{unsigned int u; float f;} c; c.u=u; return c.f; }

// ---------------- weight prep: pack LSTM weights into MFMA B-fragment order ---
__global__ __launch_bounds__(256) void prep_w_kernel(
    const float* __restrict__ wih1, const float* __restrict__ whh1,
    const float* __restrict__ bih1, const float* __restrict__ bhh1,
    const float* __restrict__ wih2, const float* __restrict__ whh2,
    const float* __restrict__ bih2, const float* __restrict__ bhh2,
    unsigned int* __restrict__ W1f, unsigned int* __restrict__ W2f,
    float* __restrict__ bs1, float* __restrict__ bs2)
{
    int gid = blockIdx.x*256 + threadIdx.x;
    if (gid < 24576) {
        int i = gid & 3, lane = (gid>>2)&63, rest = gid>>8;
        int ks = rest % 6; rest /= 6;
        int nt = rest & 3, w = rest >> 2;
        int gate = nt*64 + w*16 + (lane & 15);
        int k = ks*32 + ((lane>>4)&3)*8 + 2*i;
        float v0 = (k     < 128) ? wih1[gate*128 + k]       : whh1[gate*64 + (k-128)];
        float v1 = (k + 1 < 128) ? wih1[gate*128 + k + 1]   : whh1[gate*64 + (k+1-128)];
        __hip_bfloat16 h0 = __float2bfloat16(v0), h1 = __float2bfloat16(v1);
        W1f[gid] = (unsigned int)*(unsigned short*)&h0 | ((unsigned int)*(unsigned short*)&h1 << 16);
    } else if (gid < 24576 + 16384) {
        int r = gid - 24576;
        int i = r & 3, lane = (r>>2)&63, rest = r>>8;
        int ks = rest & 3; rest >>= 2;
        int nt = rest & 3, w = rest >> 2;
        int gate = nt*64 + w*16 + (lane & 15);
        int k = ks*32 + ((lane>>4)&3)*8 + 2*i;
        float v0 = (k     < 64) ? wih2[gate*64 + k]     : whh2[gate*64 + (k-64)];
        float v1 = (k + 1 < 64) ? wih2[gate*64 + k + 1] : whh2[gate*64 + (k+1-64)];
        __hip_bfloat16 h0 = __float2bfloat16(v0), h1 = __float2bfloat16(v1);
        W2f[r] = (unsigned int)*(unsigned short*)&h0 | ((unsigned int)*(unsigned short*)&h1 << 16);
    } else if (gid < 24576 + 16384 + 256) {
        int j = gid - (24576 + 16384); bs1[j] = bih1[j] + bhh1[j];
    } else if (gid < 24576 + 16384 + 512) {
        int j = gid - (24576 + 16384 + 256); bs2[j] = bih2[j] + bhh2[j];
    }
}

// fused: deg[d] += ew ; count[d] += 1
__global__ __launch_bounds__(256) void histdeg_kernel(const int* __restrict__ dst,
                                                      const float* __restrict__ ew,
                                                      float* __restrict__ deg,
                                                      int* __restrict__ count)
{
    int gid = blockIdx.x*blockDim.x + threadIdx.x;
    int stride = gridDim.x*blockDim.x;
    for (int e = gid; e < NE; e += stride) {
        int d = dst[e];
        atomicAdd(&deg[d], ew[e]);
        atomicAdd(&count[d], 1);
    }
}

// ---- 3-phase parallel scan of count[NT] (625 blocks x 128) ----
// scan1: per-block total; also deg -> rsqrt(deg+1) in place (fused dinv)
__global__ __launch_bounds__(128) void scan1_kernel(const int* __restrict__ count,
                                                    int* __restrict__ blocksum,
                                                    float* __restrict__ deg)
{
    __shared__ int sm[128];
    int tid = threadIdx.x;
    int idx = blockIdx.x*128 + tid;
    deg[idx] = rsqrtf(deg[idx] + 1.0f);
    sm[tid] = count[idx];
    __syncthreads();
    #pragma unroll
    for (int off = 64; off > 0; off >>= 1) {
        if (tid < off) sm[tid] += sm[tid + off];
        __syncthreads();
    }
    if (tid == 0) blocksum[blockIdx.x] = sm[0];
}

// scan2: exclusive scan of 625 block sums (single block, 1024 threads)
__global__ __launch_bounds__(1024) void scan2_kernel(const int* __restrict__ blocksum,
                                                     int* __restrict__ blockoff)
{
    __shared__ int part[1024];
    int tid = threadIdx.x;
    int v = (tid < 625) ? blocksum[tid] : 0;
    part[tid] = v;
    __syncthreads();
    for (int off = 1; off < 1024; off <<= 1) {
        int t = (tid >= off) ? part[tid - off] : 0;
        __syncthreads();
        part[tid] += t;
        __syncthreads();
    }
    if (tid < 625) blockoff[tid] = part[tid] - v;
}

// scan3: in-block exclusive scan + block offset -> rowptr, cursor
__global__ __launch_bounds__(128) void scan3_kernel(const int* __restrict__ count,
                                                    const int* __restrict__ blockoff,
                                                    int* __restrict__ rowptr,
                                                    int* __restrict__ cursor)
{
    __shared__ int part[128];
    int tid = threadIdx.x;
    int idx = blockIdx.x*128 + tid;
    int v = count[idx];
    part[tid] = v;
    __syncthreads();
    #pragma unroll
    for (int off = 1; off < 128; off <<= 1) {
        int t = (tid >= off) ? part[tid - off] : 0;
        __syncthreads();
        part[tid] += t;
        __syncthreads();
    }
    int ex = part[tid] - v + blockoff[blockIdx.x];
    rowptr[idx] = ex;
    cursor[idx] = ex;
    if (idx == 0) rowptr[NT] = NE;
}

// bucket edges by dst: epack[pos] = (src, norm) with norm = ew*dinv[s]*dinv[d]
__global__ __launch_bounds__(256) void reorder_kernel(const int* __restrict__ src,
                                                      const int* __restrict__ dst,
                                                      const float* __restrict__ ew,
                                                      const float* __restrict__ dinv,
                                                      int* __restrict__ cursor,
                                                      uint2* __restrict__ epack)
{
    int gid = blockIdx.x*blockDim.x + threadIdx.x;
    int stride = gridDim.x*blockDim.x;
    for (int e = gid; e < NE; e += stride) {
        int d = dst[e], s = src[e];
        float nrm = ew[e] * dinv[s] * dinv[d];
        int pos = atomicAdd(&cursor[d], 1);
        uint2 p; p.x = (unsigned int)s;
        union{float f; unsigned int u;} c; c.f = nrm; p.y = c.u;
        epack[pos] = p;
    }
}

// h[n][j] = sum_k X[n][k] * w[k][j], K=8
__global__ __launch_bounds__(256) void gemm8_kernel(const float* __restrict__ X,
                                                    const float* __restrict__ w,
                                                    float* __restrict__ h)
{
    __shared__ float ws[512];
    for (int i = threadIdx.x; i < 512; i += 256) ws[i] = w[i];
    __syncthreads();
    int gid = blockIdx.x*256 + threadIdx.x;
    int n = gid >> 6, j = gid & 63;
    const float* xr = X + (size_t)n*8;
    float a = 0.f;
    #pragma unroll
    for (int k = 0; k < 8; ++k) a = fmaf(xr[k], ws[k*64 + j], a);
    h[gid] = a;
}

// h[n][j] = sum_k bf16(xcat[n][k]) * w[k][j], K=64 (xcat row stride 128)
__global__ __launch_bounds__(256) void gemm64bf_kernel(const unsigned short* __restrict__ xcat,
                                                       const float* __restrict__ w,
                                                       float* __restrict__ h)
{
    __shared__ float ws[4096];
    for (int i = threadIdx.x; i < 4096; i += 256) ws[i] = w[i];
    __syncthreads();
    int gid = blockIdx.x*256 + threadIdx.x;
    int n = gid >> 6, j = gid & 63;
    const uint4* xr = (const uint4*)(xcat + (size_t)n*128);
    float a = 0.f;
    #pragma unroll
    for (int kk = 0; kk < 8; ++kk) {
        uint4 xv = xr[kk];
        unsigned int um[4] = {xv.x, xv.y, xv.z, xv.w};
        #pragma unroll
        for (int m = 0; m < 4; ++m) {
            int k0 = kk*8 + m*2;
            a = fmaf(u2f(um[m] << 16),          ws[k0*64 + j],     a);
            a = fmaf(u2f(um[m] & 0xffff0000u),  ws[(k0+1)*64 + j], a);
        }
    }
    h[gid] = a;
}

// wave-per-dst gather: y = relu(sum norm*h[src] + h[d]*dinv^2 + b); BN stats
__global__ __launch_bounds__(256) void gather_kernel(const int* __restrict__ rowptr,
                                                     const uint2* __restrict__ epack,
                                                     const float* __restrict__ h,
                                                     const float* __restrict__ dinv,
                                                     const float* __restrict__ b,
                                                     float* __restrict__ y,
                                                     float* __restrict__ sums)
{
    int lane = threadIdx.x & 63;
    int gwave = blockIdx.x*4 + (threadIdx.x >> 6);
    int nwaves = gridDim.x*4;
    float bc = b[lane];
    float s = 0.f, q = 0.f;
    for (int d = gwave; d < NT; d += nwaves) {
        int beg = rowptr[d], end = rowptr[d+1];
        float acc = 0.f;
        int i = beg;
        uint2 p = (i < end) ? epack[i] : make_uint2(0u, 0u);
        while (i < end) {
            uint2 pn = (i + 1 < end) ? epack[i+1] : p;
            acc = fmaf(u2f(p.y), h[(size_t)p.x*64 + lane], acc);
            p = pn; ++i;
        }
        float dv = dinv[d];
        float v = acc + h[(size_t)d*64 + lane]*dv*dv + bc;
        v = fmaxf(v, 0.f);
        y[(size_t)d*64 + lane] = v;
        s += v; q += v*v;
    }
    __shared__ float sm[256], sq[256];
    sm[threadIdx.x] = s; sq[threadIdx.x] = q;
    __syncthreads();
    if (threadIdx.x < 64) {
        atomicAdd(&sums[lane],      sm[lane] + sm[lane+64] + sm[lane+128] + sm[lane+192]);
        atomicAdd(&sums[64 + lane], sq[lane] + sq[lane+64] + sq[lane+128] + sq[lane+192]);
    }
}

// BN apply -> bf16 xcat[node][coloff + c]
__global__ __launch_bounds__(256) void bnapply_kernel(const float* __restrict__ y,
                                                      unsigned short* __restrict__ xcat,
                                                      int coloff,
                                                      const float* __restrict__ sums,
                                                      const float* __restrict__ g,
                                                      const float* __restrict__ be)
{
    int gid = blockIdx.x*256 + threadIdx.x;
    int c = gid & 63;
    float mu  = sums[c] * (1.0f/NT);
    float var = sums[64 + c] * (1.0f/NT) - mu*mu;
    float v = (y[gid] - mu) * rsqrtf(var + 1e-5f) * g[c] + be[c];
    __hip_bfloat16 hb = __float2bfloat16(v);
    xcat[(size_t)(gid >> 6)*128 + coloff + c] = *(unsigned short*)&hb;
}

// ---------------- fused 2-layer 8-step LSTM on MFMA --------------------------
#define LROW 328
__global__ __launch_bounds__(256, 2) void lstm_mfma_kernel(
    const unsigned short* __restrict__ xcat,
    const unsigned int* __restrict__ W1f, const unsigned int* __restrict__ W2f,
    const float* __restrict__ bs1, const float* __restrict__ bs2,
    float* __restrict__ out)
{
    __shared__ __align__(16) unsigned short xb[16][LROW];
    const int tid  = threadIdx.x;
    const int w    = tid >> 6, lane = tid & 63;
    const int lr   = lane & 15;
    const int lg   = lane >> 4;
    const int nb0  = blockIdx.x * 16;

    uint4 w1f[4][6], w2f[4][4];
    {
        const uint4* p1 = (const uint4*)W1f;
        #pragma unroll
        for (int nt = 0; nt < 4; ++nt)
            #pragma unroll
            for (int ks = 0; ks < 6; ++ks)
                w1f[nt][ks] = p1[((w*4 + nt)*6 + ks)*64 + lane];
        const uint4* p2 = (const uint4*)W2f;
        #pragma unroll
        for (int nt = 0; nt < 4; ++nt)
            #pragma unroll
            for (int ks = 0; ks < 4; ++ks)
                w2f[nt][ks] = p2[((w*4 + nt)*4 + ks)*64 + lane];
    }
    float b1v[4], b2v[4];
    #pragma unroll
    for (int nt = 0; nt < 4; ++nt) {
        b1v[nt] = bs1[nt*64 + w*16 + lr];
        b2v[nt] = bs2[nt*64 + w*16 + lr];
    }

    {
        int n = tid >> 4, k0 = 128 + (tid & 15)*8;
        uint4 z; z.x = z.y = z.z = z.w = 0u;
        *(uint4*)&xb[n][k0] = z;
    }
    float c1[4] = {0.f,0.f,0.f,0.f}, c2[4] = {0.f,0.f,0.f,0.f};

    for (int step = 0; step < 8; ++step) {
        {
            int n = tid >> 4, k0 = (tid & 15)*8;
            *(uint4*)&xb[n][k0] =
                *(const uint4*)&xcat[((size_t)(step*NNODES + nb0 + n))*128 + k0];
        }
        __syncthreads();

        f32x4 acc[4];
        #pragma unroll
        for (int nt = 0; nt < 4; ++nt) { acc[nt][0]=0.f; acc[nt][1]=0.f; acc[nt][2]=0.f; acc[nt][3]=0.f; }
        #pragma unroll
        for (int ks = 0; ks < 6; ++ks) {
            bf16x8 a = *(const bf16x8*)&xb[lr][ks*32 + lg*8];
            #pragma unroll
            for (int nt = 0; nt < 4; ++nt) {
                union { uint4 u; bf16x8 v; } wb; wb.u = w1f[nt][ks];
                acc[nt] = __builtin_amdgcn_mfma_f32_16x16x32_bf16(a, wb.v, acc[nt], 0, 0, 0);
            }
        }
        __syncthreads();

        float h1v[4];
        #pragma unroll
        for (int r = 0; r < 4; ++r) {
            float zi = acc[0][r] + b1v[0];
            float zf = acc[1][r] + b1v[1];
            float zg = acc[2][r] + b1v[2];
            float zo = acc[3][r] + b1v[3];
            float c  = fsig(zf)*c1[r] + fsig(zi)*ftanh(zg);
            c1[r] = c;
            h1v[r] = fsig(zo)*ftanh(c);
            int node = lg*4 + r;
            __hip_bfloat16 hb = __float2bfloat16(h1v[r]);
            xb[node][128 + w*16 + lr] = *(unsigned short*)&hb;
            if (step == 7) out[(size_t)(nb0 + node)*143 + w*16 + lr] = h1v[r];
        }
        __syncthreads();

        #pragma unroll
        for (int nt = 0; nt < 4; ++nt) { acc[nt][0]=0.f; acc[nt][1]=0.f; acc[nt][2]=0.f; acc[nt][3]=0.f; }
        #pragma unroll
        for (int ks = 0; ks < 4; ++ks) {
            bf16x8 a = *(const bf16x8*)&xb[lr][128 + ks*32 + lg*8];
            #pragma unroll
            for (int nt = 0; nt < 4; ++nt) {
                union { uint4 u; bf16x8 v; } wb; wb.u = w2f[nt][ks];
                acc[nt] = __builtin_amdgcn_mfma_f32_16x16x32_bf16(a, wb.v, acc[nt], 0, 0, 0);
            }
        }
        __syncthreads();

        #pragma unroll
        for (int r = 0; r < 4; ++r) {
            float zi = acc[0][r] + b2v[0];
            float zf = acc[1][r] + b2v[1];
            float zg = acc[2][r] + b2v[2];
            float zo = acc[3][r] + b2v[3];
            float c  = fsig(zf)*c2[r] + fsig(zi)*ftanh(zg);
            c2[r] = c;
            float hv = fsig(zo)*ftanh(c);
            int node = lg*4 + r;
            __hip_bfloat16 hb = __float2bfloat16(hv);
            xb[node][192 + w*16 + lr] = *(unsigned short*)&hb;
            if (step == 7) out[(size_t)(nb0 + node)*143 + 64 + w*16 + lr] = hv;
        }
        __syncthreads();
    }
}

__global__ __launch_bounds__(256) void sfeat_kernel(const float* __restrict__ X,
                                                    float* __restrict__ out)
{
    int gid = blockIdx.x*256 + threadIdx.x;
    if (gid >= NNODES*15) return;
    int n = gid/15, i = gid%15;
    float v = (i < 8) ? X[(size_t)n*8 + i]
                      : X[((size_t)(i-7)*NNODES + n)*8 + 7];
    out[(size_t)n*143 + 128 + i] = v;
}

extern "C" void kernel_launch(void* const* d_in, const int* in_sizes, int n_in,
                              void* d_out, int out_size, void* d_ws, size_t ws_size,
                              hipStream_t stream)
{
    (void)in_sizes; (void)n_in; (void)out_size; (void)ws_size;
    const float* X    = (const float*)d_in[0];
    const int*   ei   = (const int*)d_in[1];
    const float* ew   = (const float*)d_in[2];
    const float* w1   = (const float*)d_in[3];
    const float* b1   = (const float*)d_in[4];
    const float* w2   = (const float*)d_in[5];
    const float* b2   = (const float*)d_in[6];
    const float* g1   = (const float*)d_in[7];
    const float* be1  = (const float*)d_in[8];
    const float* g2   = (const float*)d_in[9];
    const float* be2  = (const float*)d_in[10];
    const float* wih1 = (const float*)d_in[11];
    const float* whh1 = (const float*)d_in[12];
    const float* bih1 = (const float*)d_in[13];
    const float* bhh1 = (const float*)d_in[14];
    const float* wih2 = (const float*)d_in[15];
    const float* whh2 = (const float*)d_in[16];
    const float* bih2 = (const float*)d_in[17];
    const float* bhh2 = (const float*)d_in[18];
    float* out = (float*)d_out;
    float* ws  = (float*)d_ws;

    const int* src = ei;
    const int* dst = ei + NE;

    // workspace layout (word offsets)
    float* deg    = ws;                        // 80000 (becomes dinv)
    float* sums   = ws + 80000;                // 256
    int*   count  = (int*)(ws + 80256);        // 80000   [zeroed]
    int*   rowptr = count + 80000;             // 80001
    int*   cursor = rowptr + 80001;            // 80000
    int*   blocksum = cursor + 80000;          // 625
    int*   blockoff = blocksum + 625;          // 625
    float* h      = ws + 321536;               // NT*64 (16B aligned)
    float* y      = h + (size_t)NT*64;         // NT*64
    unsigned short* xcat = (unsigned short*)(y + (size_t)NT*64);   // NT*128 bf16
    uint2* epack  = (uint2*)(xcat + (size_t)NT*128);               // NE * 8B
    unsigned int* W1f = (unsigned int*)(epack + NE);               // 24576
    unsigned int* W2f = W1f + 24576;           // 16384
    float* bs1 = (float*)(W2f + 16384);        // 256
    float* bs2 = bs1 + 256;                    // 256

    // zero deg + sums + count
    hipMemsetAsync(ws, 0, (size_t)(80256 + 80000) * 4, stream);

    prep_w_kernel<<<162, 256, 0, stream>>>(wih1,whh1,bih1,bhh1,
                                           wih2,whh2,bih2,bhh2,
                                           W1f,W2f,bs1,bs2);
    histdeg_kernel<<<1024, 256, 0, stream>>>(dst, ew, deg, count);
    scan1_kernel<<<625, 128, 0, stream>>>(count, blocksum, deg);
    scan2_kernel<<<1, 1024, 0, stream>>>(blocksum, blockoff);
    scan3_kernel<<<625, 128, 0, stream>>>(count, blockoff, rowptr, cursor);
    reorder_kernel<<<1024, 256, 0, stream>>>(src, dst, ew, deg, cursor, epack);

    // GCN layer 1
    gemm8_kernel<<<NT*64/256, 256, 0, stream>>>(X, w1, h);
    gather_kernel<<<2048, 256, 0, stream>>>(rowptr, epack, h, deg, b1, y, sums);
    bnapply_kernel<<<NT*64/256, 256, 0, stream>>>(y, xcat, 0, sums, g1, be1);

    // GCN layer 2
    gemm64bf_kernel<<<NT*64/256, 256, 0, stream>>>(xcat, w2, h);
    gather_kernel<<<2048, 256, 0, stream>>>(rowptr, epack, h, deg, b2, y, sums + 128);
    bnapply_kernel<<<NT*64/256, 256, 0, stream>>>(y, xcat, 64, sums + 128, g2, be2);

    // fused MFMA LSTM + skip features
    lstm_mfma_kernel<<<NNODES/16, 256, 0, stream>>>(xcat, W1f, W2f, bs1, bs2, out);
    sfeat_kernel<<<(NNODES*15+255)/256, 256, 0, stream>>>(X, out);
}

// Round 5
// 419.195 us; speedup vs baseline: 2.0206x; 1.5261x over previous
//
#include <hip/hip_runtime.h>
#include <hip/hip_bf16.h>
#include <math.h>

#define NNODES 10000
#define NT     80000
#define NE     1280000

typedef __bf16 bf16x8 __attribute__((ext_vector_type(8)));
typedef float  f32x4  __attribute__((ext_vector_type(4)));

__device__ __forceinline__ float frcp(float x){ return __builtin_amdgcn_rcpf(x); }
__device__ __forceinline__ float fsig(float x){ return frcp(1.0f + __expf(-x)); }
__device__ __forceinline__ float ftanh(float x){ return 1.0f - 2.0f*frcp(1.0f + __expf(2.0f*x)); }
__device__ __forceinline__ float u2f(unsigned int u){ union{unsigned int u; float f;} c; c.u=u; return c.f; }
__device__ __forceinline__ unsigned short f2bu(float v){ __hip_bfloat16 h = __float2bfloat16(v); return *(unsigned short*)&h; }
__device__ __forceinline__ unsigned int pk2(float a, float b){ return (unsigned int)f2bu(a) | ((unsigned int)f2bu(b) << 16); }

// ---------------- weight prep: pack LSTM weights into MFMA B-fragment order ---
__global__ __launch_bounds__(256) void prep_w_kernel(
    const float* __restrict__ wih1, const float* __restrict__ whh1,
    const float* __restrict__ bih1, const float* __restrict__ bhh1,
    const float* __restrict__ wih2, const float* __restrict__ whh2,
    const float* __restrict__ bih2, const float* __restrict__ bhh2,
    unsigned int* __restrict__ W1f, unsigned int* __restrict__ W2f,
    float* __restrict__ bs1, float* __restrict__ bs2)
{
    int gid = blockIdx.x*256 + threadIdx.x;
    if (gid < 24576) {
        int i = gid & 3, lane = (gid>>2)&63, rest = gid>>8;
        int ks = rest % 6; rest /= 6;
        int nt = rest & 3, w = rest >> 2;
        int gate = nt*64 + w*16 + (lane & 15);
        int k = ks*32 + ((lane>>4)&3)*8 + 2*i;
        float v0 = (k     < 128) ? wih1[gate*128 + k]       : whh1[gate*64 + (k-128)];
        float v1 = (k + 1 < 128) ? wih1[gate*128 + k + 1]   : whh1[gate*64 + (k+1-128)];
        W1f[gid] = pk2(v0, v1);
    } else if (gid < 24576 + 16384) {
        int r = gid - 24576;
        int i = r & 3, lane = (r>>2)&63, rest = r>>8;
        int ks = rest & 3; rest >>= 2;
        int nt = rest & 3, w = rest >> 2;
        int gate = nt*64 + w*16 + (lane & 15);
        int k = ks*32 + ((lane>>4)&3)*8 + 2*i;
        float v0 = (k     < 64) ? wih2[gate*64 + k]     : whh2[gate*64 + (k-64)];
        float v1 = (k + 1 < 64) ? wih2[gate*64 + k + 1] : whh2[gate*64 + (k+1-64)];
        W2f[r] = pk2(v0, v1);
    } else if (gid < 24576 + 16384 + 256) {
        int j = gid - (24576 + 16384); bs1[j] = bih1[j] + bhh1[j];
    } else if (gid < 24576 + 16384 + 512) {
        int j = gid - (24576 + 16384 + 256); bs2[j] = bih2[j] + bhh2[j];
    }
}

// fused: deg[d] += ew ; count[d] += 1
__global__ __launch_bounds__(256) void histdeg_kernel(const int* __restrict__ dst,
                                                      const float* __restrict__ ew,
                                                      float* __restrict__ deg,
                                                      int* __restrict__ count)
{
    int gid = blockIdx.x*blockDim.x + threadIdx.x;
    int stride = gridDim.x*blockDim.x;
    for (int e = gid; e < NE; e += stride) {
        int d = dst[e];
        atomicAdd(&deg[d], ew[e]);
        atomicAdd(&count[d], 1);
    }
}

// ---- 3-phase parallel scan of count[NT] (625 blocks x 128) ----
__global__ __launch_bounds__(128) void scan1_kernel(const int* __restrict__ count,
                                                    int* __restrict__ blocksum,
                                                    float* __restrict__ deg)
{
    __shared__ int sm[128];
    int tid = threadIdx.x;
    int idx = blockIdx.x*128 + tid;
    deg[idx] = rsqrtf(deg[idx] + 1.0f);
    sm[tid] = count[idx];
    __syncthreads();
    #pragma unroll
    for (int off = 64; off > 0; off >>= 1) {
        if (tid < off) sm[tid] += sm[tid + off];
        __syncthreads();
    }
    if (tid == 0) blocksum[blockIdx.x] = sm[0];
}

__global__ __launch_bounds__(1024) void scan2_kernel(const int* __restrict__ blocksum,
                                                     int* __restrict__ blockoff)
{
    __shared__ int part[1024];
    int tid = threadIdx.x;
    int v = (tid < 625) ? blocksum[tid] : 0;
    part[tid] = v;
    __syncthreads();
    for (int off = 1; off < 1024; off <<= 1) {
        int t = (tid >= off) ? part[tid - off] : 0;
        __syncthreads();
        part[tid] += t;
        __syncthreads();
    }
    if (tid < 625) blockoff[tid] = part[tid] - v;
}

__global__ __launch_bounds__(128) void scan3_kernel(const int* __restrict__ count,
                                                    const int* __restrict__ blockoff,
                                                    int* __restrict__ rowptr,
                                                    int* __restrict__ cursor)
{
    __shared__ int part[128];
    int tid = threadIdx.x;
    int idx = blockIdx.x*128 + tid;
    int v = count[idx];
    part[tid] = v;
    __syncthreads();
    #pragma unroll
    for (int off = 1; off < 128; off <<= 1) {
        int t = (tid >= off) ? part[tid - off] : 0;
        __syncthreads();
        part[tid] += t;
        __syncthreads();
    }
    int ex = part[tid] - v + blockoff[blockIdx.x];
    rowptr[idx] = ex;
    cursor[idx] = ex;
    if (idx == 0) rowptr[NT] = NE;
}

// bucket edges by dst: epack[pos] = (src, norm) with norm = ew*dinv[s]*dinv[d]
__global__ __launch_bounds__(256) void reorder_kernel(const int* __restrict__ src,
                                                      const int* __restrict__ dst,
                                                      const float* __restrict__ ew,
                                                      const float* __restrict__ dinv,
                                                      int* __restrict__ cursor,
                                                      uint2* __restrict__ epack)
{
    int gid = blockIdx.x*blockDim.x + threadIdx.x;
    int stride = gridDim.x*blockDim.x;
    for (int e = gid; e < NE; e += stride) {
        int d = dst[e], s = src[e];
        float nrm = ew[e] * dinv[s] * dinv[d];
        int pos = atomicAdd(&cursor[d], 1);
        uint2 p; p.x = (unsigned int)s;
        union{float f; unsigned int u;} c; c.f = nrm; p.y = c.u;
        epack[pos] = p;
    }
}

// X f32 [NT,8] -> Xb bf16 (packed dwords, 4 per row)
__global__ __launch_bounds__(256) void xconv_kernel(const float* __restrict__ X,
                                                    unsigned int* __restrict__ Xb)
{
    int gid = blockIdx.x*256 + threadIdx.x;
    if (gid >= NT*4) return;
    float2 v = *(const float2*)&X[(size_t)gid*2];
    Xb[gid] = pk2(v.x, v.y);
}

// thread-per-dst 8-channel aggregation of Xb (L2-resident table):
// agg8[d] = sum norm*Xb[src] + Xb[d]*dinv^2
__global__ __launch_bounds__(256) void gather8_kernel(const int* __restrict__ rowptr,
                                                      const uint2* __restrict__ epack,
                                                      const uint4* __restrict__ Xb,
                                                      const float* __restrict__ dinv,
                                                      float* __restrict__ agg8)
{
    int d = blockIdx.x*256 + threadIdx.x;
    if (d >= NT) return;
    int beg = rowptr[d], end = rowptr[d+1];
    float acc[8];
    #pragma unroll
    for (int k = 0; k < 8; ++k) acc[k] = 0.f;
    for (int i = beg; i < end; ++i) {
        uint2 p = epack[i];
        float nrm = u2f(p.y);
        uint4 xv = Xb[p.x];
        unsigned int um[4] = {xv.x, xv.y, xv.z, xv.w};
        #pragma unroll
        for (int m = 0; m < 4; ++m) {
            acc[2*m]   = fmaf(nrm, u2f(um[m] << 16),         acc[2*m]);
            acc[2*m+1] = fmaf(nrm, u2f(um[m] & 0xffff0000u), acc[2*m+1]);
        }
    }
    float dv = dinv[d], dv2 = dv*dv;
    uint4 xd = Xb[d];
    unsigned int ud[4] = {xd.x, xd.y, xd.z, xd.w};
    #pragma unroll
    for (int m = 0; m < 4; ++m) {
        acc[2*m]   = fmaf(dv2, u2f(ud[m] << 16),         acc[2*m]);
        acc[2*m+1] = fmaf(dv2, u2f(ud[m] & 0xffff0000u), acc[2*m+1]);
    }
    float4* o = (float4*)&agg8[(size_t)d*8];
    o[0] = make_float4(acc[0], acc[1], acc[2], acc[3]);
    o[1] = make_float4(acc[4], acc[5], acc[6], acc[7]);
}

// y = relu(agg8 @ w1 + b1) -> bf16; fused BN stats
__global__ __launch_bounds__(256) void gemm8relu_kernel(const float* __restrict__ agg8,
                                                        const float* __restrict__ w,
                                                        const float* __restrict__ b,
                                                        unsigned short* __restrict__ y,
                                                        float* __restrict__ sums)
{
    __shared__ float ws[512];
    for (int i = threadIdx.x; i < 512; i += 256) ws[i] = w[i];
    __syncthreads();
    int c = threadIdx.x & 63, wq = threadIdx.x >> 6;
    float bc = b[c];
    float s = 0.f, q = 0.f;
    for (int r = blockIdx.x*4 + wq; r < NT; r += gridDim.x*4) {
        const float4* ar = (const float4*)&agg8[(size_t)r*8];
        float4 a0 = ar[0], a1 = ar[1];
        float v = bc;
        v = fmaf(a0.x, ws[0*64+c], v); v = fmaf(a0.y, ws[1*64+c], v);
        v = fmaf(a0.z, ws[2*64+c], v); v = fmaf(a0.w, ws[3*64+c], v);
        v = fmaf(a1.x, ws[4*64+c], v); v = fmaf(a1.y, ws[5*64+c], v);
        v = fmaf(a1.z, ws[6*64+c], v); v = fmaf(a1.w, ws[7*64+c], v);
        v = fmaxf(v, 0.f);
        y[(size_t)r*64 + c] = f2bu(v);
        s += v; q += v*v;
    }
    __shared__ float sm[256], sq[256];
    sm[threadIdx.x] = s; sq[threadIdx.x] = q;
    __syncthreads();
    if (threadIdx.x < 64) {
        atomicAdd(&sums[c],      sm[c] + sm[c+64] + sm[c+128] + sm[c+192]);
        atomicAdd(&sums[64 + c], sq[c] + sq[c+64] + sq[c+128] + sq[c+192]);
    }
}

// BN apply (2 channels per thread) -> bf16 xcat dword column segment
__global__ __launch_bounds__(256) void bnapply2_kernel(const unsigned short* __restrict__ y,
                                                       unsigned int* __restrict__ xcat,
                                                       int coloffd,
                                                       const float* __restrict__ sums,
                                                       const float* __restrict__ g,
                                                       const float* __restrict__ be)
{
    int gid = blockIdx.x*256 + threadIdx.x;
    if (gid >= NT*32) return;
    int c2 = gid & 31, n = gid >> 5;
    int c0 = 2*c2, c1 = c0 + 1;
    unsigned int yy = *(const unsigned int*)&y[(size_t)n*64 + c0];
    float v0 = u2f(yy << 16), v1 = u2f(yy & 0xffff0000u);
    float mu0 = sums[c0] * (1.0f/NT), mu1 = sums[c1] * (1.0f/NT);
    float va0 = sums[64+c0] * (1.0f/NT) - mu0*mu0;
    float va1 = sums[64+c1] * (1.0f/NT) - mu1*mu1;
    v0 = (v0 - mu0) * rsqrtf(va0 + 1e-5f) * g[c0] + be[c0];
    v1 = (v1 - mu1) * rsqrtf(va1 + 1e-5f) * g[c1] + be[c1];
    xcat[(size_t)n*64 + coloffd + c2] = pk2(v0, v1);
}

// 64-ch bf16 gather from xcat x1-part: 2 edges per wave, dword = 2 ch per lane
__global__ __launch_bounds__(256) void gather64_kernel(const int* __restrict__ rowptr,
                                                       const uint2* __restrict__ epack,
                                                       const unsigned int* __restrict__ xcat,
                                                       const float* __restrict__ dinv,
                                                       unsigned int* __restrict__ agg2)
{
    int lane = threadIdx.x & 63;
    int half = lane >> 5, l = lane & 31;
    int gwave = blockIdx.x*4 + (threadIdx.x >> 6);
    int nwaves = gridDim.x*4;
    for (int d = gwave; d < NT; d += nwaves) {
        int beg = rowptr[d], end = rowptr[d+1];
        float acc0 = 0.f, acc1 = 0.f;
        for (int i = beg; i < end; i += 2) {
            int idx = i + half;
            int idc = (idx < end) ? idx : (end - 1);
            uint2 p = epack[idc];
            float nrm = (idx < end) ? u2f(p.y) : 0.f;
            unsigned int xv = xcat[(size_t)p.x*64 + l];
            acc0 = fmaf(nrm, u2f(xv << 16),         acc0);
            acc1 = fmaf(nrm, u2f(xv & 0xffff0000u), acc1);
        }
        acc0 += __shfl_xor(acc0, 32);
        acc1 += __shfl_xor(acc1, 32);
        if (half == 0) {
            float dv = dinv[d], dv2 = dv*dv;
            unsigned int xd = xcat[(size_t)d*64 + l];
            acc0 = fmaf(dv2, u2f(xd << 16),         acc0);
            acc1 = fmaf(dv2, u2f(xd & 0xffff0000u), acc1);
            agg2[(size_t)d*32 + l] = pk2(acc0, acc1);
        }
    }
}

// y2 = relu(agg2(bf16) @ w2 + b2) -> bf16; fused BN stats
__global__ __launch_bounds__(256) void gemm64relu_kernel(const unsigned int* __restrict__ agg2,
                                                         const float* __restrict__ w,
                                                         const float* __restrict__ b,
                                                         unsigned short* __restrict__ y,
                                                         float* __restrict__ sums)
{
    __shared__ float ws[4096];
    for (int i = threadIdx.x; i < 4096; i += 256) ws[i] = w[i];
    __syncthreads();
    int c = threadIdx.x & 63, wq = threadIdx.x >> 6;
    float bc = b[c];
    float s = 0.f, q = 0.f;
    for (int r = blockIdx.x*4 + wq; r < NT; r += gridDim.x*4) {
        const uint4* xr = (const uint4*)&agg2[(size_t)r*32];
        float v = bc;
        #pragma unroll
        for (int kk = 0; kk < 8; ++kk) {
            uint4 xv = xr[kk];
            unsigned int um[4] = {xv.x, xv.y, xv.z, xv.w};
            #pragma unroll
            for (int m = 0; m < 4; ++m) {
                int k0 = kk*8 + m*2;
                v = fmaf(u2f(um[m] << 16),         ws[k0*64 + c],     v);
                v = fmaf(u2f(um[m] & 0xffff0000u), ws[(k0+1)*64 + c], v);
            }
        }
        v = fmaxf(v, 0.f);
        y[(size_t)r*64 + c] = f2bu(v);
        s += v; q += v*v;
    }
    __shared__ float sm[256], sq[256];
    sm[threadIdx.x] = s; sq[threadIdx.x] = q;
    __syncthreads();
    if (threadIdx.x < 64) {
        atomicAdd(&sums[c],      sm[c] + sm[c+64] + sm[c+128] + sm[c+192]);
        atomicAdd(&sums[64 + c], sq[c] + sq[c+64] + sq[c+128] + sq[c+192]);
    }
}

// ---------------- fused 2-layer 8-step LSTM on MFMA --------------------------
#define LROW 328
__global__ __launch_bounds__(256, 2) void lstm_mfma_kernel(
    const unsigned short* __restrict__ xcat,
    const unsigned int* __restrict__ W1f, const unsigned int* __restrict__ W2f,
    const float* __restrict__ bs1, const float* __restrict__ bs2,
    float* __restrict__ out)
{
    __shared__ __align__(16) unsigned short xb[16][LROW];
    const int tid  = threadIdx.x;
    const int w    = tid >> 6, lane = tid & 63;
    const int lr   = lane & 15;
    const int lg   = lane >> 4;
    const int nb0  = blockIdx.x * 16;

    uint4 w1f[4][6], w2f[4][4];
    {
        const uint4* p1 = (const uint4*)W1f;
        #pragma unroll
        for (int nt = 0; nt < 4; ++nt)
            #pragma unroll
            for (int ks = 0; ks < 6; ++ks)
                w1f[nt][ks] = p1[((w*4 + nt)*6 + ks)*64 + lane];
        const uint4* p2 = (const uint4*)W2f;
        #pragma unroll
        for (int nt = 0; nt < 4; ++nt)
            #pragma unroll
            for (int ks = 0; ks < 4; ++ks)
                w2f[nt][ks] = p2[((w*4 + nt)*4 + ks)*64 + lane];
    }
    float b1v[4], b2v[4];
    #pragma unroll
    for (int nt = 0; nt < 4; ++nt) {
        b1v[nt] = bs1[nt*64 + w*16 + lr];
        b2v[nt] = bs2[nt*64 + w*16 + lr];
    }

    {
        int n = tid >> 4, k0 = 128 + (tid & 15)*8;
        uint4 z; z.x = z.y = z.z = z.w = 0u;
        *(uint4*)&xb[n][k0] = z;
    }
    float c1[4] = {0.f,0.f,0.f,0.f}, c2[4] = {0.f,0.f,0.f,0.f};

    for (int step = 0; step < 8; ++step) {
        {
            int n = tid >> 4, k0 = (tid & 15)*8;
            *(uint4*)&xb[n][k0] =
                *(const uint4*)&xcat[((size_t)(step*NNODES + nb0 + n))*128 + k0];
        }
        __syncthreads();

        f32x4 acc[4];
        #pragma unroll
        for (int nt = 0; nt < 4; ++nt) { acc[nt][0]=0.f; acc[nt][1]=0.f; acc[nt][2]=0.f; acc[nt][3]=0.f; }
        #pragma unroll
        for (int ks = 0; ks < 6; ++ks) {
            bf16x8 a = *(const bf16x8*)&xb[lr][ks*32 + lg*8];
            #pragma unroll
            for (int nt = 0; nt < 4; ++nt) {
                union { uint4 u; bf16x8 v; } wb; wb.u = w1f[nt][ks];
                acc[nt] = __builtin_amdgcn_mfma_f32_16x16x32_bf16(a, wb.v, acc[nt], 0, 0, 0);
            }
        }
        __syncthreads();

        float h1v[4];
        #pragma unroll
        for (int r = 0; r < 4; ++r) {
            float zi = acc[0][r] + b1v[0];
            float zf = acc[1][r] + b1v[1];
            float zg = acc[2][r] + b1v[2];
            float zo = acc[3][r] + b1v[3];
            float c  = fsig(zf)*c1[r] + fsig(zi)*ftanh(zg);
            c1[r] = c;
            h1v[r] = fsig(zo)*ftanh(c);
            int node = lg*4 + r;
            xb[node][128 + w*16 + lr] = f2bu(h1v[r]);
            if (step == 7) out[(size_t)(nb0 + node)*143 + w*16 + lr] = h1v[r];
        }
        __syncthreads();

        #pragma unroll
        for (int nt = 0; nt < 4; ++nt) { acc[nt][0]=0.f; acc[nt][1]=0.f; acc[nt][2]=0.f; acc[nt][3]=0.f; }
        #pragma unroll
        for (int ks = 0; ks < 4; ++ks) {
            bf16x8 a = *(const bf16x8*)&xb[lr][128 + ks*32 + lg*8];
            #pragma unroll
            for (int nt = 0; nt < 4; ++nt) {
                union { uint4 u; bf16x8 v; } wb; wb.u = w2f[nt][ks];
                acc[nt] = __builtin_amdgcn_mfma_f32_16x16x32_bf16(a, wb.v, acc[nt], 0, 0, 0);
            }
        }
        __syncthreads();

        #pragma unroll
        for (int r = 0; r < 4; ++r) {
            float zi = acc[0][r] + b2v[0];
            float zf = acc[1][r] + b2v[1];
            float zg = acc[2][r] + b2v[2];
            float zo = acc[3][r] + b2v[3];
            float c  = fsig(zf)*c2[r] + fsig(zi)*ftanh(zg);
            c2[r] = c;
            float hv = fsig(zo)*ftanh(c);
            int node = lg*4 + r;
            xb[node][192 + w*16 + lr] = f2bu(hv);
            if (step == 7) out[(size_t)(nb0 + node)*143 + 64 + w*16 + lr] = hv;
        }
        __syncthreads();
    }
}

__global__ __launch_bounds__(256) void sfeat_kernel(const float* __restrict__ X,
                                                    float* __restrict__ out)
{
    int gid = blockIdx.x*256 + threadIdx.x;
    if (gid >= NNODES*15) return;
    int n = gid/15, i = gid%15;
    float v = (i < 8) ? X[(size_t)n*8 + i]
                      : X[((size_t)(i-7)*NNODES + n)*8 + 7];
    out[(size_t)n*143 + 128 + i] = v;
}

extern "C" void kernel_launch(void* const* d_in, const int* in_sizes, int n_in,
                              void* d_out, int out_size, void* d_ws, size_t ws_size,
                              hipStream_t stream)
{
    (void)in_sizes; (void)n_in; (void)out_size; (void)ws_size;
    const float* X    = (const float*)d_in[0];
    const int*   ei   = (const int*)d_in[1];
    const float* ew   = (const float*)d_in[2];
    const float* w1   = (const float*)d_in[3];
    const float* b1   = (const float*)d_in[4];
    const float* w2   = (const float*)d_in[5];
    const float* b2   = (const float*)d_in[6];
    const float* g1   = (const float*)d_in[7];
    const float* be1  = (const float*)d_in[8];
    const float* g2   = (const float*)d_in[9];
    const float* be2  = (const float*)d_in[10];
    const float* wih1 = (const float*)d_in[11];
    const float* whh1 = (const float*)d_in[12];
    const float* bih1 = (const float*)d_in[13];
    const float* bhh1 = (const float*)d_in[14];
    const float* wih2 = (const float*)d_in[15];
    const float* whh2 = (const float*)d_in[16];
    const float* bih2 = (const float*)d_in[17];
    const float* bhh2 = (const float*)d_in[18];
    float* out = (float*)d_out;
    float* ws  = (float*)d_ws;

    const int* src = ei;
    const int* dst = ei + NE;

    // workspace layout (word offsets)
    float* deg      = ws;                      // 80000 (becomes dinv)
    float* sums     = ws + 80000;              // 256
    int*   count    = (int*)(ws + 80256);      // 80000   [zeroed]
    int*   rowptr   = count + 80000;           // 80001
    int*   cursor   = rowptr + 80001;          // 80000
    int*   blocksum = cursor + 80000;          // 625
    int*   blockoff = blocksum + 625;          // 625 (ends 321507; pad to 321536)
    unsigned int* Xb   = (unsigned int*)(ws + 321536);   // NT*4   dwords
    float*        agg8 = ws + 641536;                    // NT*8   f32
    unsigned short* y  = (unsigned short*)(ws + 1281536);// NT*64  bf16 (NT*32 dwords)
    unsigned int* agg2 = (unsigned int*)(ws + 3841536);  // NT*32  dwords
    unsigned int* xcat = (unsigned int*)(ws + 6401536);  // NT*64  dwords (128 bf16/row)
    uint2* epack  = (uint2*)(ws + 11521536);             // NE * 8B
    unsigned int* W1f = (unsigned int*)(ws + 14081536);  // 24576
    unsigned int* W2f = W1f + 24576;                     // 16384
    float* bs1 = (float*)(W2f + 16384);                  // 256
    float* bs2 = bs1 + 256;                              // 256

    // zero deg + sums + count
    hipMemsetAsync(ws, 0, (size_t)(80256 + 80000) * 4, stream);

    prep_w_kernel<<<162, 256, 0, stream>>>(wih1,whh1,bih1,bhh1,
                                           wih2,whh2,bih2,bhh2,
                                           W1f,W2f,bs1,bs2);
    histdeg_kernel<<<1024, 256, 0, stream>>>(dst, ew, deg, count);
    scan1_kernel<<<625, 128, 0, stream>>>(count, blocksum, deg);
    scan2_kernel<<<1, 1024, 0, stream>>>(blocksum, blockoff);
    scan3_kernel<<<625, 128, 0, stream>>>(count, blockoff, rowptr, cursor);
    reorder_kernel<<<1024, 256, 0, stream>>>(src, dst, ew, deg, cursor, epack);
    xconv_kernel<<<(NT*4+255)/256, 256, 0, stream>>>(X, Xb);

    // GCN layer 1: aggregate X (8ch) then GEMM+relu+stats, BN apply
    gather8_kernel<<<(NT+255)/256, 256, 0, stream>>>(rowptr, epack, (const uint4*)Xb, deg, agg8);
    gemm8relu_kernel<<<1024, 256, 0, stream>>>(agg8, w1, b1, y, sums);
    bnapply2_kernel<<<(NT*32+255)/256, 256, 0, stream>>>(y, xcat, 0, sums, g1, be1);

    // GCN layer 2: aggregate x1 (bf16, 64ch) then GEMM+relu+stats, BN apply
    gather64_kernel<<<2048, 256, 0, stream>>>(rowptr, epack, xcat, deg, agg2);
    gemm64relu_kernel<<<1024, 256, 0, stream>>>(agg2, w2, b2, y, sums + 128);
    bnapply2_kernel<<<(NT*32+255)/256, 256, 0, stream>>>(y, xcat, 32, sums + 128, g2, be2);

    // fused MFMA LSTM + skip features
    lstm_mfma_kernel<<<NNODES/16, 256, 0, stream>>>((const unsigned short*)xcat, W1f, W2f, bs1, bs2, out);
    sfeat_kernel<<<(NNODES*15+255)/256, 256, 0, stream>>>(X, out);
}

// Round 6
// 396.118 us; speedup vs baseline: 2.1383x; 1.0583x over previous
//
#include <hip/hip_runtime.h>
#include <hip/hip_bf16.h>
#include <math.h>

#define NNODES 10000
#define NT     80000
#define NE     1280000
#define NXCD   8

typedef __bf16 bf16x8 __attribute__((ext_vector_type(8)));
typedef float  f32x4  __attribute__((ext_vector_type(4)));

__device__ __forceinline__ float frcp(float x){ return __builtin_amdgcn_rcpf(x); }
__device__ __forceinline__ float fsig(float x){ return frcp(1.0f + __expf(-x)); }
__device__ __forceinline__ float ftanh(float x){ return 1.0f - 2.0f*frcp(1.0f + __expf(2.0f*x)); }
__device__ __forceinline__ float u2f(unsigned int u){ union{unsigned int u; float f;} c; c.u=u; return c.f; }
__device__ __forceinline__ unsigned short f2bu(float v){ __hip_bfloat16 h = __float2bfloat16(v); return *(unsigned short*)&h; }
__device__ __forceinline__ unsigned int pk2(float a, float b){ return (unsigned int)f2bu(a) | ((unsigned int)f2bu(b) << 16); }

// XCD id of the CU this block runs on (stable for block lifetime)
__device__ __forceinline__ int xcc_id() {
    unsigned int x;
    asm volatile("s_getreg_b32 %0, hwreg(HW_REG_XCC_ID, 0, 32)" : "=s"(x));
    return (int)(x & (NXCD-1));
}
__device__ __forceinline__ void atomf_wg(float* p, float v) {
    __hip_atomic_fetch_add(p, v, __ATOMIC_RELAXED, __HIP_MEMORY_SCOPE_WORKGROUP);
}
__device__ __forceinline__ int atomi_wg(int* p, int v) {
    return __hip_atomic_fetch_add(p, v, __ATOMIC_RELAXED, __HIP_MEMORY_SCOPE_WORKGROUP);
}

// ---------------- weight prep: pack LSTM weights into MFMA B-fragment order ---
__global__ __launch_bounds__(256) void prep_w_kernel(
    const float* __restrict__ wih1, const float* __restrict__ whh1,
    const float* __restrict__ bih1, const float* __restrict__ bhh1,
    const float* __restrict__ wih2, const float* __restrict__ whh2,
    const float* __restrict__ bih2, const float* __restrict__ bhh2,
    unsigned int* __restrict__ W1f, unsigned int* __restrict__ W2f,
    float* __restrict__ bs1, float* __restrict__ bs2)
{
    int gid = blockIdx.x*256 + threadIdx.x;
    if (gid < 24576) {
        int i = gid & 3, lane = (gid>>2)&63, rest = gid>>8;
        int ks = rest % 6; rest /= 6;
        int nt = rest & 3, w = rest >> 2;
        int gate = nt*64 + w*16 + (lane & 15);
        int k = ks*32 + ((lane>>4)&3)*8 + 2*i;
        float v0 = (k     < 128) ? wih1[gate*128 + k]       : whh1[gate*64 + (k-128)];
        float v1 = (k + 1 < 128) ? wih1[gate*128 + k + 1]   : whh1[gate*64 + (k+1-128)];
        W1f[gid] = pk2(v0, v1);
    } else if (gid < 24576 + 16384) {
        int r = gid - 24576;
        int i = r & 3, lane = (r>>2)&63, rest = r>>8;
        int ks = rest & 3; rest >>= 2;
        int nt = rest & 3, w = rest >> 2;
        int gate = nt*64 + w*16 + (lane & 15);
        int k = ks*32 + ((lane>>4)&3)*8 + 2*i;
        float v0 = (k     < 64) ? wih2[gate*64 + k]     : whh2[gate*64 + (k-64)];
        float v1 = (k + 1 < 64) ? wih2[gate*64 + k + 1] : whh2[gate*64 + (k+1-64)];
        W2f[r] = pk2(v0, v1);
    } else if (gid < 24576 + 16384 + 256) {
        int j = gid - (24576 + 16384); bs1[j] = bih1[j] + bhh1[j];
    } else if (gid < 24576 + 16384 + 512) {
        int j = gid - (24576 + 16384 + 256); bs2[j] = bih2[j] + bhh2[j];
    }
}

// per-XCD privatized histogram: deg8[xcd][d] += ew ; count8[xcd][d] += 1
// (workgroup-scope atomics execute in the local L2 -> no fabric RMW traffic)
__global__ __launch_bounds__(256) void histdeg_kernel(const int* __restrict__ dst,
                                                      const float* __restrict__ ew,
                                                      float* __restrict__ deg8,
                                                      int* __restrict__ count8)
{
    int xcd = xcc_id();
    float* degx = deg8 + (size_t)xcd*NT;
    int*   cntx = count8 + (size_t)xcd*NT;
    int gid = blockIdx.x*blockDim.x + threadIdx.x;
    int stride = gridDim.x*blockDim.x;
    for (int e = gid; e < NE; e += stride) {
        int d = dst[e];
        atomf_wg(&degx[d], ew[e]);
        atomi_wg(&cntx[d], 1);
    }
}

// ---- 3-phase parallel scan (625 blocks x 128) ----
// scan1: merge 8 copies -> counttot, dinv; per-block total
__global__ __launch_bounds__(128) void scan1_kernel(const int* __restrict__ count8,
                                                    const float* __restrict__ deg8,
                                                    int* __restrict__ counttot,
                                                    float* __restrict__ dinv,
                                                    int* __restrict__ blocksum)
{
    __shared__ int sm[128];
    int tid = threadIdx.x;
    int idx = blockIdx.x*128 + tid;
    int c = 0; float dg = 0.f;
    #pragma unroll
    for (int x = 0; x < NXCD; ++x) {
        c  += count8[(size_t)x*NT + idx];
        dg += deg8[(size_t)x*NT + idx];
    }
    counttot[idx] = c;
    dinv[idx] = rsqrtf(dg + 1.0f);
    sm[tid] = c;
    __syncthreads();
    #pragma unroll
    for (int off = 64; off > 0; off >>= 1) {
        if (tid < off) sm[tid] += sm[tid + off];
        __syncthreads();
    }
    if (tid == 0) blocksum[blockIdx.x] = sm[0];
}

__global__ __launch_bounds__(1024) void scan2_kernel(const int* __restrict__ blocksum,
                                                     int* __restrict__ blockoff)
{
    __shared__ int part[1024];
    int tid = threadIdx.x;
    int v = (tid < 625) ? blocksum[tid] : 0;
    part[tid] = v;
    __syncthreads();
    for (int off = 1; off < 1024; off <<= 1) {
        int t = (tid >= off) ? part[tid - off] : 0;
        __syncthreads();
        part[tid] += t;
        __syncthreads();
    }
    if (tid < 625) blockoff[tid] = part[tid] - v;
}

// scan3: rowptr + per-XCD sub-segment cursors
__global__ __launch_bounds__(128) void scan3_kernel(const int* __restrict__ counttot,
                                                    const int* __restrict__ count8,
                                                    const int* __restrict__ blockoff,
                                                    int* __restrict__ rowptr,
                                                    int* __restrict__ subcursor)
{
    __shared__ int part[128];
    int tid = threadIdx.x;
    int idx = blockIdx.x*128 + tid;
    int v = counttot[idx];
    part[tid] = v;
    __syncthreads();
    #pragma unroll
    for (int off = 1; off < 128; off <<= 1) {
        int t = (tid >= off) ? part[tid - off] : 0;
        __syncthreads();
        part[tid] += t;
        __syncthreads();
    }
    int ex = part[tid] - v + blockoff[blockIdx.x];
    rowptr[idx] = ex;
    int run = ex;
    #pragma unroll
    for (int x = 0; x < NXCD; ++x) {
        subcursor[(size_t)x*NT + idx] = run;
        run += count8[(size_t)x*NT + idx];
    }
    if (idx == 0) rowptr[NT] = NE;
}

// bucket edges by dst into this XCD's sub-segment (L2-local cursor atomics)
__global__ __launch_bounds__(256) void reorder_kernel(const int* __restrict__ src,
                                                      const int* __restrict__ dst,
                                                      const float* __restrict__ ew,
                                                      const float* __restrict__ dinv,
                                                      int* __restrict__ subcursor,
                                                      uint2* __restrict__ epack)
{
    int xcd = xcc_id();
    int* curx = subcursor + (size_t)xcd*NT;
    int gid = blockIdx.x*blockDim.x + threadIdx.x;
    int stride = gridDim.x*blockDim.x;
    for (int e = gid; e < NE; e += stride) {
        int d = dst[e], s = src[e];
        float nrm = ew[e] * dinv[s] * dinv[d];
        int pos = atomi_wg(&curx[d], 1);
        uint2 p; p.x = (unsigned int)s;
        union{float f; unsigned int u;} c; c.f = nrm; p.y = c.u;
        epack[pos] = p;
    }
}

// X f32 [NT,8] -> Xb bf16 (packed dwords, 4 per row)
__global__ __launch_bounds__(256) void xconv_kernel(const float* __restrict__ X,
                                                    unsigned int* __restrict__ Xb)
{
    int gid = blockIdx.x*256 + threadIdx.x;
    if (gid >= NT*4) return;
    float2 v = *(const float2*)&X[(size_t)gid*2];
    Xb[gid] = pk2(v.x, v.y);
}

// thread-per-dst 8-channel aggregation (L2-resident 1.28MB table)
__global__ __launch_bounds__(256) void gather8_kernel(const int* __restrict__ rowptr,
                                                      const uint2* __restrict__ epack,
                                                      const uint4* __restrict__ Xb,
                                                      const float* __restrict__ dinv,
                                                      float* __restrict__ agg8)
{
    int d = blockIdx.x*256 + threadIdx.x;
    if (d >= NT) return;
    int beg = rowptr[d], end = rowptr[d+1];
    float acc[8];
    #pragma unroll
    for (int k = 0; k < 8; ++k) acc[k] = 0.f;
    for (int i = beg; i < end; ++i) {
        uint2 p = epack[i];
        float nrm = u2f(p.y);
        uint4 xv = Xb[p.x];
        unsigned int um[4] = {xv.x, xv.y, xv.z, xv.w};
        #pragma unroll
        for (int m = 0; m < 4; ++m) {
            acc[2*m]   = fmaf(nrm, u2f(um[m] << 16),         acc[2*m]);
            acc[2*m+1] = fmaf(nrm, u2f(um[m] & 0xffff0000u), acc[2*m+1]);
        }
    }
    float dv = dinv[d], dv2 = dv*dv;
    uint4 xd = Xb[d];
    unsigned int ud[4] = {xd.x, xd.y, xd.z, xd.w};
    #pragma unroll
    for (int m = 0; m < 4; ++m) {
        acc[2*m]   = fmaf(dv2, u2f(ud[m] << 16),         acc[2*m]);
        acc[2*m+1] = fmaf(dv2, u2f(ud[m] & 0xffff0000u), acc[2*m+1]);
    }
    float4* o = (float4*)&agg8[(size_t)d*8];
    o[0] = make_float4(acc[0], acc[1], acc[2], acc[3]);
    o[1] = make_float4(acc[4], acc[5], acc[6], acc[7]);
}

// y = relu(agg8 @ w1 + b1) -> bf16; fused BN stats
__global__ __launch_bounds__(256) void gemm8relu_kernel(const float* __restrict__ agg8,
                                                        const float* __restrict__ w,
                                                        const float* __restrict__ b,
                                                        unsigned short* __restrict__ y,
                                                        float* __restrict__ sums)
{
    __shared__ float ws[512];
    for (int i = threadIdx.x; i < 512; i += 256) ws[i] = w[i];
    __syncthreads();
    int c = threadIdx.x & 63, wq = threadIdx.x >> 6;
    float bc = b[c];
    float s = 0.f, q = 0.f;
    for (int r = blockIdx.x*4 + wq; r < NT; r += gridDim.x*4) {
        const float4* ar = (const float4*)&agg8[(size_t)r*8];
        float4 a0 = ar[0], a1 = ar[1];
        float v = bc;
        v = fmaf(a0.x, ws[0*64+c], v); v = fmaf(a0.y, ws[1*64+c], v);
        v = fmaf(a0.z, ws[2*64+c], v); v = fmaf(a0.w, ws[3*64+c], v);
        v = fmaf(a1.x, ws[4*64+c], v); v = fmaf(a1.y, ws[5*64+c], v);
        v = fmaf(a1.z, ws[6*64+c], v); v = fmaf(a1.w, ws[7*64+c], v);
        v = fmaxf(v, 0.f);
        y[(size_t)r*64 + c] = f2bu(v);
        s += v; q += v*v;
    }
    __shared__ float sm[256], sq[256];
    sm[threadIdx.x] = s; sq[threadIdx.x] = q;
    __syncthreads();
    if (threadIdx.x < 64) {
        atomicAdd(&sums[c],      sm[c] + sm[c+64] + sm[c+128] + sm[c+192]);
        atomicAdd(&sums[64 + c], sq[c] + sq[c+64] + sq[c+128] + sq[c+192]);
    }
}

// BN apply (2 channels per thread) -> bf16 xcat dword column segment
__global__ __launch_bounds__(256) void bnapply2_kernel(const unsigned short* __restrict__ y,
                                                       unsigned int* __restrict__ xcat,
                                                       int coloffd,
                                                       const float* __restrict__ sums,
                                                       const float* __restrict__ g,
                                                       const float* __restrict__ be)
{
    int gid = blockIdx.x*256 + threadIdx.x;
    if (gid >= NT*32) return;
    int c2 = gid & 31, n = gid >> 5;
    int c0 = 2*c2, c1 = c0 + 1;
    unsigned int yy = *(const unsigned int*)&y[(size_t)n*64 + c0];
    float v0 = u2f(yy << 16), v1 = u2f(yy & 0xffff0000u);
    float mu0 = sums[c0] * (1.0f/NT), mu1 = sums[c1] * (1.0f/NT);
    float va0 = sums[64+c0] * (1.0f/NT) - mu0*mu0;
    float va1 = sums[64+c1] * (1.0f/NT) - mu1*mu1;
    v0 = (v0 - mu0) * rsqrtf(va0 + 1e-5f) * g[c0] + be[c0];
    v1 = (v1 - mu1) * rsqrtf(va1 + 1e-5f) * g[c1] + be[c1];
    xcat[(size_t)n*64 + coloffd + c2] = pk2(v0, v1);
}

// 64-ch bf16 gather: 4 edges per wave (16-lane groups, uint2 = 4ch per lane)
// result written bf16-packed into xcat cols 32:64 (agg2 alias)
__global__ __launch_bounds__(256) void gather64_kernel(const int* __restrict__ rowptr,
                                                       const uint2* __restrict__ epack,
                                                       unsigned int* __restrict__ xcat,
                                                       const float* __restrict__ dinv)
{
    int lane = threadIdx.x & 63;
    int grp = lane >> 4, l = lane & 15;       // edge slot, channel quad (4ch = 2 dwords)
    int gwave = blockIdx.x*4 + (threadIdx.x >> 6);
    int nwaves = gridDim.x*4;
    for (int d = gwave; d < NT; d += nwaves) {
        int beg = rowptr[d], end = rowptr[d+1];
        float a0 = 0.f, a1 = 0.f, a2 = 0.f, a3 = 0.f;
        for (int i = beg; i < end; i += 4) {
            int idx = i + grp;
            bool valid = idx < end;
            uint2 p = epack[valid ? idx : (end - 1)];
            float nrm = valid ? u2f(p.y) : 0.f;
            uint2 xv = *(const uint2*)&xcat[(size_t)p.x*64 + 2*l];
            a0 = fmaf(nrm, u2f(xv.x << 16),         a0);
            a1 = fmaf(nrm, u2f(xv.x & 0xffff0000u), a1);
            a2 = fmaf(nrm, u2f(xv.y << 16),         a2);
            a3 = fmaf(nrm, u2f(xv.y & 0xffff0000u), a3);
        }
        a0 += __shfl_xor(a0, 16); a1 += __shfl_xor(a1, 16);
        a2 += __shfl_xor(a2, 16); a3 += __shfl_xor(a3, 16);
        a0 += __shfl_xor(a0, 32); a1 += __shfl_xor(a1, 32);
        a2 += __shfl_xor(a2, 32); a3 += __shfl_xor(a3, 32);
        if (grp == 0) {
            float dv = dinv[d], dv2 = dv*dv;
            uint2 xd = *(const uint2*)&xcat[(size_t)d*64 + 2*l];
            a0 = fmaf(dv2, u2f(xd.x << 16),         a0);
            a1 = fmaf(dv2, u2f(xd.x & 0xffff0000u), a1);
            a2 = fmaf(dv2, u2f(xd.y << 16),         a2);
            a3 = fmaf(dv2, u2f(xd.y & 0xffff0000u), a3);
            *(uint2*)&xcat[(size_t)d*64 + 32 + 2*l] = make_uint2(pk2(a0, a1), pk2(a2, a3));
        }
    }
}

// y2 = relu(agg2(bf16, xcat cols 32:64) @ w2 + b2) -> bf16; fused BN stats
__global__ __launch_bounds__(256) void gemm64relu_kernel(const unsigned int* __restrict__ xcat,
                                                         const float* __restrict__ w,
                                                         const float* __restrict__ b,
                                                         unsigned short* __restrict__ y,
                                                         float* __restrict__ sums)
{
    __shared__ float ws[4096];
    for (int i = threadIdx.x; i < 4096; i += 256) ws[i] = w[i];
    __syncthreads();
    int c = threadIdx.x & 63, wq = threadIdx.x >> 6;
    float bc = b[c];
    float s = 0.f, q = 0.f;
    for (int r = blockIdx.x*4 + wq; r < NT; r += gridDim.x*4) {
        const uint4* xr = (const uint4*)&xcat[(size_t)r*64 + 32];
        float v = bc;
        #pragma unroll
        for (int kk = 0; kk < 8; ++kk) {
            uint4 xv = xr[kk];
            unsigned int um[4] = {xv.x, xv.y, xv.z, xv.w};
            #pragma unroll
            for (int m = 0; m < 4; ++m) {
                int k0 = kk*8 + m*2;
                v = fmaf(u2f(um[m] << 16),         ws[k0*64 + c],     v);
                v = fmaf(u2f(um[m] & 0xffff0000u), ws[(k0+1)*64 + c], v);
            }
        }
        v = fmaxf(v, 0.f);
        y[(size_t)r*64 + c] = f2bu(v);
        s += v; q += v*v;
    }
    __shared__ float sm[256], sq[256];
    sm[threadIdx.x] = s; sq[threadIdx.x] = q;
    __syncthreads();
    if (threadIdx.x < 64) {
        atomicAdd(&sums[c],      sm[c] + sm[c+64] + sm[c+128] + sm[c+192]);
        atomicAdd(&sums[64 + c], sq[c] + sq[c+64] + sq[c+128] + sq[c+192]);
    }
}

// ---------------- fused 2-layer 8-step LSTM on MFMA (3 barriers/step) --------
// LDS row: 0:128 x(t) | 128:192 h1 | 192:256 h2 buf0 | 256:320 h2 buf1
#define LROW 328
__global__ __launch_bounds__(256, 2) void lstm_mfma_kernel(
    const unsigned short* __restrict__ xcat,
    const unsigned int* __restrict__ W1f, const unsigned int* __restrict__ W2f,
    const float* __restrict__ bs1, const float* __restrict__ bs2,
    float* __restrict__ out)
{
    __shared__ __align__(16) unsigned short xb[16][LROW];
    const int tid  = threadIdx.x;
    const int w    = tid >> 6, lane = tid & 63;
    const int lr   = lane & 15;
    const int lg   = lane >> 4;
    const int nb0  = blockIdx.x * 16;

    uint4 w1f[4][6], w2f[4][4];
    {
        const uint4* p1 = (const uint4*)W1f;
        #pragma unroll
        for (int nt = 0; nt < 4; ++nt)
            #pragma unroll
            for (int ks = 0; ks < 6; ++ks)
                w1f[nt][ks] = p1[((w*4 + nt)*6 + ks)*64 + lane];
        const uint4* p2 = (const uint4*)W2f;
        #pragma unroll
        for (int nt = 0; nt < 4; ++nt)
            #pragma unroll
            for (int ks = 0; ks < 4; ++ks)
                w2f[nt][ks] = p2[((w*4 + nt)*4 + ks)*64 + lane];
    }
    float b1v[4], b2v[4];
    #pragma unroll
    for (int nt = 0; nt < 4; ++nt) {
        b1v[nt] = bs1[nt*64 + w*16 + lr];
        b2v[nt] = bs2[nt*64 + w*16 + lr];
    }

    // zero h1 + both h2 buffers (cols 128:320)
    for (int i = tid; i < 16*24; i += 256) {
        int n = i / 24, k0 = 128 + (i % 24)*8;
        uint4 z; z.x = z.y = z.z = z.w = 0u;
        *(uint4*)&xb[n][k0] = z;
    }
    // stage x(0)
    {
        int n = tid >> 4, k0 = (tid & 15)*8;
        *(uint4*)&xb[n][k0] = *(const uint4*)&xcat[((size_t)(nb0 + n))*128 + k0];
    }
    float c1[4] = {0.f,0.f,0.f,0.f}, c2[4] = {0.f,0.f,0.f,0.f};

    for (int step = 0; step < 8; ++step) {
        __syncthreads();                    // B_a: x(t)/h1(t-1)/h2(t-1) visible

        // ---- layer 1: A = cols 0:192 ----
        f32x4 acc[4];
        #pragma unroll
        for (int nt = 0; nt < 4; ++nt) { acc[nt][0]=0.f; acc[nt][1]=0.f; acc[nt][2]=0.f; acc[nt][3]=0.f; }
        #pragma unroll
        for (int ks = 0; ks < 6; ++ks) {
            bf16x8 a = *(const bf16x8*)&xb[lr][ks*32 + lg*8];
            #pragma unroll
            for (int nt = 0; nt < 4; ++nt) {
                union { uint4 u; bf16x8 v; } wb; wb.u = w1f[nt][ks];
                acc[nt] = __builtin_amdgcn_mfma_f32_16x16x32_bf16(a, wb.v, acc[nt], 0, 0, 0);
            }
        }
        __syncthreads();                    // B_b: L1 reads done (x + h1 WAR safe)

        // write h1(t); stage x(t+1)
        #pragma unroll
        for (int r = 0; r < 4; ++r) {
            float zi = acc[0][r] + b1v[0];
            float zf = acc[1][r] + b1v[1];
            float zg = acc[2][r] + b1v[2];
            float zo = acc[3][r] + b1v[3];
            float c  = fsig(zf)*c1[r] + fsig(zi)*ftanh(zg);
            c1[r] = c;
            float hv = fsig(zo)*ftanh(c);
            int node = lg*4 + r;
            xb[node][128 + w*16 + lr] = f2bu(hv);
            if (step == 7) out[(size_t)(nb0 + node)*143 + w*16 + lr] = hv;
        }
        if (step < 7) {
            int n = tid >> 4, k0 = (tid & 15)*8;
            *(uint4*)&xb[n][k0] =
                *(const uint4*)&xcat[((size_t)((step+1)*NNODES + nb0 + n))*128 + k0];
        }
        __syncthreads();                    // B_c: h1(t) visible for L2

        // ---- layer 2: A = [h1 | h2 prev buf] ----
        int rb = 192 + 64*((step+1)&1);     // read buffer (prev parity)
        int wb2 = 192 + 64*(step&1);        // write buffer
        #pragma unroll
        for (int nt = 0; nt < 4; ++nt) { acc[nt][0]=0.f; acc[nt][1]=0.f; acc[nt][2]=0.f; acc[nt][3]=0.f; }
        #pragma unroll
        for (int ks = 0; ks < 2; ++ks) {
            bf16x8 a = *(const bf16x8*)&xb[lr][128 + ks*32 + lg*8];
            #pragma unroll
            for (int nt = 0; nt < 4; ++nt) {
                union { uint4 u; bf16x8 v; } wbv; wbv.u = w2f[nt][ks];
                acc[nt] = __builtin_amdgcn_mfma_f32_16x16x32_bf16(a, wbv.v, acc[nt], 0, 0, 0);
            }
        }
        #pragma unroll
        for (int ks = 0; ks < 2; ++ks) {
            bf16x8 a = *(const bf16x8*)&xb[lr][rb + ks*32 + lg*8];
            #pragma unroll
            for (int nt = 0; nt < 4; ++nt) {
                union { uint4 u; bf16x8 v; } wbv; wbv.u = w2f[nt][2+ks];
                acc[nt] = __builtin_amdgcn_mfma_f32_16x16x32_bf16(a, wbv.v, acc[nt], 0, 0, 0);
            }
        }
        // write h2(t) into the other buffer (no barrier needed: disjoint region)
        #pragma unroll
        for (int r = 0; r < 4; ++r) {
            float zi = acc[0][r] + b2v[0];
            float zf = acc[1][r] + b2v[1];
            float zg = acc[2][r] + b2v[2];
            float zo = acc[3][r] + b2v[3];
            float c  = fsig(zf)*c2[r] + fsig(zi)*ftanh(zg);
            c2[r] = c;
            float hv = fsig(zo)*ftanh(c);
            int node = lg*4 + r;
            xb[node][wb2 + w*16 + lr] = f2bu(hv);
            if (step == 7) out[(size_t)(nb0 + node)*143 + 64 + w*16 + lr] = hv;
        }
    }
}

__global__ __launch_bounds__(256) void sfeat_kernel(const float* __restrict__ X,
                                                    float* __restrict__ out)
{
    int gid = blockIdx.x*256 + threadIdx.x;
    if (gid >= NNODES*15) return;
    int n = gid/15, i = gid%15;
    float v = (i < 8) ? X[(size_t)n*8 + i]
                      : X[((size_t)(i-7)*NNODES + n)*8 + 7];
    out[(size_t)n*143 + 128 + i] = v;
}

extern "C" void kernel_launch(void* const* d_in, const int* in_sizes, int n_in,
                              void* d_out, int out_size, void* d_ws, size_t ws_size,
                              hipStream_t stream)
{
    (void)in_sizes; (void)n_in; (void)out_size; (void)ws_size;
    const float* X    = (const float*)d_in[0];
    const int*   ei   = (const int*)d_in[1];
    const float* ew   = (const float*)d_in[2];
    const float* w1   = (const float*)d_in[3];
    const float* b1   = (const float*)d_in[4];
    const float* w2   = (const float*)d_in[5];
    const float* b2   = (const float*)d_in[6];
    const float* g1   = (const float*)d_in[7];
    const float* be1  = (const float*)d_in[8];
    const float* g2   = (const float*)d_in[9];
    const float* be2  = (const float*)d_in[10];
    const float* wih1 = (const float*)d_in[11];
    const float* whh1 = (const float*)d_in[12];
    const float* bih1 = (const float*)d_in[13];
    const float* bhh1 = (const float*)d_in[14];
    const float* wih2 = (const float*)d_in[15];
    const float* whh2 = (const float*)d_in[16];
    const float* bih2 = (const float*)d_in[17];
    const float* bhh2 = (const float*)d_in[18];
    float* out = (float*)d_out;
    float* ws  = (float*)d_ws;

    const int* src = ei;
    const int* dst = ei + NE;

    // workspace layout (word offsets)
    float* deg8     = ws;                                //  8*NT  [zeroed]
    int*   count8   = (int*)(ws + 640000);               //  8*NT  [zeroed]
    float* sums     = ws + 1280000;                      //  256   [zeroed]
    float* dinv     = ws + 1280256;                      //  NT
    int*   counttot = (int*)(ws + 1360256);              //  NT
    int*   rowptr   = (int*)(ws + 1440256);              //  NT+1 (pad to +4)
    int*   subcursor= (int*)(ws + 1520260);              //  8*NT
    int*   blocksum = (int*)(ws + 2160260);              //  625
    int*   blockoff = (int*)(ws + 2160885);              //  625 (pad to 2161536)
    unsigned int* Xb   = (unsigned int*)(ws + 2161536);  //  NT*4
    float*        agg8 = ws + 2481536;                   //  NT*8
    unsigned short* y  = (unsigned short*)(ws + 3121536);//  NT*64 bf16 (NT*32 dw)
    unsigned int* xcat = (unsigned int*)(ws + 5681536);  //  NT*64 dw (x1|x2, agg2 alias)
    uint2* epack  = (uint2*)(ws + 10801536);             //  NE*2 dw
    unsigned int* W1f = (unsigned int*)(ws + 13361536);  //  24576
    unsigned int* W2f = W1f + 24576;                     //  16384
    float* bs1 = (float*)(W2f + 16384);                  //  256
    float* bs2 = bs1 + 256;                              //  256

    // zero deg8 + count8 + sums
    hipMemsetAsync(ws, 0, (size_t)(1280256) * 4, stream);

    prep_w_kernel<<<162, 256, 0, stream>>>(wih1,whh1,bih1,bhh1,
                                           wih2,whh2,bih2,bhh2,
                                           W1f,W2f,bs1,bs2);
    histdeg_kernel<<<1024, 256, 0, stream>>>(dst, ew, deg8, count8);
    scan1_kernel<<<625, 128, 0, stream>>>(count8, deg8, counttot, dinv, blocksum);
    scan2_kernel<<<1, 1024, 0, stream>>>(blocksum, blockoff);
    scan3_kernel<<<625, 128, 0, stream>>>(counttot, count8, blockoff, rowptr, subcursor);
    reorder_kernel<<<1024, 256, 0, stream>>>(src, dst, ew, dinv, subcursor, epack);
    xconv_kernel<<<(NT*4+255)/256, 256, 0, stream>>>(X, Xb);

    // GCN layer 1
    gather8_kernel<<<(NT+255)/256, 256, 0, stream>>>(rowptr, epack, (const uint4*)Xb, dinv, agg8);
    gemm8relu_kernel<<<1024, 256, 0, stream>>>(agg8, w1, b1, y, sums);
    bnapply2_kernel<<<(NT*32+255)/256, 256, 0, stream>>>(y, xcat, 0, sums, g1, be1);

    // GCN layer 2 (aggregate into xcat cols 32:64, then GEMM+relu+stats, BN)
    gather64_kernel<<<2048, 256, 0, stream>>>(rowptr, epack, xcat, dinv);
    gemm64relu_kernel<<<1024, 256, 0, stream>>>(xcat, w2, b2, y, sums + 128);
    bnapply2_kernel<<<(NT*32+255)/256, 256, 0, stream>>>(y, xcat, 32, sums + 128, g2, be2);

    // fused MFMA LSTM + skip features
    lstm_mfma_kernel<<<NNODES/16, 256, 0, stream>>>((const unsigned short*)xcat, W1f, W2f, bs1, bs2, out);
    sfeat_kernel<<<(NNODES*15+255)/256, 256, 0, stream>>>(X, out);
}

// Round 7
// 335.416 us; speedup vs baseline: 2.5253x; 1.1810x over previous
//
#include <hip/hip_runtime.h>
#include <hip/hip_bf16.h>
#include <math.h>

#define NNODES 10000
#define NT     80000
#define NE     1280000

typedef __bf16 bf16x8 __attribute__((ext_vector_type(8)));
typedef float  f32x4  __attribute__((ext_vector_type(4)));

__device__ __forceinline__ float frcp(float x){ return __builtin_amdgcn_rcpf(x); }
__device__ __forceinline__ float fsig(float x){ return frcp(1.0f + __expf(-x)); }
__device__ __forceinline__ float ftanh(float x){ return 1.0f - 2.0f*frcp(1.0f + __expf(2.0f*x)); }
__device__ __forceinline__ float u2f(unsigned int u){ union{unsigned int u; float f;} c; c.u=u; return c.f; }
__device__ __forceinline__ unsigned short f2bu(float v){ __hip_bfloat16 h = __float2bfloat16(v); return *(unsigned short*)&h; }
__device__ __forceinline__ unsigned int pk2(float a, float b){ return (unsigned int)f2bu(a) | ((unsigned int)f2bu(b) << 16); }

// ---------------- weight prep: pack LSTM weights into MFMA B-fragment order ---
__global__ __launch_bounds__(256) void prep_w_kernel(
    const float* __restrict__ wih1, const float* __restrict__ whh1,
    const float* __restrict__ bih1, const float* __restrict__ bhh1,
    const float* __restrict__ wih2, const float* __restrict__ whh2,
    const float* __restrict__ bih2, const float* __restrict__ bhh2,
    unsigned int* __restrict__ W1f, unsigned int* __restrict__ W2f,
    float* __restrict__ bs1, float* __restrict__ bs2)
{
    int gid = blockIdx.x*256 + threadIdx.x;
    if (gid < 24576) {
        int i = gid & 3, lane = (gid>>2)&63, rest = gid>>8;
        int ks = rest % 6; rest /= 6;
        int nt = rest & 3, w = rest >> 2;
        int gate = nt*64 + w*16 + (lane & 15);
        int k = ks*32 + ((lane>>4)&3)*8 + 2*i;
        float v0 = (k     < 128) ? wih1[gate*128 + k]       : whh1[gate*64 + (k-128)];
        float v1 = (k + 1 < 128) ? wih1[gate*128 + k + 1]   : whh1[gate*64 + (k+1-128)];
        W1f[gid] = pk2(v0, v1);
    } else if (gid < 24576 + 16384) {
        int r = gid - 24576;
        int i = r & 3, lane = (r>>2)&63, rest = r>>8;
        int ks = rest & 3; rest >>= 2;
        int nt = rest & 3, w = rest >> 2;
        int gate = nt*64 + w*16 + (lane & 15);
        int k = ks*32 + ((lane>>4)&3)*8 + 2*i;
        float v0 = (k     < 64) ? wih2[gate*64 + k]     : whh2[gate*64 + (k-64)];
        float v1 = (k + 1 < 64) ? wih2[gate*64 + k + 1] : whh2[gate*64 + (k+1-64)];
        W2f[r] = pk2(v0, v1);
    } else if (gid < 24576 + 16384 + 256) {
        int j = gid - (24576 + 16384); bs1[j] = bih1[j] + bhh1[j];
    } else if (gid < 24576 + 16384 + 512) {
        int j = gid - (24576 + 16384 + 256); bs2[j] = bih2[j] + bhh2[j];
    }
}

// one packed 64-bit atomic per edge: hist[d] += (1<<48) | fixpoint(ew, 2^-32)
// (count in [48,64); deg as 48-bit fixed point, max 2^38 -- no overflow)
__global__ __launch_bounds__(256) void histdeg_kernel(const int* __restrict__ dst,
                                                      const float* __restrict__ ew,
                                                      unsigned long long* __restrict__ hist)
{
    int gid = blockIdx.x*blockDim.x + threadIdx.x;
    int stride = gridDim.x*blockDim.x;
    for (int e = gid; e < NE; e += stride) {
        int d = dst[e];
        unsigned long long v = (1ULL << 48)
            | (unsigned long long)(ew[e] * 4294967296.0f);
        atomicAdd(&hist[d], v);
    }
}

// ---- 3-phase parallel scan (625 blocks x 128) ----
// scan1: unpack hist -> counttot, dinv; per-block total
__global__ __launch_bounds__(128) void scan1_kernel(const unsigned long long* __restrict__ hist,
                                                    int* __restrict__ counttot,
                                                    float* __restrict__ dinv,
                                                    int* __restrict__ blocksum)
{
    __shared__ int sm[128];
    int tid = threadIdx.x;
    int idx = blockIdx.x*128 + tid;
    unsigned long long v = hist[idx];
    int c = (int)(v >> 48);
    float dg = (float)(v & 0x0000FFFFFFFFFFFFULL) * (1.0f/4294967296.0f);
    counttot[idx] = c;
    dinv[idx] = rsqrtf(dg + 1.0f);
    sm[tid] = c;
    __syncthreads();
    #pragma unroll
    for (int off = 64; off > 0; off >>= 1) {
        if (tid < off) sm[tid] += sm[tid + off];
        __syncthreads();
    }
    if (tid == 0) blocksum[blockIdx.x] = sm[0];
}

__global__ __launch_bounds__(1024) void scan2_kernel(const int* __restrict__ blocksum,
                                                     int* __restrict__ blockoff)
{
    __shared__ int part[1024];
    int tid = threadIdx.x;
    int v = (tid < 625) ? blocksum[tid] : 0;
    part[tid] = v;
    __syncthreads();
    for (int off = 1; off < 1024; off <<= 1) {
        int t = (tid >= off) ? part[tid - off] : 0;
        __syncthreads();
        part[tid] += t;
        __syncthreads();
    }
    if (tid < 625) blockoff[tid] = part[tid] - v;
}

__global__ __launch_bounds__(128) void scan3_kernel(const int* __restrict__ counttot,
                                                    const int* __restrict__ blockoff,
                                                    int* __restrict__ rowptr,
                                                    int* __restrict__ cursor)
{
    __shared__ int part[128];
    int tid = threadIdx.x;
    int idx = blockIdx.x*128 + tid;
    int v = counttot[idx];
    part[tid] = v;
    __syncthreads();
    #pragma unroll
    for (int off = 1; off < 128; off <<= 1) {
        int t = (tid >= off) ? part[tid - off] : 0;
        __syncthreads();
        part[tid] += t;
        __syncthreads();
    }
    int ex = part[tid] - v + blockoff[blockIdx.x];
    rowptr[idx] = ex;
    cursor[idx] = ex;
    if (idx == 0) rowptr[NT] = NE;
}

// bucket edges by dst: epack[pos] = (src, norm), norm = ew*dinv[s]*dinv[d]
__global__ __launch_bounds__(256) void reorder_kernel(const int* __restrict__ src,
                                                      const int* __restrict__ dst,
                                                      const float* __restrict__ ew,
                                                      const float* __restrict__ dinv,
                                                      int* __restrict__ cursor,
                                                      uint2* __restrict__ epack)
{
    int gid = blockIdx.x*blockDim.x + threadIdx.x;
    int stride = gridDim.x*blockDim.x;
    for (int e = gid; e < NE; e += stride) {
        int d = dst[e], s = src[e];
        float nrm = ew[e] * dinv[s] * dinv[d];
        int pos = atomicAdd(&cursor[d], 1);
        uint2 p; p.x = (unsigned int)s;
        union{float f; unsigned int u;} c; c.f = nrm; p.y = c.u;
        epack[pos] = p;
    }
}

// X f32 [NT,8] -> Xb bf16 (packed dwords, 4 per row)
__global__ __launch_bounds__(256) void xconv_kernel(const float* __restrict__ X,
                                                    unsigned int* __restrict__ Xb)
{
    int gid = blockIdx.x*256 + threadIdx.x;
    if (gid >= NT*4) return;
    float2 v = *(const float2*)&X[(size_t)gid*2];
    Xb[gid] = pk2(v.x, v.y);
}

// thread-per-dst 8-channel aggregation (L2-resident 1.28MB table)
__global__ __launch_bounds__(256) void gather8_kernel(const int* __restrict__ rowptr,
                                                      const uint2* __restrict__ epack,
                                                      const uint4* __restrict__ Xb,
                                                      const float* __restrict__ dinv,
                                                      float* __restrict__ agg8)
{
    int d = blockIdx.x*256 + threadIdx.x;
    if (d >= NT) return;
    int beg = rowptr[d], end = rowptr[d+1];
    float acc[8];
    #pragma unroll
    for (int k = 0; k < 8; ++k) acc[k] = 0.f;
    for (int i = beg; i < end; ++i) {
        uint2 p = epack[i];
        float nrm = u2f(p.y);
        uint4 xv = Xb[p.x];
        unsigned int um[4] = {xv.x, xv.y, xv.z, xv.w};
        #pragma unroll
        for (int m = 0; m < 4; ++m) {
            acc[2*m]   = fmaf(nrm, u2f(um[m] << 16),         acc[2*m]);
            acc[2*m+1] = fmaf(nrm, u2f(um[m] & 0xffff0000u), acc[2*m+1]);
        }
    }
    float dv = dinv[d], dv2 = dv*dv;
    uint4 xd = Xb[d];
    unsigned int ud[4] = {xd.x, xd.y, xd.z, xd.w};
    #pragma unroll
    for (int m = 0; m < 4; ++m) {
        acc[2*m]   = fmaf(dv2, u2f(ud[m] << 16),         acc[2*m]);
        acc[2*m+1] = fmaf(dv2, u2f(ud[m] & 0xffff0000u), acc[2*m+1]);
    }
    float4* o = (float4*)&agg8[(size_t)d*8];
    o[0] = make_float4(acc[0], acc[1], acc[2], acc[3]);
    o[1] = make_float4(acc[4], acc[5], acc[6], acc[7]);
}

// y = relu(agg8 @ w1 + b1) -> bf16; fused BN stats
__global__ __launch_bounds__(256) void gemm8relu_kernel(const float* __restrict__ agg8,
                                                        const float* __restrict__ w,
                                                        const float* __restrict__ b,
                                                        unsigned short* __restrict__ y,
                                                        float* __restrict__ sums)
{
    __shared__ float ws[512];
    for (int i = threadIdx.x; i < 512; i += 256) ws[i] = w[i];
    __syncthreads();
    int c = threadIdx.x & 63, wq = threadIdx.x >> 6;
    float bc = b[c];
    float s = 0.f, q = 0.f;
    for (int r = blockIdx.x*4 + wq; r < NT; r += gridDim.x*4) {
        const float4* ar = (const float4*)&agg8[(size_t)r*8];
        float4 a0 = ar[0], a1 = ar[1];
        float v = bc;
        v = fmaf(a0.x, ws[0*64+c], v); v = fmaf(a0.y, ws[1*64+c], v);
        v = fmaf(a0.z, ws[2*64+c], v); v = fmaf(a0.w, ws[3*64+c], v);
        v = fmaf(a1.x, ws[4*64+c], v); v = fmaf(a1.y, ws[5*64+c], v);
        v = fmaf(a1.z, ws[6*64+c], v); v = fmaf(a1.w, ws[7*64+c], v);
        v = fmaxf(v, 0.f);
        y[(size_t)r*64 + c] = f2bu(v);
        s += v; q += v*v;
    }
    __shared__ float sm[256], sq[256];
    sm[threadIdx.x] = s; sq[threadIdx.x] = q;
    __syncthreads();
    if (threadIdx.x < 64) {
        atomicAdd(&sums[c],      sm[c] + sm[c+64] + sm[c+128] + sm[c+192]);
        atomicAdd(&sums[64 + c], sq[c] + sq[c+64] + sq[c+128] + sq[c+192]);
    }
}

// BN apply (2 channels per thread) -> bf16 xcat dword column segment
__global__ __launch_bounds__(256) void bnapply2_kernel(const unsigned short* __restrict__ y,
                                                       unsigned int* __restrict__ xcat,
                                                       int coloffd,
                                                       const float* __restrict__ sums,
                                                       const float* __restrict__ g,
                                                       const float* __restrict__ be)
{
    int gid = blockIdx.x*256 + threadIdx.x;
    if (gid >= NT*32) return;
    int c2 = gid & 31, n = gid >> 5;
    int c0 = 2*c2, c1 = c0 + 1;
    unsigned int yy = *(const unsigned int*)&y[(size_t)n*64 + c0];
    float v0 = u2f(yy << 16), v1 = u2f(yy & 0xffff0000u);
    float mu0 = sums[c0] * (1.0f/NT), mu1 = sums[c1] * (1.0f/NT);
    float va0 = sums[64+c0] * (1.0f/NT) - mu0*mu0;
    float va1 = sums[64+c1] * (1.0f/NT) - mu1*mu1;
    v0 = (v0 - mu0) * rsqrtf(va0 + 1e-5f) * g[c0] + be[c0];
    v1 = (v1 - mu1) * rsqrtf(va1 + 1e-5f) * g[c1] + be[c1];
    xcat[(size_t)n*64 + coloffd + c2] = pk2(v0, v1);
}

// 64-ch bf16 gather: 4 edges per wave (16-lane groups, uint2 = 4ch per lane)
// result written bf16-packed into xcat cols 32:64 (agg2 alias)
__global__ __launch_bounds__(256) void gather64_kernel(const int* __restrict__ rowptr,
                                                       const uint2* __restrict__ epack,
                                                       unsigned int* __restrict__ xcat,
                                                       const float* __restrict__ dinv)
{
    int lane = threadIdx.x & 63;
    int grp = lane >> 4, l = lane & 15;       // edge slot, channel quad (4ch = 2 dwords)
    int gwave = blockIdx.x*4 + (threadIdx.x >> 6);
    int nwaves = gridDim.x*4;
    for (int d = gwave; d < NT; d += nwaves) {
        int beg = rowptr[d], end = rowptr[d+1];
        float a0 = 0.f, a1 = 0.f, a2 = 0.f, a3 = 0.f;
        for (int i = beg; i < end; i += 4) {
            int idx = i + grp;
            bool valid = idx < end;
            uint2 p = epack[valid ? idx : (end - 1)];
            float nrm = valid ? u2f(p.y) : 0.f;
            uint2 xv = *(const uint2*)&xcat[(size_t)p.x*64 + 2*l];
            a0 = fmaf(nrm, u2f(xv.x << 16),         a0);
            a1 = fmaf(nrm, u2f(xv.x & 0xffff0000u), a1);
            a2 = fmaf(nrm, u2f(xv.y << 16),         a2);
            a3 = fmaf(nrm, u2f(xv.y & 0xffff0000u), a3);
        }
        a0 += __shfl_xor(a0, 16); a1 += __shfl_xor(a1, 16);
        a2 += __shfl_xor(a2, 16); a3 += __shfl_xor(a3, 16);
        a0 += __shfl_xor(a0, 32); a1 += __shfl_xor(a1, 32);
        a2 += __shfl_xor(a2, 32); a3 += __shfl_xor(a3, 32);
        if (grp == 0) {
            float dv = dinv[d], dv2 = dv*dv;
            uint2 xd = *(const uint2*)&xcat[(size_t)d*64 + 2*l];
            a0 = fmaf(dv2, u2f(xd.x << 16),         a0);
            a1 = fmaf(dv2, u2f(xd.x & 0xffff0000u), a1);
            a2 = fmaf(dv2, u2f(xd.y << 16),         a2);
            a3 = fmaf(dv2, u2f(xd.y & 0xffff0000u), a3);
            *(uint2*)&xcat[(size_t)d*64 + 32 + 2*l] = make_uint2(pk2(a0, a1), pk2(a2, a3));
        }
    }
}

// y2 = relu(agg2(bf16, xcat cols 32:64) @ w2 + b2) -> bf16; fused BN stats
__global__ __launch_bounds__(256) void gemm64relu_kernel(const unsigned int* __restrict__ xcat,
                                                         const float* __restrict__ w,
                                                         const float* __restrict__ b,
                                                         unsigned short* __restrict__ y,
                                                         float* __restrict__ sums)
{
    __shared__ float ws[4096];
    for (int i = threadIdx.x; i < 4096; i += 256) ws[i] = w[i];
    __syncthreads();
    int c = threadIdx.x & 63, wq = threadIdx.x >> 6;
    float bc = b[c];
    float s = 0.f, q = 0.f;
    for (int r = blockIdx.x*4 + wq; r < NT; r += gridDim.x*4) {
        const uint4* xr = (const uint4*)&xcat[(size_t)r*64 + 32];
        float v = bc;
        #pragma unroll
        for (int kk = 0; kk < 8; ++kk) {
            uint4 xv = xr[kk];
            unsigned int um[4] = {xv.x, xv.y, xv.z, xv.w};
            #pragma unroll
            for (int m = 0; m < 4; ++m) {
                int k0 = kk*8 + m*2;
                v = fmaf(u2f(um[m] << 16),         ws[k0*64 + c],     v);
                v = fmaf(u2f(um[m] & 0xffff0000u), ws[(k0+1)*64 + c], v);
            }
        }
        v = fmaxf(v, 0.f);
        y[(size_t)r*64 + c] = f2bu(v);
        s += v; q += v*v;
    }
    __shared__ float sm[256], sq[256];
    sm[threadIdx.x] = s; sq[threadIdx.x] = q;
    __syncthreads();
    if (threadIdx.x < 64) {
        atomicAdd(&sums[c],      sm[c] + sm[c+64] + sm[c+128] + sm[c+192]);
        atomicAdd(&sums[64 + c], sq[c] + sq[c+64] + sq[c+128] + sq[c+192]);
    }
}

// ---------------- fused 2-layer 8-step LSTM on MFMA (3 barriers/step) --------
// LDS row: 0:128 x(t) | 128:192 h1 | 192:256 h2 buf0 | 256:320 h2 buf1
#define LROW 328
__global__ __launch_bounds__(256, 2) void lstm_mfma_kernel(
    const unsigned short* __restrict__ xcat,
    const unsigned int* __restrict__ W1f, const unsigned int* __restrict__ W2f,
    const float* __restrict__ bs1, const float* __restrict__ bs2,
    float* __restrict__ out)
{
    __shared__ __align__(16) unsigned short xb[16][LROW];
    const int tid  = threadIdx.x;
    const int w    = tid >> 6, lane = tid & 63;
    const int lr   = lane & 15;
    const int lg   = lane >> 4;
    const int nb0  = blockIdx.x * 16;

    uint4 w1f[4][6], w2f[4][4];
    {
        const uint4* p1 = (const uint4*)W1f;
        #pragma unroll
        for (int nt = 0; nt < 4; ++nt)
            #pragma unroll
            for (int ks = 0; ks < 6; ++ks)
                w1f[nt][ks] = p1[((w*4 + nt)*6 + ks)*64 + lane];
        const uint4* p2 = (const uint4*)W2f;
        #pragma unroll
        for (int nt = 0; nt < 4; ++nt)
            #pragma unroll
            for (int ks = 0; ks < 4; ++ks)
                w2f[nt][ks] = p2[((w*4 + nt)*4 + ks)*64 + lane];
    }
    float b1v[4], b2v[4];
    #pragma unroll
    for (int nt = 0; nt < 4; ++nt) {
        b1v[nt] = bs1[nt*64 + w*16 + lr];
        b2v[nt] = bs2[nt*64 + w*16 + lr];
    }

    // zero h1 + both h2 buffers (cols 128:320)
    for (int i = tid; i < 16*24; i += 256) {
        int n = i / 24, k0 = 128 + (i % 24)*8;
        uint4 z; z.x = z.y = z.z = z.w = 0u;
        *(uint4*)&xb[n][k0] = z;
    }
    // stage x(0)
    {
        int n = tid >> 4, k0 = (tid & 15)*8;
        *(uint4*)&xb[n][k0] = *(const uint4*)&xcat[((size_t)(nb0 + n))*128 + k0];
    }
    float c1[4] = {0.f,0.f,0.f,0.f}, c2[4] = {0.f,0.f,0.f,0.f};

    for (int step = 0; step < 8; ++step) {
        __syncthreads();                    // B_a: x(t)/h1(t-1)/h2(t-1) visible

        // ---- layer 1: A = cols 0:192 ----
        f32x4 acc[4];
        #pragma unroll
        for (int nt = 0; nt < 4; ++nt) { acc[nt][0]=0.f; acc[nt][1]=0.f; acc[nt][2]=0.f; acc[nt][3]=0.f; }
        #pragma unroll
        for (int ks = 0; ks < 6; ++ks) {
            bf16x8 a = *(const bf16x8*)&xb[lr][ks*32 + lg*8];
            #pragma unroll
            for (int nt = 0; nt < 4; ++nt) {
                union { uint4 u; bf16x8 v; } wb; wb.u = w1f[nt][ks];
                acc[nt] = __builtin_amdgcn_mfma_f32_16x16x32_bf16(a, wb.v, acc[nt], 0, 0, 0);
            }
        }
        __syncthreads();                    // B_b: L1 reads done (x + h1 WAR safe)

        // write h1(t); stage x(t+1)
        #pragma unroll
        for (int r = 0; r < 4; ++r) {
            float zi = acc[0][r] + b1v[0];
            float zf = acc[1][r] + b1v[1];
            float zg = acc[2][r] + b1v[2];
            float zo = acc[3][r] + b1v[3];
            float c  = fsig(zf)*c1[r] + fsig(zi)*ftanh(zg);
            c1[r] = c;
            float hv = fsig(zo)*ftanh(c);
            int node = lg*4 + r;
            xb[node][128 + w*16 + lr] = f2bu(hv);
            if (step == 7) out[(size_t)(nb0 + node)*143 + w*16 + lr] = hv;
        }
        if (step < 7) {
            int n = tid >> 4, k0 = (tid & 15)*8;
            *(uint4*)&xb[n][k0] =
                *(const uint4*)&xcat[((size_t)((step+1)*NNODES + nb0 + n))*128 + k0];
        }
        __syncthreads();                    // B_c: h1(t) visible for L2

        // ---- layer 2: A = [h1 | h2 prev buf] ----
        int rb = 192 + 64*((step+1)&1);     // read buffer (prev parity)
        int wb2 = 192 + 64*(step&1);        // write buffer
        #pragma unroll
        for (int nt = 0; nt < 4; ++nt) { acc[nt][0]=0.f; acc[nt][1]=0.f; acc[nt][2]=0.f; acc[nt][3]=0.f; }
        #pragma unroll
        for (int ks = 0; ks < 2; ++ks) {
            bf16x8 a = *(const bf16x8*)&xb[lr][128 + ks*32 + lg*8];
            #pragma unroll
            for (int nt = 0; nt < 4; ++nt) {
                union { uint4 u; bf16x8 v; } wbv; wbv.u = w2f[nt][ks];
                acc[nt] = __builtin_amdgcn_mfma_f32_16x16x32_bf16(a, wbv.v, acc[nt], 0, 0, 0);
            }
        }
        #pragma unroll
        for (int ks = 0; ks < 2; ++ks) {
            bf16x8 a = *(const bf16x8*)&xb[lr][rb + ks*32 + lg*8];
            #pragma unroll
            for (int nt = 0; nt < 4; ++nt) {
                union { uint4 u; bf16x8 v; } wbv; wbv.u = w2f[nt][2+ks];
                acc[nt] = __builtin_amdgcn_mfma_f32_16x16x32_bf16(a, wbv.v, acc[nt], 0, 0, 0);
            }
        }
        // write h2(t) into the other buffer (no barrier needed: disjoint region)
        #pragma unroll
        for (int r = 0; r < 4; ++r) {
            float zi = acc[0][r] + b2v[0];
            float zf = acc[1][r] + b2v[1];
            float zg = acc[2][r] + b2v[2];
            float zo = acc[3][r] + b2v[3];
            float c  = fsig(zf)*c2[r] + fsig(zi)*ftanh(zg);
            c2[r] = c;
            float hv = fsig(zo)*ftanh(c);
            int node = lg*4 + r;
            xb[node][wb2 + w*16 + lr] = f2bu(hv);
            if (step == 7) out[(size_t)(nb0 + node)*143 + 64 + w*16 + lr] = hv;
        }
    }
}

__global__ __launch_bounds__(256) void sfeat_kernel(const float* __restrict__ X,
                                                    float* __restrict__ out)
{
    int gid = blockIdx.x*256 + threadIdx.x;
    if (gid >= NNODES*15) return;
    int n = gid/15, i = gid%15;
    float v = (i < 8) ? X[(size_t)n*8 + i]
                      : X[((size_t)(i-7)*NNODES + n)*8 + 7];
    out[(size_t)n*143 + 128 + i] = v;
}

extern "C" void kernel_launch(void* const* d_in, const int* in_sizes, int n_in,
                              void* d_out, int out_size, void* d_ws, size_t ws_size,
                              hipStream_t stream)
{
    (void)in_sizes; (void)n_in; (void)out_size; (void)ws_size;
    const float* X    = (const float*)d_in[0];
    const int*   ei   = (const int*)d_in[1];
    const float* ew   = (const float*)d_in[2];
    const float* w1   = (const float*)d_in[3];
    const float* b1   = (const float*)d_in[4];
    const float* w2   = (const float*)d_in[5];
    const float* b2   = (const float*)d_in[6];
    const float* g1   = (const float*)d_in[7];
    const float* be1  = (const float*)d_in[8];
    const float* g2   = (const float*)d_in[9];
    const float* be2  = (const float*)d_in[10];
    const float* wih1 = (const float*)d_in[11];
    const float* whh1 = (const float*)d_in[12];
    const float* bih1 = (const float*)d_in[13];
    const float* bhh1 = (const float*)d_in[14];
    const float* wih2 = (const float*)d_in[15];
    const float* whh2 = (const float*)d_in[16];
    const float* bih2 = (const float*)d_in[17];
    const float* bhh2 = (const float*)d_in[18];
    float* out = (float*)d_out;
    float* ws  = (float*)d_ws;

    const int* src = ei;
    const int* dst = ei + NE;

    // workspace layout (word offsets)
    unsigned long long* hist = (unsigned long long*)ws;  //  NT*2 words [zeroed]
    float* sums     = ws + 160000;                       //  256   [zeroed]
    float* dinv     = ws + 160256;                       //  NT
    int*   counttot = (int*)(ws + 240256);               //  NT
    int*   rowptr   = (int*)(ws + 320256);               //  NT+1 (pad to +4)
    int*   cursor   = (int*)(ws + 400260);               //  NT
    int*   blocksum = (int*)(ws + 480260);               //  625
    int*   blockoff = (int*)(ws + 480885);               //  625 (pad to 481536)
    unsigned int* Xb   = (unsigned int*)(ws + 481536);   //  NT*4
    float*        agg8 = ws + 801536;                    //  NT*8
    unsigned short* y  = (unsigned short*)(ws + 1441536);//  NT*64 bf16 (NT*32 dw)
    unsigned int* xcat = (unsigned int*)(ws + 4001536);  //  NT*64 dw (x1|x2, agg2 alias)
    uint2* epack  = (uint2*)(ws + 9121536);              //  NE*2 dw
    unsigned int* W1f = (unsigned int*)(ws + 11681536);  //  24576
    unsigned int* W2f = W1f + 24576;                     //  16384
    float* bs1 = (float*)(W2f + 16384);                  //  256
    float* bs2 = bs1 + 256;                              //  256

    // zero hist + sums
    hipMemsetAsync(ws, 0, (size_t)(160256) * 4, stream);

    prep_w_kernel<<<162, 256, 0, stream>>>(wih1,whh1,bih1,bhh1,
                                           wih2,whh2,bih2,bhh2,
                                           W1f,W2f,bs1,bs2);
    histdeg_kernel<<<1024, 256, 0, stream>>>(dst, ew, hist);
    scan1_kernel<<<625, 128, 0, stream>>>(hist, counttot, dinv, blocksum);
    scan2_kernel<<<1, 1024, 0, stream>>>(blocksum, blockoff);
    scan3_kernel<<<625, 128, 0, stream>>>(counttot, blockoff, rowptr, cursor);
    reorder_kernel<<<1024, 256, 0, stream>>>(src, dst, ew, dinv, cursor, epack);
    xconv_kernel<<<(NT*4+255)/256, 256, 0, stream>>>(X, Xb);

    // GCN layer 1
    gather8_kernel<<<(NT+255)/256, 256, 0, stream>>>(rowptr, epack, (const uint4*)Xb, dinv, agg8);
    gemm8relu_kernel<<<1024, 256, 0, stream>>>(agg8, w1, b1, y, sums);
    bnapply2_kernel<<<(NT*32+255)/256, 256, 0, stream>>>(y, xcat, 0, sums, g1, be1);

    // GCN layer 2 (aggregate into xcat cols 32:64, then GEMM+relu+stats, BN)
    gather64_kernel<<<2048, 256, 0, stream>>>(rowptr, epack, xcat, dinv);
    gemm64relu_kernel<<<1024, 256, 0, stream>>>(xcat, w2, b2, y, sums + 128);
    bnapply2_kernel<<<(NT*32+255)/256, 256, 0, stream>>>(y, xcat, 32, sums + 128, g2, be2);

    // fused MFMA LSTM + skip features
    lstm_mfma_kernel<<<NNODES/16, 256, 0, stream>>>((const unsigned short*)xcat, W1f, W2f, bs1, bs2, out);
    sfeat_kernel<<<(NNODES*15+255)/256, 256, 0, stream>>>(X, out);
}

// Round 8
// 285.629 us; speedup vs baseline: 2.9655x; 1.1743x over previous
//
#include <hip/hip_runtime.h>
#include <hip/hip_bf16.h>
#include <math.h>

#define NNODES 10000
#define NT     80000
#define NE     1280000
#define BNEPS  1e-5f

typedef __bf16 bf16x8 __attribute__((ext_vector_type(8)));
typedef float  f32x4  __attribute__((ext_vector_type(4)));

__device__ __forceinline__ float frcp(float x){ return __builtin_amdgcn_rcpf(x); }
__device__ __forceinline__ float fsig(float x){ return frcp(1.0f + __expf(-x)); }
__device__ __forceinline__ float ftanh(float x){ return 1.0f - 2.0f*frcp(1.0f + __expf(2.0f*x)); }
__device__ __forceinline__ float u2f(unsigned int u){ union{unsigned int u; float f;} c; c.u=u; return c.f; }
__device__ __forceinline__ unsigned int f2u(float f){ union{float f; unsigned int u;} c; c.f=f; return c.u; }
__device__ __forceinline__ unsigned short f2bu(float v){ __hip_bfloat16 h = __float2bfloat16(v); return *(unsigned short*)&h; }
__device__ __forceinline__ unsigned int pk2(float a, float b){ return (unsigned int)f2bu(a) | ((unsigned int)f2bu(b) << 16); }
// 15-bit float decode: 8-bit exp, 6-bit mantissa, positive only
__device__ __forceinline__ float dec15(unsigned int p){ return u2f((p & 0x7fffu) << 17); }

// ---------------- weight prep: pack LSTM weights into MFMA B-fragment order ---
__global__ __launch_bounds__(256) void prep_w_kernel(
    const float* __restrict__ wih1, const float* __restrict__ whh1,
    const float* __restrict__ bih1, const float* __restrict__ bhh1,
    const float* __restrict__ wih2, const float* __restrict__ whh2,
    const float* __restrict__ bih2, const float* __restrict__ bhh2,
    unsigned int* __restrict__ W1f, unsigned int* __restrict__ W2f,
    float* __restrict__ bs1, float* __restrict__ bs2)
{
    int gid = blockIdx.x*256 + threadIdx.x;
    if (gid < 24576) {
        int i = gid & 3, lane = (gid>>2)&63, rest = gid>>8;
        int ks = rest % 6; rest /= 6;
        int nt = rest & 3, w = rest >> 2;
        int gate = nt*64 + w*16 + (lane & 15);
        int k = ks*32 + ((lane>>4)&3)*8 + 2*i;
        float v0 = (k     < 128) ? wih1[gate*128 + k]       : whh1[gate*64 + (k-128)];
        float v1 = (k + 1 < 128) ? wih1[gate*128 + k + 1]   : whh1[gate*64 + (k+1-128)];
        W1f[gid] = pk2(v0, v1);
    } else if (gid < 24576 + 16384) {
        int r = gid - 24576;
        int i = r & 3, lane = (r>>2)&63, rest = r>>8;
        int ks = rest & 3; rest >>= 2;
        int nt = rest & 3, w = rest >> 2;
        int gate = nt*64 + w*16 + (lane & 15);
        int k = ks*32 + ((lane>>4)&3)*8 + 2*i;
        float v0 = (k     < 64) ? wih2[gate*64 + k]     : whh2[gate*64 + (k-64)];
        float v1 = (k + 1 < 64) ? wih2[gate*64 + k + 1] : whh2[gate*64 + (k+1-64)];
        W2f[r] = pk2(v0, v1);
    } else if (gid < 24576 + 16384 + 256) {
        int j = gid - (24576 + 16384); bs1[j] = bih1[j] + bhh1[j];
    } else if (gid < 24576 + 16384 + 512) {
        int j = gid - (24576 + 16384 + 256); bs2[j] = bih2[j] + bhh2[j];
    }
}

// one packed 64-bit atomic per edge; returned old count = this edge's rank
__global__ __launch_bounds__(256) void histdeg_kernel(const int* __restrict__ dst,
                                                      const float* __restrict__ ew,
                                                      unsigned long long* __restrict__ hist,
                                                      unsigned short* __restrict__ erank)
{
    int gid = blockIdx.x*blockDim.x + threadIdx.x;
    int stride = gridDim.x*blockDim.x;
    for (int e = gid; e < NE; e += stride) {
        int d = dst[e];
        unsigned long long v = (1ULL << 48)
            | (unsigned long long)(ew[e] * 4294967296.0f);
        unsigned long long old = atomicAdd(&hist[d], v);
        erank[e] = (unsigned short)(old >> 48);
    }
}

// ---- 3-phase parallel scan (625 blocks x 128) ----
__global__ __launch_bounds__(128) void scan1_kernel(const unsigned long long* __restrict__ hist,
                                                    int* __restrict__ counttot,
                                                    float* __restrict__ dinv,
                                                    int* __restrict__ blocksum)
{
    __shared__ int sm[128];
    int tid = threadIdx.x;
    int idx = blockIdx.x*128 + tid;
    unsigned long long v = hist[idx];
    int c = (int)(v >> 48);
    float dg = (float)(v & 0x0000FFFFFFFFFFFFULL) * (1.0f/4294967296.0f);
    counttot[idx] = c;
    dinv[idx] = rsqrtf(dg + 1.0f);
    sm[tid] = c;
    __syncthreads();
    #pragma unroll
    for (int off = 64; off > 0; off >>= 1) {
        if (tid < off) sm[tid] += sm[tid + off];
        __syncthreads();
    }
    if (tid == 0) blocksum[blockIdx.x] = sm[0];
}

__global__ __launch_bounds__(1024) void scan2_kernel(const int* __restrict__ blocksum,
                                                     int* __restrict__ blockoff)
{
    __shared__ int part[1024];
    int tid = threadIdx.x;
    int v = (tid < 625) ? blocksum[tid] : 0;
    part[tid] = v;
    __syncthreads();
    for (int off = 1; off < 1024; off <<= 1) {
        int t = (tid >= off) ? part[tid - off] : 0;
        __syncthreads();
        part[tid] += t;
        __syncthreads();
    }
    if (tid < 625) blockoff[tid] = part[tid] - v;
}

__global__ __launch_bounds__(128) void scan3_kernel(const int* __restrict__ counttot,
                                                    const int* __restrict__ blockoff,
                                                    int* __restrict__ rowptr)
{
    __shared__ int part[128];
    int tid = threadIdx.x;
    int idx = blockIdx.x*128 + tid;
    int v = counttot[idx];
    part[tid] = v;
    __syncthreads();
    #pragma unroll
    for (int off = 1; off < 128; off <<= 1) {
        int t = (tid >= off) ? part[tid - off] : 0;
        __syncthreads();
        part[tid] += t;
        __syncthreads();
    }
    rowptr[idx] = part[tid] - v + blockoff[blockIdx.x];
    if (idx == 0) rowptr[NT] = NE;
}

// atomic-free bucketing: pos = rowptr[d] + erank[e]; epack = (src<<15)|fp15(ew*dinv[s])
__global__ __launch_bounds__(256) void reorder_kernel(const int* __restrict__ src,
                                                      const int* __restrict__ dst,
                                                      const float* __restrict__ ew,
                                                      const float* __restrict__ dinv,
                                                      const unsigned short* __restrict__ erank,
                                                      const int* __restrict__ rowptr,
                                                      unsigned int* __restrict__ epack)
{
    int gid = blockIdx.x*blockDim.x + threadIdx.x;
    int stride = gridDim.x*blockDim.x;
    for (int e = gid; e < NE; e += stride) {
        int d = dst[e], s = src[e];
        float w = ew[e] * dinv[s];
        unsigned int p15 = (f2u(w) + (1u << 16)) >> 17;   // round-to-nearest 6-bit mantissa
        int pos = rowptr[d] + (int)erank[e];
        epack[pos] = ((unsigned int)s << 15) | p15;
    }
}

// X f32 [NT,8] -> Xb bf16 (packed dwords, 4 per row)
__global__ __launch_bounds__(256) void xconv_kernel(const float* __restrict__ X,
                                                    unsigned int* __restrict__ Xb)
{
    int gid = blockIdx.x*256 + threadIdx.x;
    if (gid >= NT*4) return;
    float2 v = *(const float2*)&X[(size_t)gid*2];
    Xb[gid] = pk2(v.x, v.y);
}

// thread-per-dst 8-channel aggregation; dinv[d] folded at the end
__global__ __launch_bounds__(256) void gather8_kernel(const int* __restrict__ rowptr,
                                                      const unsigned int* __restrict__ epack,
                                                      const uint4* __restrict__ Xb,
                                                      const float* __restrict__ dinv,
                                                      float* __restrict__ agg8)
{
    int d = blockIdx.x*256 + threadIdx.x;
    if (d >= NT) return;
    int beg = rowptr[d], end = rowptr[d+1];
    float acc[8];
    #pragma unroll
    for (int k = 0; k < 8; ++k) acc[k] = 0.f;
    for (int i = beg; i < end; ++i) {
        unsigned int p = epack[i];
        float nrm = dec15(p);
        uint4 xv = Xb[p >> 15];
        unsigned int um[4] = {xv.x, xv.y, xv.z, xv.w};
        #pragma unroll
        for (int m = 0; m < 4; ++m) {
            acc[2*m]   = fmaf(nrm, u2f(um[m] << 16),         acc[2*m]);
            acc[2*m+1] = fmaf(nrm, u2f(um[m] & 0xffff0000u), acc[2*m+1]);
        }
    }
    float dv = dinv[d];
    uint4 xd = Xb[d];
    unsigned int ud[4] = {xd.x, xd.y, xd.z, xd.w};
    #pragma unroll
    for (int m = 0; m < 4; ++m) {
        acc[2*m]   = dv * fmaf(dv, u2f(ud[m] << 16),         acc[2*m]);
        acc[2*m+1] = dv * fmaf(dv, u2f(ud[m] & 0xffff0000u), acc[2*m+1]);
    }
    float4* o = (float4*)&agg8[(size_t)d*8];
    o[0] = make_float4(acc[0], acc[1], acc[2], acc[3]);
    o[1] = make_float4(acc[4], acc[5], acc[6], acc[7]);
}

// y1 = relu(agg8 @ w1 + b1) -> bf16 (pre-BN); fused BN stats
__global__ __launch_bounds__(256) void gemm8relu_kernel(const float* __restrict__ agg8,
                                                        const float* __restrict__ w,
                                                        const float* __restrict__ b,
                                                        unsigned short* __restrict__ y,
                                                        float* __restrict__ sums)
{
    __shared__ float ws[512];
    for (int i = threadIdx.x; i < 512; i += 256) ws[i] = w[i];
    __syncthreads();
    int c = threadIdx.x & 63, wq = threadIdx.x >> 6;
    float bc = b[c];
    float s = 0.f, q = 0.f;
    for (int r = blockIdx.x*4 + wq; r < NT; r += gridDim.x*4) {
        const float4* ar = (const float4*)&agg8[(size_t)r*8];
        float4 a0 = ar[0], a1 = ar[1];
        float v = bc;
        v = fmaf(a0.x, ws[0*64+c], v); v = fmaf(a0.y, ws[1*64+c], v);
        v = fmaf(a0.z, ws[2*64+c], v); v = fmaf(a0.w, ws[3*64+c], v);
        v = fmaf(a1.x, ws[4*64+c], v); v = fmaf(a1.y, ws[5*64+c], v);
        v = fmaf(a1.z, ws[6*64+c], v); v = fmaf(a1.w, ws[7*64+c], v);
        v = fmaxf(v, 0.f);
        y[(size_t)r*64 + c] = f2bu(v);
        s += v; q += v*v;
    }
    __shared__ float sm[256], sq[256];
    sm[threadIdx.x] = s; sq[threadIdx.x] = q;
    __syncthreads();
    if (threadIdx.x < 64) {
        atomicAdd(&sums[c],      sm[c] + sm[c+64] + sm[c+128] + sm[c+192]);
        atomicAdd(&sums[64 + c], sq[c] + sq[c+64] + sq[c+128] + sq[c+192]);
    }
}

// 64-ch gather with INLINE BatchNorm on y1 reads; writes BN'd x1 into xcat[0:32]
// and the aggregate (bf16) into xcat[32:64]. 4 edges/wave, 4 ch/lane.
__global__ __launch_bounds__(256) void gather64_kernel(const int* __restrict__ rowptr,
                                                       const unsigned int* __restrict__ epack,
                                                       const unsigned int* __restrict__ y1,
                                                       const float* __restrict__ dinv,
                                                       const float* __restrict__ sums,
                                                       const float* __restrict__ g,
                                                       const float* __restrict__ be,
                                                       unsigned int* __restrict__ xcat)
{
    int lane = threadIdx.x & 63;
    int grp = lane >> 4, l = lane & 15;       // edge slot, channel quad
    int gwave = blockIdx.x*4 + (threadIdx.x >> 6);
    int nwaves = gridDim.x*4;
    // BN affine coeffs for channels 4l..4l+3
    float ax[4], bx[4];
    #pragma unroll
    for (int j = 0; j < 4; ++j) {
        int c = 4*l + j;
        float mu  = sums[c] * (1.0f/NT);
        float var = sums[64 + c] * (1.0f/NT) - mu*mu;
        float a = rsqrtf(var + BNEPS) * g[c];
        ax[j] = a; bx[j] = be[c] - mu*a;
    }
    for (int d = gwave; d < NT; d += nwaves) {
        int beg = rowptr[d], end = rowptr[d+1];
        float a0 = 0.f, a1 = 0.f, a2 = 0.f, a3 = 0.f;
        for (int i = beg; i < end; i += 4) {
            int idx = i + grp;
            bool valid = idx < end;
            unsigned int p = epack[valid ? idx : (end - 1)];
            float nrm = valid ? dec15(p) : 0.f;
            uint2 xv = *(const uint2*)&y1[(size_t)(p >> 15)*32 + 2*l];
            a0 = fmaf(nrm, fmaf(ax[0], u2f(xv.x << 16),         bx[0]), a0);
            a1 = fmaf(nrm, fmaf(ax[1], u2f(xv.x & 0xffff0000u), bx[1]), a1);
            a2 = fmaf(nrm, fmaf(ax[2], u2f(xv.y << 16),         bx[2]), a2);
            a3 = fmaf(nrm, fmaf(ax[3], u2f(xv.y & 0xffff0000u), bx[3]), a3);
        }
        a0 += __shfl_xor(a0, 16); a1 += __shfl_xor(a1, 16);
        a2 += __shfl_xor(a2, 16); a3 += __shfl_xor(a3, 16);
        a0 += __shfl_xor(a0, 32); a1 += __shfl_xor(a1, 32);
        a2 += __shfl_xor(a2, 32); a3 += __shfl_xor(a3, 32);
        if (grp == 0) {
            float dv = dinv[d];
            uint2 xd = *(const uint2*)&y1[(size_t)d*32 + 2*l];
            float x0 = fmaf(ax[0], u2f(xd.x << 16),         bx[0]);
            float x1 = fmaf(ax[1], u2f(xd.x & 0xffff0000u), bx[1]);
            float x2 = fmaf(ax[2], u2f(xd.y << 16),         bx[2]);
            float x3 = fmaf(ax[3], u2f(xd.y & 0xffff0000u), bx[3]);
            // BN'd x1 row for the LSTM
            *(uint2*)&xcat[(size_t)d*64 + 2*l] = make_uint2(pk2(x0, x1), pk2(x2, x3));
            // aggregate with self-loop, dinv[d] folded
            a0 = dv * fmaf(dv, x0, a0);
            a1 = dv * fmaf(dv, x1, a1);
            a2 = dv * fmaf(dv, x2, a2);
            a3 = dv * fmaf(dv, x3, a3);
            *(uint2*)&xcat[(size_t)d*64 + 32 + 2*l] = make_uint2(pk2(a0, a1), pk2(a2, a3));
        }
    }
}

// y2 = relu(agg2(bf16, xcat cols 32:64) @ w2 + b2) -> bf16 (pre-BN); BN stats
__global__ __launch_bounds__(256) void gemm64relu_kernel(const unsigned int* __restrict__ xcat,
                                                         const float* __restrict__ w,
                                                         const float* __restrict__ b,
                                                         unsigned short* __restrict__ y,
                                                         float* __restrict__ sums)
{
    __shared__ float ws[4096];
    for (int i = threadIdx.x; i < 4096; i += 256) ws[i] = w[i];
    __syncthreads();
    int c = threadIdx.x & 63, wq = threadIdx.x >> 6;
    float bc = b[c];
    float s = 0.f, q = 0.f;
    for (int r = blockIdx.x*4 + wq; r < NT; r += gridDim.x*4) {
        const uint4* xr = (const uint4*)&xcat[(size_t)r*64 + 32];
        float v = bc;
        #pragma unroll
        for (int kk = 0; kk < 8; ++kk) {
            uint4 xv = xr[kk];
            unsigned int um[4] = {xv.x, xv.y, xv.z, xv.w};
            #pragma unroll
            for (int m = 0; m < 4; ++m) {
                int k0 = kk*8 + m*2;
                v = fmaf(u2f(um[m] << 16),         ws[k0*64 + c],     v);
                v = fmaf(u2f(um[m] & 0xffff0000u), ws[(k0+1)*64 + c], v);
            }
        }
        v = fmaxf(v, 0.f);
        y[(size_t)r*64 + c] = f2bu(v);
        s += v; q += v*v;
    }
    __shared__ float sm[256], sq[256];
    sm[threadIdx.x] = s; sq[threadIdx.x] = q;
    __syncthreads();
    if (threadIdx.x < 64) {
        atomicAdd(&sums[c],      sm[c] + sm[c+64] + sm[c+128] + sm[c+192]);
        atomicAdd(&sums[64 + c], sq[c] + sq[c+64] + sq[c+128] + sq[c+192]);
    }
}

// ---------------- fused 2-layer 8-step LSTM on MFMA (3 barriers/step) --------
// x2's BatchNorm applied inline during LDS staging (from pre-BN y2).
// LDS row: 0:128 x(t) | 128:192 h1 | 192:256 h2 buf0 | 256:320 h2 buf1
#define LROW 328
__global__ __launch_bounds__(256, 2) void lstm_mfma_kernel(
    const unsigned int* __restrict__ xcat,
    const unsigned int* __restrict__ y2,
    const float* __restrict__ sums2, const float* __restrict__ g2,
    const float* __restrict__ be2,
    const unsigned int* __restrict__ W1f, const unsigned int* __restrict__ W2f,
    const float* __restrict__ bs1, const float* __restrict__ bs2,
    float* __restrict__ out)
{
    __shared__ __align__(16) unsigned short xb[16][LROW];
    const int tid  = threadIdx.x;
    const int w    = tid >> 6, lane = tid & 63;
    const int lr   = lane & 15;
    const int lg   = lane >> 4;
    const int nb0  = blockIdx.x * 16;

    uint4 w1f[4][6], w2f[4][4];
    {
        const uint4* p1 = (const uint4*)W1f;
        #pragma unroll
        for (int nt = 0; nt < 4; ++nt)
            #pragma unroll
            for (int ks = 0; ks < 6; ++ks)
                w1f[nt][ks] = p1[((w*4 + nt)*6 + ks)*64 + lane];
        const uint4* p2 = (const uint4*)W2f;
        #pragma unroll
        for (int nt = 0; nt < 4; ++nt)
            #pragma unroll
            for (int ks = 0; ks < 4; ++ks)
                w2f[nt][ks] = p2[((w*4 + nt)*4 + ks)*64 + lane];
    }
    float b1v[4], b2v[4];
    #pragma unroll
    for (int nt = 0; nt < 4; ++nt) {
        b1v[nt] = bs1[nt*64 + w*16 + lr];
        b2v[nt] = bs2[nt*64 + w*16 + lr];
    }

    // staging role: node sn, channel block k0 (8 ch). k0>=64 -> from y2 + BN affine
    const int sn = tid >> 4, k0 = (tid & 15)*8;
    float ax[8], bx[8];
    if (k0 >= 64) {
        #pragma unroll
        for (int j = 0; j < 8; ++j) {
            int c = k0 - 64 + j;
            float mu  = sums2[c] * (1.0f/NT);
            float var = sums2[64 + c] * (1.0f/NT) - mu*mu;
            float a = rsqrtf(var + BNEPS) * g2[c];
            ax[j] = a; bx[j] = be2[c] - mu*a;
        }
    }

    // zero h1 + both h2 buffers (cols 128:320)
    for (int i = tid; i < 16*24; i += 256) {
        int n = i / 24, kk = 128 + (i % 24)*8;
        uint4 z; z.x = z.y = z.z = z.w = 0u;
        *(uint4*)&xb[n][kk] = z;
    }

    auto stage = [&](int step) {
        size_t row = (size_t)(step*NNODES + nb0 + sn);
        uint4 raw;
        if (k0 < 64) {
            raw = *(const uint4*)&xcat[row*64 + (k0 >> 1)];
        } else {
            raw = *(const uint4*)&y2[row*32 + ((k0 - 64) >> 1)];
            unsigned int um[4] = {raw.x, raw.y, raw.z, raw.w};
            #pragma unroll
            for (int m = 0; m < 4; ++m) {
                float v0 = fmaf(ax[2*m],   u2f(um[m] << 16),         bx[2*m]);
                float v1 = fmaf(ax[2*m+1], u2f(um[m] & 0xffff0000u), bx[2*m+1]);
                um[m] = pk2(v0, v1);
            }
            raw.x = um[0]; raw.y = um[1]; raw.z = um[2]; raw.w = um[3];
        }
        *(uint4*)&xb[sn][k0] = raw;
    };
    stage(0);
    float c1[4] = {0.f,0.f,0.f,0.f}, c2[4] = {0.f,0.f,0.f,0.f};

    for (int step = 0; step < 8; ++step) {
        __syncthreads();                    // B_a: x(t)/h1(t-1)/h2(t-1) visible

        // ---- layer 1: A = cols 0:192 ----
        f32x4 acc[4];
        #pragma unroll
        for (int nt = 0; nt < 4; ++nt) { acc[nt][0]=0.f; acc[nt][1]=0.f; acc[nt][2]=0.f; acc[nt][3]=0.f; }
        #pragma unroll
        for (int ks = 0; ks < 6; ++ks) {
            bf16x8 a = *(const bf16x8*)&xb[lr][ks*32 + lg*8];
            #pragma unroll
            for (int nt = 0; nt < 4; ++nt) {
                union { uint4 u; bf16x8 v; } wb; wb.u = w1f[nt][ks];
                acc[nt] = __builtin_amdgcn_mfma_f32_16x16x32_bf16(a, wb.v, acc[nt], 0, 0, 0);
            }
        }
        __syncthreads();                    // B_b: L1 reads done (x + h1 WAR safe)

        // write h1(t); stage x(t+1)
        #pragma unroll
        for (int r = 0; r < 4; ++r) {
            float zi = acc[0][r] + b1v[0];
            float zf = acc[1][r] + b1v[1];
            float zg = acc[2][r] + b1v[2];
            float zo = acc[3][r] + b1v[3];
            float c  = fsig(zf)*c1[r] + fsig(zi)*ftanh(zg);
            c1[r] = c;
            float hv = fsig(zo)*ftanh(c);
            int node = lg*4 + r;
            xb[node][128 + w*16 + lr] = f2bu(hv);
            if (step == 7) out[(size_t)(nb0 + node)*143 + w*16 + lr] = hv;
        }
        if (step < 7) stage(step + 1);
        __syncthreads();                    // B_c: h1(t) visible for L2

        // ---- layer 2: A = [h1 | h2 prev buf] ----
        int rb = 192 + 64*((step+1)&1);     // read buffer (prev parity)
        int wb2 = 192 + 64*(step&1);        // write buffer
        #pragma unroll
        for (int nt = 0; nt < 4; ++nt) { acc[nt][0]=0.f; acc[nt][1]=0.f; acc[nt][2]=0.f; acc[nt][3]=0.f; }
        #pragma unroll
        for (int ks = 0; ks < 2; ++ks) {
            bf16x8 a = *(const bf16x8*)&xb[lr][128 + ks*32 + lg*8];
            #pragma unroll
            for (int nt = 0; nt < 4; ++nt) {
                union { uint4 u; bf16x8 v; } wbv; wbv.u = w2f[nt][ks];
                acc[nt] = __builtin_amdgcn_mfma_f32_16x16x32_bf16(a, wbv.v, acc[nt], 0, 0, 0);
            }
        }
        #pragma unroll
        for (int ks = 0; ks < 2; ++ks) {
            bf16x8 a = *(const bf16x8*)&xb[lr][rb + ks*32 + lg*8];
            #pragma unroll
            for (int nt = 0; nt < 4; ++nt) {
                union { uint4 u; bf16x8 v; } wbv; wbv.u = w2f[nt][2+ks];
                acc[nt] = __builtin_amdgcn_mfma_f32_16x16x32_bf16(a, wbv.v, acc[nt], 0, 0, 0);
            }
        }
        #pragma unroll
        for (int r = 0; r < 4; ++r) {
            float zi = acc[0][r] + b2v[0];
            float zf = acc[1][r] + b2v[1];
            float zg = acc[2][r] + b2v[2];
            float zo = acc[3][r] + b2v[3];
            float c  = fsig(zf)*c2[r] + fsig(zi)*ftanh(zg);
            c2[r] = c;
            float hv = fsig(zo)*ftanh(c);
            int node = lg*4 + r;
            xb[node][wb2 + w*16 + lr] = f2bu(hv);
            if (step == 7) out[(size_t)(nb0 + node)*143 + 64 + w*16 + lr] = hv;
        }
    }
}

__global__ __launch_bounds__(256) void sfeat_kernel(const float* __restrict__ X,
                                                    float* __restrict__ out)
{
    int gid = blockIdx.x*256 + threadIdx.x;
    if (gid >= NNODES*15) return;
    int n = gid/15, i = gid%15;
    float v = (i < 8) ? X[(size_t)n*8 + i]
                      : X[((size_t)(i-7)*NNODES + n)*8 + 7];
    out[(size_t)n*143 + 128 + i] = v;
}

extern "C" void kernel_launch(void* const* d_in, const int* in_sizes, int n_in,
                              void* d_out, int out_size, void* d_ws, size_t ws_size,
                              hipStream_t stream)
{
    (void)in_sizes; (void)n_in; (void)out_size; (void)ws_size;
    const float* X    = (const float*)d_in[0];
    const int*   ei   = (const int*)d_in[1];
    const float* ew   = (const float*)d_in[2];
    const float* w1   = (const float*)d_in[3];
    const float* b1   = (const float*)d_in[4];
    const float* w2   = (const float*)d_in[5];
    const float* b2   = (const float*)d_in[6];
    const float* g1   = (const float*)d_in[7];
    const float* be1  = (const float*)d_in[8];
    const float* g2   = (const float*)d_in[9];
    const float* be2  = (const float*)d_in[10];
    const float* wih1 = (const float*)d_in[11];
    const float* whh1 = (const float*)d_in[12];
    const float* bih1 = (const float*)d_in[13];
    const float* bhh1 = (const float*)d_in[14];
    const float* wih2 = (const float*)d_in[15];
    const float* whh2 = (const float*)d_in[16];
    const float* bih2 = (const float*)d_in[17];
    const float* bhh2 = (const float*)d_in[18];
    float* out = (float*)d_out;
    float* ws  = (float*)d_ws;

    const int* src = ei;
    const int* dst = ei + NE;

    // workspace layout (word offsets)
    unsigned long long* hist = (unsigned long long*)ws;  //  160000 words [zeroed]
    float* sums     = ws + 160000;                       //  256 [zeroed] (128 L1 + 128 L2)
    float* dinv     = ws + 160256;                       //  NT
    int*   counttot = (int*)(ws + 240256);               //  NT
    int*   rowptr   = (int*)(ws + 320256);               //  NT+1 (pad 4)
    int*   blocksum = (int*)(ws + 400260);               //  625
    int*   blockoff = (int*)(ws + 400885);               //  625 (pad to 401536)
    unsigned short* erank = (unsigned short*)(ws + 401536); // NE ushort = 640000 words
    unsigned int* Xb   = (unsigned int*)(ws + 1041536);  //  NT*4
    float*        agg8 = ws + 1361536;                   //  NT*8
    unsigned int* y1   = (unsigned int*)(ws + 2001536);  //  NT*32 dw (bf16 pre-BN L1)
    unsigned int* y2   = (unsigned int*)(ws + 4561536);  //  NT*32 dw (bf16 pre-BN L2)
    unsigned int* xcat = (unsigned int*)(ws + 7121536);  //  NT*64 dw (BN x1 | agg2)
    unsigned int* epack= (unsigned int*)(ws + 12241536); //  NE dw
    unsigned int* W1f  = (unsigned int*)(ws + 13521536); //  24576
    unsigned int* W2f  = W1f + 24576;                    //  16384
    float* bs1 = (float*)(W2f + 16384);                  //  256
    float* bs2 = bs1 + 256;                              //  256

    // zero hist + sums
    hipMemsetAsync(ws, 0, (size_t)(160256) * 4, stream);

    prep_w_kernel<<<162, 256, 0, stream>>>(wih1,whh1,bih1,bhh1,
                                           wih2,whh2,bih2,bhh2,
                                           W1f,W2f,bs1,bs2);
    histdeg_kernel<<<1024, 256, 0, stream>>>(dst, ew, hist, erank);
    scan1_kernel<<<625, 128, 0, stream>>>(hist, counttot, dinv, blocksum);
    scan2_kernel<<<1, 1024, 0, stream>>>(blocksum, blockoff);
    scan3_kernel<<<625, 128, 0, stream>>>(counttot, blockoff, rowptr);
    reorder_kernel<<<1024, 256, 0, stream>>>(src, dst, ew, dinv, erank, rowptr, epack);
    xconv_kernel<<<(NT*4+255)/256, 256, 0, stream>>>(X, Xb);

    // GCN layer 1
    gather8_kernel<<<(NT+255)/256, 256, 0, stream>>>(rowptr, epack, (const uint4*)Xb, dinv, agg8);
    gemm8relu_kernel<<<1024, 256, 0, stream>>>(agg8, w1, b1, (unsigned short*)y1, sums);

    // GCN layer 2 (BN1 fused into gather64; BN2 fused into LSTM staging)
    gather64_kernel<<<2048, 256, 0, stream>>>(rowptr, epack, y1, dinv, sums, g1, be1, xcat);
    gemm64relu_kernel<<<1024, 256, 0, stream>>>(xcat, w2, b2, (unsigned short*)y2, sums + 128);

    // fused MFMA LSTM + skip features
    lstm_mfma_kernel<<<NNODES/16, 256, 0, stream>>>(xcat, y2, sums + 128, g2, be2,
                                                    W1f, W2f, bs1, bs2, out);
    sfeat_kernel<<<(NNODES*15+255)/256, 256, 0, stream>>>(X, out);
}

// Round 9
// 253.169 us; speedup vs baseline: 3.3457x; 1.1282x over previous
//
#include <hip/hip_runtime.h>
#include <hip/hip_bf16.h>
#include <math.h>

#define NNODES 10000
#define NT     80000
#define NE     1280000
#define NBKT   625       // coarse buckets = NT/128
#define CHUNK  5000      // edges per A-block = NE/256
#define BNEPS  1e-5f

typedef __bf16 bf16x8 __attribute__((ext_vector_type(8)));
typedef float  f32x4  __attribute__((ext_vector_type(4)));

__device__ __forceinline__ float frcp(float x){ return __builtin_amdgcn_rcpf(x); }
__device__ __forceinline__ float fsig(float x){ return frcp(1.0f + __expf(-x)); }
__device__ __forceinline__ float ftanh(float x){ return 1.0f - 2.0f*frcp(1.0f + __expf(2.0f*x)); }
__device__ __forceinline__ float u2f(unsigned int u){ union{unsigned int u; float f;} c; c.u=u; return c.f; }
__device__ __forceinline__ unsigned int f2u(float f){ union{float f; unsigned int u;} c; c.f=f; return c.u; }
__device__ __forceinline__ unsigned short f2bu(float v){ __hip_bfloat16 h = __float2bfloat16(v); return *(unsigned short*)&h; }
__device__ __forceinline__ unsigned int pk2(float a, float b){ return (unsigned int)f2bu(a) | ((unsigned int)f2bu(b) << 16); }
// 15-bit float decode: 8-bit exp, 6-bit mantissa, positive only
__device__ __forceinline__ float dec15(unsigned int p){ return u2f((p & 0x7fffu) << 17); }

// ---------------- weight prep: pack LSTM weights into MFMA B-fragment order ---
__global__ __launch_bounds__(256) void prep_w_kernel(
    const float* __restrict__ wih1, const float* __restrict__ whh1,
    const float* __restrict__ bih1, const float* __restrict__ bhh1,
    const float* __restrict__ wih2, const float* __restrict__ whh2,
    const float* __restrict__ bih2, const float* __restrict__ bhh2,
    unsigned int* __restrict__ W1f, unsigned int* __restrict__ W2f,
    float* __restrict__ bs1, float* __restrict__ bs2)
{
    int gid = blockIdx.x*256 + threadIdx.x;
    if (gid < 24576) {
        int i = gid & 3, lane = (gid>>2)&63, rest = gid>>8;
        int ks = rest % 6; rest /= 6;
        int nt = rest & 3, w = rest >> 2;
        int gate = nt*64 + w*16 + (lane & 15);
        int k = ks*32 + ((lane>>4)&3)*8 + 2*i;
        float v0 = (k     < 128) ? wih1[gate*128 + k]       : whh1[gate*64 + (k-128)];
        float v1 = (k + 1 < 128) ? wih1[gate*128 + k + 1]   : whh1[gate*64 + (k+1-128)];
        W1f[gid] = pk2(v0, v1);
    } else if (gid < 24576 + 16384) {
        int r = gid - 24576;
        int i = r & 3, lane = (r>>2)&63, rest = r>>8;
        int ks = rest & 3; rest >>= 2;
        int nt = rest & 3, w = rest >> 2;
        int gate = nt*64 + w*16 + (lane & 15);
        int k = ks*32 + ((lane>>4)&3)*8 + 2*i;
        float v0 = (k     < 64) ? wih2[gate*64 + k]     : whh2[gate*64 + (k-64)];
        float v1 = (k + 1 < 64) ? wih2[gate*64 + k + 1] : whh2[gate*64 + (k+1-64)];
        W2f[r] = pk2(v0, v1);
    } else if (gid < 24576 + 16384 + 256) {
        int j = gid - (24576 + 16384); bs1[j] = bih1[j] + bhh1[j];
    } else if (gid < 24576 + 16384 + 512) {
        int j = gid - (24576 + 16384 + 256); bs2[j] = bih2[j] + bhh2[j];
    }
}

// ---------- deterministic two-level counting sort (no global atomics) --------
// A1: per-block coarse histogram (dst>>7) -> histmat[blk][640+bin]
__global__ __launch_bounds__(256) void sortA1_kernel(const int* __restrict__ dst,
                                                     int* __restrict__ histmat)
{
    __shared__ int h[NBKT];
    for (int i = threadIdx.x; i < NBKT; i += 256) h[i] = 0;
    __syncthreads();
    int base = blockIdx.x*CHUNK;
    for (int i = threadIdx.x; i < CHUNK; i += 256)
        atomicAdd(&h[dst[base + i] >> 7], 1);
    __syncthreads();
    for (int i = threadIdx.x; i < NBKT; i += 256)
        histmat[blockIdx.x*640 + i] = h[i];
}

// A2a: per-bin exclusive scan over 256 blocks -> offmatT[bin][blk], binTotal
__global__ __launch_bounds__(256) void sortA2a_kernel(const int* __restrict__ histmat,
                                                      int* __restrict__ offmatT,
                                                      int* __restrict__ binTotal)
{
    __shared__ int v[256];
    int b = blockIdx.x, t = threadIdx.x;
    int x = histmat[t*640 + b];
    v[t] = x;
    __syncthreads();
    for (int off = 1; off < 256; off <<= 1) {
        int y = (t >= off) ? v[t-off] : 0;
        __syncthreads();
        v[t] += y;
        __syncthreads();
    }
    offmatT[b*256 + t] = v[t] - x;
    if (t == 255) binTotal[b] = v[255];
}

// A2b: exclusive scan of 625 bucket totals -> bucketbase[626]; rowptr[NT]=NE
__global__ __launch_bounds__(1024) void sortA2b_kernel(const int* __restrict__ binTotal,
                                                       int* __restrict__ bucketbase,
                                                       int* __restrict__ rowptr)
{
    __shared__ int part[1024];
    int t = threadIdx.x;
    int v = (t < NBKT) ? binTotal[t] : 0;
    part[t] = v;
    __syncthreads();
    for (int off = 1; off < 1024; off <<= 1) {
        int y = (t >= off) ? part[t-off] : 0;
        __syncthreads();
        part[t] += y;
        __syncthreads();
    }
    if (t < NBKT) bucketbase[t] = part[t] - v;
    if (t == 0) { bucketbase[NBKT] = NE; rowptr[NT] = NE; }
}

// A3: scatter (src | dlow<<17, ew) into coarse buckets at precomputed offsets
__global__ __launch_bounds__(256) void sortA3_kernel(const int* __restrict__ src,
                                                     const int* __restrict__ dst,
                                                     const float* __restrict__ ew,
                                                     const int* __restrict__ offmatT,
                                                     const int* __restrict__ bucketbase,
                                                     uint2* __restrict__ esort)
{
    __shared__ int cur[NBKT];
    int blk = blockIdx.x;
    for (int i = threadIdx.x; i < NBKT; i += 256)
        cur[i] = bucketbase[i] + offmatT[i*256 + blk];
    __syncthreads();
    int base = blk*CHUNK;
    for (int i = threadIdx.x; i < CHUNK; i += 256) {
        int e = base + i;
        int d = dst[e];
        int pos = atomicAdd(&cur[d >> 7], 1);
        uint2 r;
        r.x = (unsigned int)src[e] | ((unsigned int)(d & 127) << 17);
        r.y = f2u(ew[e]);
        esort[pos] = r;
    }
}

// B1: per-bucket fine count (rank byte) + deg accumulate -> rowptr, dinv, urank
__global__ __launch_bounds__(256) void sortB1_kernel(const int* __restrict__ bucketbase,
                                                     const uint2* __restrict__ esort,
                                                     unsigned char* __restrict__ urank,
                                                     int* __restrict__ rowptr,
                                                     float* __restrict__ dinv)
{
    __shared__ int cnt[128];
    __shared__ float dg[128];
    __shared__ int ptr[128];
    int bin = blockIdx.x, t = threadIdx.x;
    if (t < 128) { cnt[t] = 0; dg[t] = 0.f; }
    __syncthreads();
    int base = bucketbase[bin], end = bucketbase[bin+1];
    for (int i = base + t; i < end; i += 256) {
        uint2 r = esort[i];
        int dl = (r.x >> 17) & 127;
        int rk = atomicAdd(&cnt[dl], 1);
        atomicAdd(&dg[dl], u2f(r.y));
        urank[i] = (unsigned char)rk;
    }
    __syncthreads();
    if (t < 128) ptr[t] = cnt[t];
    __syncthreads();
    for (int off = 1; off < 128; off <<= 1) {
        int y = (t >= off && t < 128) ? ptr[t-off] : 0;
        __syncthreads();
        if (t < 128) ptr[t] += y;
        __syncthreads();
    }
    if (t < 128) {
        rowptr[bin*128 + t] = base + ptr[t] - cnt[t];
        dinv[bin*128 + t]   = rsqrtf(dg[t] + 1.0f);
    }
}

// B2: final placement: epack[rowptr[d]+rank] = (src<<15)|fp15(ew*dinv[src])
__global__ __launch_bounds__(256) void sortB2_kernel(const int* __restrict__ bucketbase,
                                                     const uint2* __restrict__ esort,
                                                     const unsigned char* __restrict__ urank,
                                                     const int* __restrict__ rowptr,
                                                     const float* __restrict__ dinv,
                                                     unsigned int* __restrict__ epack)
{
    int bin = blockIdx.x;
    int base = bucketbase[bin], end = bucketbase[bin+1];
    for (int i = base + threadIdx.x; i < end; i += 256) {
        uint2 r = esort[i];
        int s = r.x & 0x1FFFF;
        int d = bin*128 + ((r.x >> 17) & 127);
        float w = u2f(r.y) * dinv[s];
        unsigned int p15 = (f2u(w) + (1u << 16)) >> 17;
        epack[rowptr[d] + (int)urank[i]] = ((unsigned int)s << 15) | p15;
    }
}

// X f32 [NT,8] -> Xb bf16 (packed dwords, 4 per row)
__global__ __launch_bounds__(256) void xconv_kernel(const float* __restrict__ X,
                                                    unsigned int* __restrict__ Xb)
{
    int gid = blockIdx.x*256 + threadIdx.x;
    if (gid >= NT*4) return;
    float2 v = *(const float2*)&X[(size_t)gid*2];
    Xb[gid] = pk2(v.x, v.y);
}

// thread-per-dst 8-channel aggregation; dinv[d] folded at the end
__global__ __launch_bounds__(256) void gather8_kernel(const int* __restrict__ rowptr,
                                                      const unsigned int* __restrict__ epack,
                                                      const uint4* __restrict__ Xb,
                                                      const float* __restrict__ dinv,
                                                      float* __restrict__ agg8)
{
    int d = blockIdx.x*256 + threadIdx.x;
    if (d >= NT) return;
    int beg = rowptr[d], end = rowptr[d+1];
    float acc[8];
    #pragma unroll
    for (int k = 0; k < 8; ++k) acc[k] = 0.f;
    for (int i = beg; i < end; ++i) {
        unsigned int p = epack[i];
        float nrm = dec15(p);
        uint4 xv = Xb[p >> 15];
        unsigned int um[4] = {xv.x, xv.y, xv.z, xv.w};
        #pragma unroll
        for (int m = 0; m < 4; ++m) {
            acc[2*m]   = fmaf(nrm, u2f(um[m] << 16),         acc[2*m]);
            acc[2*m+1] = fmaf(nrm, u2f(um[m] & 0xffff0000u), acc[2*m+1]);
        }
    }
    float dv = dinv[d];
    uint4 xd = Xb[d];
    unsigned int ud[4] = {xd.x, xd.y, xd.z, xd.w};
    #pragma unroll
    for (int m = 0; m < 4; ++m) {
        acc[2*m]   = dv * fmaf(dv, u2f(ud[m] << 16),         acc[2*m]);
        acc[2*m+1] = dv * fmaf(dv, u2f(ud[m] & 0xffff0000u), acc[2*m+1]);
    }
    float4* o = (float4*)&agg8[(size_t)d*8];
    o[0] = make_float4(acc[0], acc[1], acc[2], acc[3]);
    o[1] = make_float4(acc[4], acc[5], acc[6], acc[7]);
}

// y1 = relu(agg8 @ w1 + b1) -> bf16 (pre-BN); fused BN stats
__global__ __launch_bounds__(256) void gemm8relu_kernel(const float* __restrict__ agg8,
                                                        const float* __restrict__ w,
                                                        const float* __restrict__ b,
                                                        unsigned short* __restrict__ y,
                                                        float* __restrict__ sums)
{
    __shared__ float ws[512];
    for (int i = threadIdx.x; i < 512; i += 256) ws[i] = w[i];
    __syncthreads();
    int c = threadIdx.x & 63, wq = threadIdx.x >> 6;
    float bc = b[c];
    float s = 0.f, q = 0.f;
    for (int r = blockIdx.x*4 + wq; r < NT; r += gridDim.x*4) {
        const float4* ar = (const float4*)&agg8[(size_t)r*8];
        float4 a0 = ar[0], a1 = ar[1];
        float v = bc;
        v = fmaf(a0.x, ws[0*64+c], v); v = fmaf(a0.y, ws[1*64+c], v);
        v = fmaf(a0.z, ws[2*64+c], v); v = fmaf(a0.w, ws[3*64+c], v);
        v = fmaf(a1.x, ws[4*64+c], v); v = fmaf(a1.y, ws[5*64+c], v);
        v = fmaf(a1.z, ws[6*64+c], v); v = fmaf(a1.w, ws[7*64+c], v);
        v = fmaxf(v, 0.f);
        y[(size_t)r*64 + c] = f2bu(v);
        s += v; q += v*v;
    }
    __shared__ float sm[256], sq[256];
    sm[threadIdx.x] = s; sq[threadIdx.x] = q;
    __syncthreads();
    if (threadIdx.x < 64) {
        atomicAdd(&sums[c],      sm[c] + sm[c+64] + sm[c+128] + sm[c+192]);
        atomicAdd(&sums[64 + c], sq[c] + sq[c+64] + sq[c+128] + sq[c+192]);
    }
}

// 64-ch gather with INLINE BatchNorm on y1 reads; writes BN'd x1 into xcat[0:32]
// and the aggregate (bf16) into xcat[32:64]. 4 edges/wave, 4 ch/lane.
__global__ __launch_bounds__(256) void gather64_kernel(const int* __restrict__ rowptr,
                                                       const unsigned int* __restrict__ epack,
                                                       const unsigned int* __restrict__ y1,
                                                       const float* __restrict__ dinv,
                                                       const float* __restrict__ sums,
                                                       const float* __restrict__ g,
                                                       const float* __restrict__ be,
                                                       unsigned int* __restrict__ xcat)
{
    int lane = threadIdx.x & 63;
    int grp = lane >> 4, l = lane & 15;       // edge slot, channel quad
    int gwave = blockIdx.x*4 + (threadIdx.x >> 6);
    int nwaves = gridDim.x*4;
    float ax[4], bx[4];
    #pragma unroll
    for (int j = 0; j < 4; ++j) {
        int c = 4*l + j;
        float mu  = sums[c] * (1.0f/NT);
        float var = sums[64 + c] * (1.0f/NT) - mu*mu;
        float a = rsqrtf(var + BNEPS) * g[c];
        ax[j] = a; bx[j] = be[c] - mu*a;
    }
    for (int d = gwave; d < NT; d += nwaves) {
        int beg = rowptr[d], end = rowptr[d+1];
        float a0 = 0.f, a1 = 0.f, a2 = 0.f, a3 = 0.f;
        for (int i = beg; i < end; i += 4) {
            int idx = i + grp;
            bool valid = idx < end;
            unsigned int p = epack[valid ? idx : (end - 1)];
            float nrm = valid ? dec15(p) : 0.f;
            uint2 xv = *(const uint2*)&y1[(size_t)(p >> 15)*32 + 2*l];
            a0 = fmaf(nrm, fmaf(ax[0], u2f(xv.x << 16),         bx[0]), a0);
            a1 = fmaf(nrm, fmaf(ax[1], u2f(xv.x & 0xffff0000u), bx[1]), a1);
            a2 = fmaf(nrm, fmaf(ax[2], u2f(xv.y << 16),         bx[2]), a2);
            a3 = fmaf(nrm, fmaf(ax[3], u2f(xv.y & 0xffff0000u), bx[3]), a3);
        }
        a0 += __shfl_xor(a0, 16); a1 += __shfl_xor(a1, 16);
        a2 += __shfl_xor(a2, 16); a3 += __shfl_xor(a3, 16);
        a0 += __shfl_xor(a0, 32); a1 += __shfl_xor(a1, 32);
        a2 += __shfl_xor(a2, 32); a3 += __shfl_xor(a3, 32);
        if (grp == 0) {
            float dv = dinv[d];
            uint2 xd = *(const uint2*)&y1[(size_t)d*32 + 2*l];
            float x0 = fmaf(ax[0], u2f(xd.x << 16),         bx[0]);
            float x1 = fmaf(ax[1], u2f(xd.x & 0xffff0000u), bx[1]);
            float x2 = fmaf(ax[2], u2f(xd.y << 16),         bx[2]);
            float x3 = fmaf(ax[3], u2f(xd.y & 0xffff0000u), bx[3]);
            *(uint2*)&xcat[(size_t)d*64 + 2*l] = make_uint2(pk2(x0, x1), pk2(x2, x3));
            a0 = dv * fmaf(dv, x0, a0);
            a1 = dv * fmaf(dv, x1, a1);
            a2 = dv * fmaf(dv, x2, a2);
            a3 = dv * fmaf(dv, x3, a3);
            *(uint2*)&xcat[(size_t)d*64 + 32 + 2*l] = make_uint2(pk2(a0, a1), pk2(a2, a3));
        }
    }
}

// y2 = relu(agg2(bf16, xcat cols 32:64) @ w2 + b2) -> bf16 (pre-BN); BN stats
__global__ __launch_bounds__(256) void gemm64relu_kernel(const unsigned int* __restrict__ xcat,
                                                         const float* __restrict__ w,
                                                         const float* __restrict__ b,
                                                         unsigned short* __restrict__ y,
                                                         float* __restrict__ sums)
{
    __shared__ float ws[4096];
    for (int i = threadIdx.x; i < 4096; i += 256) ws[i] = w[i];
    __syncthreads();
    int c = threadIdx.x & 63, wq = threadIdx.x >> 6;
    float bc = b[c];
    float s = 0.f, q = 0.f;
    for (int r = blockIdx.x*4 + wq; r < NT; r += gridDim.x*4) {
        const uint4* xr = (const uint4*)&xcat[(size_t)r*64 + 32];
        float v = bc;
        #pragma unroll
        for (int kk = 0; kk < 8; ++kk) {
            uint4 xv = xr[kk];
            unsigned int um[4] = {xv.x, xv.y, xv.z, xv.w};
            #pragma unroll
            for (int m = 0; m < 4; ++m) {
                int k0 = kk*8 + m*2;
                v = fmaf(u2f(um[m] << 16),         ws[k0*64 + c],     v);
                v = fmaf(u2f(um[m] & 0xffff0000u), ws[(k0+1)*64 + c], v);
            }
        }
        v = fmaxf(v, 0.f);
        y[(size_t)r*64 + c] = f2bu(v);
        s += v; q += v*v;
    }
    __shared__ float sm[256], sq[256];
    sm[threadIdx.x] = s; sq[threadIdx.x] = q;
    __syncthreads();
    if (threadIdx.x < 64) {
        atomicAdd(&sums[c],      sm[c] + sm[c+64] + sm[c+128] + sm[c+192]);
        atomicAdd(&sums[64 + c], sq[c] + sq[c+64] + sq[c+128] + sq[c+192]);
    }
}

// ---------------- fused 2-layer 8-step LSTM on MFMA (3 barriers/step) --------
// x2's BatchNorm applied inline during LDS staging (from pre-BN y2).
// LDS row: 0:128 x(t) | 128:192 h1 | 192:256 h2 buf0 | 256:320 h2 buf1
#define LROW 328
__global__ __launch_bounds__(256, 2) void lstm_mfma_kernel(
    const unsigned int* __restrict__ xcat,
    const unsigned int* __restrict__ y2,
    const float* __restrict__ sums2, const float* __restrict__ g2,
    const float* __restrict__ be2,
    const unsigned int* __restrict__ W1f, const unsigned int* __restrict__ W2f,
    const float* __restrict__ bs1, const float* __restrict__ bs2,
    float* __restrict__ out)
{
    __shared__ __align__(16) unsigned short xb[16][LROW];
    const int tid  = threadIdx.x;
    const int w    = tid >> 6, lane = tid & 63;
    const int lr   = lane & 15;
    const int lg   = lane >> 4;
    const int nb0  = blockIdx.x * 16;

    uint4 w1f[4][6], w2f[4][4];
    {
        const uint4* p1 = (const uint4*)W1f;
        #pragma unroll
        for (int nt = 0; nt < 4; ++nt)
            #pragma unroll
            for (int ks = 0; ks < 6; ++ks)
                w1f[nt][ks] = p1[((w*4 + nt)*6 + ks)*64 + lane];
        const uint4* p2 = (const uint4*)W2f;
        #pragma unroll
        for (int nt = 0; nt < 4; ++nt)
            #pragma unroll
            for (int ks = 0; ks < 4; ++ks)
                w2f[nt][ks] = p2[((w*4 + nt)*4 + ks)*64 + lane];
    }
    float b1v[4], b2v[4];
    #pragma unroll
    for (int nt = 0; nt < 4; ++nt) {
        b1v[nt] = bs1[nt*64 + w*16 + lr];
        b2v[nt] = bs2[nt*64 + w*16 + lr];
    }

    const int sn = tid >> 4, k0 = (tid & 15)*8;
    float ax[8], bx[8];
    if (k0 >= 64) {
        #pragma unroll
        for (int j = 0; j < 8; ++j) {
            int c = k0 - 64 + j;
            float mu  = sums2[c] * (1.0f/NT);
            float var = sums2[64 + c] * (1.0f/NT) - mu*mu;
            float a = rsqrtf(var + BNEPS) * g2[c];
            ax[j] = a; bx[j] = be2[c] - mu*a;
        }
    }

    for (int i = tid; i < 16*24; i += 256) {
        int n = i / 24, kk = 128 + (i % 24)*8;
        uint4 z; z.x = z.y = z.z = z.w = 0u;
        *(uint4*)&xb[n][kk] = z;
    }

    auto stage = [&](int step) {
        size_t row = (size_t)(step*NNODES + nb0 + sn);
        uint4 raw;
        if (k0 < 64) {
            raw = *(const uint4*)&xcat[row*64 + (k0 >> 1)];
        } else {
            raw = *(const uint4*)&y2[row*32 + ((k0 - 64) >> 1)];
            unsigned int um[4] = {raw.x, raw.y, raw.z, raw.w};
            #pragma unroll
            for (int m = 0; m < 4; ++m) {
                float v0 = fmaf(ax[2*m],   u2f(um[m] << 16),         bx[2*m]);
                float v1 = fmaf(ax[2*m+1], u2f(um[m] & 0xffff0000u), bx[2*m+1]);
                um[m] = pk2(v0, v1);
            }
            raw.x = um[0]; raw.y = um[1]; raw.z = um[2]; raw.w = um[3];
        }
        *(uint4*)&xb[sn][k0] = raw;
    };
    stage(0);
    float c1[4] = {0.f,0.f,0.f,0.f}, c2[4] = {0.f,0.f,0.f,0.f};

    for (int step = 0; step < 8; ++step) {
        __syncthreads();                    // B_a: x(t)/h1(t-1)/h2(t-1) visible

        f32x4 acc[4];
        #pragma unroll
        for (int nt = 0; nt < 4; ++nt) { acc[nt][0]=0.f; acc[nt][1]=0.f; acc[nt][2]=0.f; acc[nt][3]=0.f; }
        #pragma unroll
        for (int ks = 0; ks < 6; ++ks) {
            bf16x8 a = *(const bf16x8*)&xb[lr][ks*32 + lg*8];
            #pragma unroll
            for (int nt = 0; nt < 4; ++nt) {
                union { uint4 u; bf16x8 v; } wb; wb.u = w1f[nt][ks];
                acc[nt] = __builtin_amdgcn_mfma_f32_16x16x32_bf16(a, wb.v, acc[nt], 0, 0, 0);
            }
        }
        __syncthreads();                    // B_b: L1 reads done (x + h1 WAR safe)

        #pragma unroll
        for (int r = 0; r < 4; ++r) {
            float zi = acc[0][r] + b1v[0];
            float zf = acc[1][r] + b1v[1];
            float zg = acc[2][r] + b1v[2];
            float zo = acc[3][r] + b1v[3];
            float c  = fsig(zf)*c1[r] + fsig(zi)*ftanh(zg);
            c1[r] = c;
            float hv = fsig(zo)*ftanh(c);
            int node = lg*4 + r;
            xb[node][128 + w*16 + lr] = f2bu(hv);
            if (step == 7) out[(size_t)(nb0 + node)*143 + w*16 + lr] = hv;
        }
        if (step < 7) stage(step + 1);
        __syncthreads();                    // B_c: h1(t) visible for L2

        int rb = 192 + 64*((step+1)&1);
        int wb2 = 192 + 64*(step&1);
        #pragma unroll
        for (int nt = 0; nt < 4; ++nt) { acc[nt][0]=0.f; acc[nt][1]=0.f; acc[nt][2]=0.f; acc[nt][3]=0.f; }
        #pragma unroll
        for (int ks = 0; ks < 2; ++ks) {
            bf16x8 a = *(const bf16x8*)&xb[lr][128 + ks*32 + lg*8];
            #pragma unroll
            for (int nt = 0; nt < 4; ++nt) {
                union { uint4 u; bf16x8 v; } wbv; wbv.u = w2f[nt][ks];
                acc[nt] = __builtin_amdgcn_mfma_f32_16x16x32_bf16(a, wbv.v, acc[nt], 0, 0, 0);
            }
        }
        #pragma unroll
        for (int ks = 0; ks < 2; ++ks) {
            bf16x8 a = *(const bf16x8*)&xb[lr][rb + ks*32 + lg*8];
            #pragma unroll
            for (int nt = 0; nt < 4; ++nt) {
                union { uint4 u; bf16x8 v; } wbv; wbv.u = w2f[nt][2+ks];
                acc[nt] = __builtin_amdgcn_mfma_f32_16x16x32_bf16(a, wbv.v, acc[nt], 0, 0, 0);
            }
        }
        #pragma unroll
        for (int r = 0; r < 4; ++r) {
            float zi = acc[0][r] + b2v[0];
            float zf = acc[1][r] + b2v[1];
            float zg = acc[2][r] + b2v[2];
            float zo = acc[3][r] + b2v[3];
            float c  = fsig(zf)*c2[r] + fsig(zi)*ftanh(zg);
            c2[r] = c;
            float hv = fsig(zo)*ftanh(c);
            int node = lg*4 + r;
            xb[node][wb2 + w*16 + lr] = f2bu(hv);
            if (step == 7) out[(size_t)(nb0 + node)*143 + 64 + w*16 + lr] = hv;
        }
    }
}

__global__ __launch_bounds__(256) void sfeat_kernel(const float* __restrict__ X,
                                                    float* __restrict__ out)
{
    int gid = blockIdx.x*256 + threadIdx.x;
    if (gid >= NNODES*15) return;
    int n = gid/15, i = gid%15;
    float v = (i < 8) ? X[(size_t)n*8 + i]
                      : X[((size_t)(i-7)*NNODES + n)*8 + 7];
    out[(size_t)n*143 + 128 + i] = v;
}

extern "C" void kernel_launch(void* const* d_in, const int* in_sizes, int n_in,
                              void* d_out, int out_size, void* d_ws, size_t ws_size,
                              hipStream_t stream)
{
    (void)in_sizes; (void)n_in; (void)out_size; (void)ws_size;
    const float* X    = (const float*)d_in[0];
    const int*   ei   = (const int*)d_in[1];
    const float* ew   = (const float*)d_in[2];
    const float* w1   = (const float*)d_in[3];
    const float* b1   = (const float*)d_in[4];
    const float* w2   = (const float*)d_in[5];
    const float* b2   = (const float*)d_in[6];
    const float* g1   = (const float*)d_in[7];
    const float* be1  = (const float*)d_in[8];
    const float* g2   = (const float*)d_in[9];
    const float* be2  = (const float*)d_in[10];
    const float* wih1 = (const float*)d_in[11];
    const float* whh1 = (const float*)d_in[12];
    const float* bih1 = (const float*)d_in[13];
    const float* bhh1 = (const float*)d_in[14];
    const float* wih2 = (const float*)d_in[15];
    const float* whh2 = (const float*)d_in[16];
    const float* bih2 = (const float*)d_in[17];
    const float* bhh2 = (const float*)d_in[18];
    float* out = (float*)d_out;
    float* ws  = (float*)d_ws;

    const int* src = ei;
    const int* dst = ei + NE;

    // workspace layout (word offsets)
    float* sums      = ws;                                //  256 [zeroed]
    float* dinv      = ws + 256;                          //  NT
    int*   rowptr    = (int*)(ws + 80256);                //  NT+1 (pad 4)
    int*   binTotal  = (int*)(ws + 160260);               //  625 (pad 640)
    int*   bucketbase= (int*)(ws + 160900);               //  626 (pad 640)
    int*   histmat   = (int*)(ws + 161540);               //  256*640 = 163840
    int*   offmatT   = (int*)(ws + 325380);               //  625*256 = 160000
    unsigned char* urank = (unsigned char*)(ws + 485380); //  NE bytes = 320000 w
    uint2* esort     = (uint2*)(ws + 805384);             //  NE*2 w  (aliased by y2)
    unsigned int* y2 = (unsigned int*)(ws + 805384);      //  NT*32 w (alias: esort dead)
    unsigned int* epack = (unsigned int*)(ws + 3365384);  //  NE w
    unsigned int* Xb = (unsigned int*)(ws + 4645384);     //  NT*4
    float* agg8      = ws + 4965384;                      //  NT*8
    unsigned int* y1 = (unsigned int*)(ws + 5605384);     //  NT*32
    unsigned int* xcat = (unsigned int*)(ws + 8165384);   //  NT*64
    unsigned int* W1f  = (unsigned int*)(ws + 13285384);  //  24576
    unsigned int* W2f  = W1f + 24576;                     //  16384
    float* bs1 = (float*)(W2f + 16384);                   //  256
    float* bs2 = bs1 + 256;                               //  256

    // zero sums only (everything else fully written before read)
    hipMemsetAsync(ws, 0, 256 * 4, stream);

    prep_w_kernel<<<162, 256, 0, stream>>>(wih1,whh1,bih1,bhh1,
                                           wih2,whh2,bih2,bhh2,
                                           W1f,W2f,bs1,bs2);
    // deterministic two-level counting sort (no global atomics)
    sortA1_kernel<<<256, 256, 0, stream>>>(dst, histmat);
    sortA2a_kernel<<<NBKT, 256, 0, stream>>>(histmat, offmatT, binTotal);
    sortA2b_kernel<<<1, 1024, 0, stream>>>(binTotal, bucketbase, rowptr);
    sortA3_kernel<<<256, 256, 0, stream>>>(src, dst, ew, offmatT, bucketbase, esort);
    sortB1_kernel<<<NBKT, 256, 0, stream>>>(bucketbase, esort, urank, rowptr, dinv);
    sortB2_kernel<<<NBKT, 256, 0, stream>>>(bucketbase, esort, urank, rowptr, dinv, epack);
    xconv_kernel<<<(NT*4+255)/256, 256, 0, stream>>>(X, Xb);

    // GCN layer 1
    gather8_kernel<<<(NT+255)/256, 256, 0, stream>>>(rowptr, epack, (const uint4*)Xb, dinv, agg8);
    gemm8relu_kernel<<<1024, 256, 0, stream>>>(agg8, w1, b1, (unsigned short*)y1, sums);

    // GCN layer 2 (BN1 fused into gather64; BN2 fused into LSTM staging)
    gather64_kernel<<<2048, 256, 0, stream>>>(rowptr, epack, y1, dinv, sums, g1, be1, xcat);
    gemm64relu_kernel<<<1024, 256, 0, stream>>>(xcat, w2, b2, (unsigned short*)y2, sums + 128);

    // fused MFMA LSTM + skip features
    lstm_mfma_kernel<<<NNODES/16, 256, 0, stream>>>(xcat, y2, sums + 128, g2, be2,
                                                    W1f, W2f, bs1, bs2, out);
    sfeat_kernel<<<(NNODES*15+255)/256, 256, 0, stream>>>(X, out);
}

// Round 10
// 201.242 us; speedup vs baseline: 4.2090x; 1.2580x over previous
//
#include <hip/hip_runtime.h>
#include <hip/hip_bf16.h>
#include <math.h>

#define NNODES 10000
#define NT     80000
#define NE     1280000
#define NBKT   625       // coarse buckets = NT/128
#define CHUNK  5000      // edges per A-block = NE/256
#define BNEPS  1e-5f

typedef __bf16 bf16x8 __attribute__((ext_vector_type(8)));
typedef float  f32x4  __attribute__((ext_vector_type(4)));

__device__ __forceinline__ float frcp(float x){ return __builtin_amdgcn_rcpf(x); }
__device__ __forceinline__ float fsig(float x){ return frcp(1.0f + __expf(-x)); }
__device__ __forceinline__ float ftanh(float x){ return 1.0f - 2.0f*frcp(1.0f + __expf(2.0f*x)); }
__device__ __forceinline__ float u2f(unsigned int u){ union{unsigned int u; float f;} c; c.u=u; return c.f; }
__device__ __forceinline__ unsigned int f2u(float f){ union{float f; unsigned int u;} c; c.f=f; return c.u; }
__device__ __forceinline__ unsigned short f2bu(float v){ __hip_bfloat16 h = __float2bfloat16(v); return *(unsigned short*)&h; }
__device__ __forceinline__ unsigned int pk2(float a, float b){ return (unsigned int)f2bu(a) | ((unsigned int)f2bu(b) << 16); }
// 15-bit float decode: 8-bit exp, 6-bit mantissa, positive only
__device__ __forceinline__ float dec15(unsigned int p){ return u2f((p & 0x7fffu) << 17); }

// ---------------- weight prep ------------------------------------------------
// W1f/W2f: LSTM weights in MFMA B-fragment order (verified layout).
// W2g: GCN w2 [64x64] B-fragments, 4 col-tiles x 2 k-slabs.
// W1g: GCN w1 [8x64] B-fragments, 4 col-tiles x 1 k-slab (k>=8 zero-padded).
__global__ __launch_bounds__(256) void prep_w_kernel(
    const float* __restrict__ wih1, const float* __restrict__ whh1,
    const float* __restrict__ bih1, const float* __restrict__ bhh1,
    const float* __restrict__ wih2, const float* __restrict__ whh2,
    const float* __restrict__ bih2, const float* __restrict__ bhh2,
    const float* __restrict__ w1g, const float* __restrict__ w2g,
    unsigned int* __restrict__ W1f, unsigned int* __restrict__ W2f,
    float* __restrict__ bs1, float* __restrict__ bs2,
    unsigned int* __restrict__ W2g, unsigned int* __restrict__ W1g)
{
    int gid = blockIdx.x*256 + threadIdx.x;
    if (gid < 24576) {
        int i = gid & 3, lane = (gid>>2)&63, rest = gid>>8;
        int ks = rest % 6; rest /= 6;
        int nt = rest & 3, w = rest >> 2;
        int gate = nt*64 + w*16 + (lane & 15);
        int k = ks*32 + ((lane>>4)&3)*8 + 2*i;
        float v0 = (k     < 128) ? wih1[gate*128 + k]       : whh1[gate*64 + (k-128)];
        float v1 = (k + 1 < 128) ? wih1[gate*128 + k + 1]   : whh1[gate*64 + (k+1-128)];
        W1f[gid] = pk2(v0, v1);
    } else if (gid < 40960) {
        int r = gid - 24576;
        int i = r & 3, lane = (r>>2)&63, rest = r>>8;
        int ks = rest & 3; rest >>= 2;
        int nt = rest & 3, w = rest >> 2;
        int gate = nt*64 + w*16 + (lane & 15);
        int k = ks*32 + ((lane>>4)&3)*8 + 2*i;
        float v0 = (k     < 64) ? wih2[gate*64 + k]     : whh2[gate*64 + (k-64)];
        float v1 = (k + 1 < 64) ? wih2[gate*64 + k + 1] : whh2[gate*64 + (k+1-64)];
        W2f[r] = pk2(v0, v1);
    } else if (gid < 41216) {
        int j = gid - 40960; bs1[j] = bih1[j] + bhh1[j];
    } else if (gid < 41472) {
        int j = gid - 41216; bs2[j] = bih2[j] + bhh2[j];
    } else if (gid < 43520) {
        int r = gid - 41472;
        int i = r & 3, lane = (r>>2)&63, rest = r>>8;
        int ks = rest & 1, w = rest >> 1;
        int col = w*16 + (lane & 15);
        int k = ks*32 + ((lane>>4)&3)*8 + 2*i;
        W2g[r] = pk2(w2g[k*64 + col], w2g[(k+1)*64 + col]);
    } else if (gid < 44544) {
        int r = gid - 43520;
        int i = r & 3, lane = (r>>2)&63, w = r>>8;
        int col = w*16 + (lane & 15);
        int k = ((lane>>4)&3)*8 + 2*i;
        float v0 = (k     < 8) ? w1g[k*64 + col]     : 0.f;
        float v1 = (k + 1 < 8) ? w1g[(k+1)*64 + col] : 0.f;
        W1g[r] = pk2(v0, v1);
    }
}

// ---------- deterministic two-level counting sort (no global atomics) --------
__global__ __launch_bounds__(256) void sortA1_kernel(const int* __restrict__ dst,
                                                     int* __restrict__ histmat)
{
    __shared__ int h[NBKT];
    for (int i = threadIdx.x; i < NBKT; i += 256) h[i] = 0;
    __syncthreads();
    int base = blockIdx.x*CHUNK;
    for (int i = threadIdx.x; i < CHUNK; i += 256)
        atomicAdd(&h[dst[base + i] >> 7], 1);
    __syncthreads();
    for (int i = threadIdx.x; i < NBKT; i += 256)
        histmat[blockIdx.x*640 + i] = h[i];
}

__global__ __launch_bounds__(256) void sortA2a_kernel(const int* __restrict__ histmat,
                                                      int* __restrict__ offmatT,
                                                      int* __restrict__ binTotal)
{
    __shared__ int v[256];
    int b = blockIdx.x, t = threadIdx.x;
    int x = histmat[t*640 + b];
    v[t] = x;
    __syncthreads();
    for (int off = 1; off < 256; off <<= 1) {
        int y = (t >= off) ? v[t-off] : 0;
        __syncthreads();
        v[t] += y;
        __syncthreads();
    }
    offmatT[b*256 + t] = v[t] - x;
    if (t == 255) binTotal[b] = v[255];
}

__global__ __launch_bounds__(1024) void sortA2b_kernel(const int* __restrict__ binTotal,
                                                       int* __restrict__ bucketbase,
                                                       int* __restrict__ rowptr)
{
    __shared__ int part[1024];
    int t = threadIdx.x;
    int v = (t < NBKT) ? binTotal[t] : 0;
    part[t] = v;
    __syncthreads();
    for (int off = 1; off < 1024; off <<= 1) {
        int y = (t >= off) ? part[t-off] : 0;
        __syncthreads();
        part[t] += y;
        __syncthreads();
    }
    if (t < NBKT) bucketbase[t] = part[t] - v;
    if (t == 0) { bucketbase[NBKT] = NE; rowptr[NT] = NE; }
}

__global__ __launch_bounds__(256) void sortA3_kernel(const int* __restrict__ src,
                                                     const int* __restrict__ dst,
                                                     const float* __restrict__ ew,
                                                     const int* __restrict__ offmatT,
                                                     const int* __restrict__ bucketbase,
                                                     uint2* __restrict__ esort)
{
    __shared__ int cur[NBKT];
    int blk = blockIdx.x;
    for (int i = threadIdx.x; i < NBKT; i += 256)
        cur[i] = bucketbase[i] + offmatT[i*256 + blk];
    __syncthreads();
    int base = blk*CHUNK;
    for (int i = threadIdx.x; i < CHUNK; i += 256) {
        int e = base + i;
        int d = dst[e];
        int pos = atomicAdd(&cur[d >> 7], 1);
        uint2 r;
        r.x = (unsigned int)src[e] | ((unsigned int)(d & 127) << 17);
        r.y = f2u(ew[e]);
        esort[pos] = r;
    }
}

__global__ __launch_bounds__(256) void sortB1_kernel(const int* __restrict__ bucketbase,
                                                     const uint2* __restrict__ esort,
                                                     unsigned char* __restrict__ urank,
                                                     int* __restrict__ rowptr,
                                                     float* __restrict__ dinv)
{
    __shared__ int cnt[128];
    __shared__ float dg[128];
    __shared__ int ptr[128];
    int bin = blockIdx.x, t = threadIdx.x;
    if (t < 128) { cnt[t] = 0; dg[t] = 0.f; }
    __syncthreads();
    int base = bucketbase[bin], end = bucketbase[bin+1];
    for (int i = base + t; i < end; i += 256) {
        uint2 r = esort[i];
        int dl = (r.x >> 17) & 127;
        int rk = atomicAdd(&cnt[dl], 1);
        atomicAdd(&dg[dl], u2f(r.y));
        urank[i] = (unsigned char)rk;
    }
    __syncthreads();
    if (t < 128) ptr[t] = cnt[t];
    __syncthreads();
    for (int off = 1; off < 128; off <<= 1) {
        int y = (t >= off && t < 128) ? ptr[t-off] : 0;
        __syncthreads();
        if (t < 128) ptr[t] += y;
        __syncthreads();
    }
    if (t < 128) {
        rowptr[bin*128 + t] = base + ptr[t] - cnt[t];
        dinv[bin*128 + t]   = rsqrtf(dg[t] + 1.0f);
    }
}

__global__ __launch_bounds__(256) void sortB2_kernel(const int* __restrict__ bucketbase,
                                                     const uint2* __restrict__ esort,
                                                     const unsigned char* __restrict__ urank,
                                                     const int* __restrict__ rowptr,
                                                     const float* __restrict__ dinv,
                                                     unsigned int* __restrict__ epack)
{
    int bin = blockIdx.x;
    int base = bucketbase[bin], end = bucketbase[bin+1];
    for (int i = base + threadIdx.x; i < end; i += 256) {
        uint2 r = esort[i];
        int s = r.x & 0x1FFFF;
        int d = bin*128 + ((r.x >> 17) & 127);
        float w = u2f(r.y) * dinv[s];
        unsigned int p15 = (f2u(w) + (1u << 16)) >> 17;
        epack[rowptr[d] + (int)urank[i]] = ((unsigned int)s << 15) | p15;
    }
}

// X f32 [NT,8] -> Xb bf16 (packed dwords, 4 per row)
__global__ __launch_bounds__(256) void xconv_kernel(const float* __restrict__ X,
                                                    unsigned int* __restrict__ Xb)
{
    int gid = blockIdx.x*256 + threadIdx.x;
    if (gid >= NT*4) return;
    float2 v = *(const float2*)&X[(size_t)gid*2];
    Xb[gid] = pk2(v.x, v.y);
}

// thread-per-dst 8-channel aggregation; dinv[d] folded; OUTPUT bf16 (uint4/row)
__global__ __launch_bounds__(256) void gather8_kernel(const int* __restrict__ rowptr,
                                                      const unsigned int* __restrict__ epack,
                                                      const uint4* __restrict__ Xb,
                                                      const float* __restrict__ dinv,
                                                      uint4* __restrict__ agg8b)
{
    int d = blockIdx.x*256 + threadIdx.x;
    if (d >= NT) return;
    int beg = rowptr[d], end = rowptr[d+1];
    float acc[8];
    #pragma unroll
    for (int k = 0; k < 8; ++k) acc[k] = 0.f;
    for (int i = beg; i < end; ++i) {
        unsigned int p = epack[i];
        float nrm = dec15(p);
        uint4 xv = Xb[p >> 15];
        unsigned int um[4] = {xv.x, xv.y, xv.z, xv.w};
        #pragma unroll
        for (int m = 0; m < 4; ++m) {
            acc[2*m]   = fmaf(nrm, u2f(um[m] << 16),         acc[2*m]);
            acc[2*m+1] = fmaf(nrm, u2f(um[m] & 0xffff0000u), acc[2*m+1]);
        }
    }
    float dv = dinv[d];
    uint4 xd = Xb[d];
    unsigned int ud[4] = {xd.x, xd.y, xd.z, xd.w};
    #pragma unroll
    for (int m = 0; m < 4; ++m) {
        acc[2*m]   = dv * fmaf(dv, u2f(ud[m] << 16),         acc[2*m]);
        acc[2*m+1] = dv * fmaf(dv, u2f(ud[m] & 0xffff0000u), acc[2*m+1]);
    }
    agg8b[d] = make_uint4(pk2(acc[0],acc[1]), pk2(acc[2],acc[3]),
                          pk2(acc[4],acc[5]), pk2(acc[6],acc[7]));
}

// y1 = relu(agg8b @ w1 + b1) via MFMA -> bf16 (pre-BN); fused BN stats.
// 64-row tiles; A staged in LDS; B = W1g fragments (K=32, k>=8 zero).
__global__ __launch_bounds__(256) void gemm8relu_kernel(const uint4* __restrict__ agg8b,
                                                        const unsigned int* __restrict__ W1g,
                                                        const float* __restrict__ b,
                                                        unsigned short* __restrict__ y,
                                                        float* __restrict__ sums)
{
    __shared__ __align__(16) unsigned short As[64][8];
    __shared__ float sm[256], sq[256];
    const int tid = threadIdx.x;
    const int w = tid >> 6, lane = tid & 63, lr = lane & 15, lg = lane >> 4;
    union { uint4 u; bf16x8 v; } bw; bw.u = ((const uint4*)W1g)[w*64 + lane];
    float bc = b[w*16 + lr];
    float s = 0.f, q = 0.f;
    for (int tile = blockIdx.x; tile < NT/64; tile += gridDim.x) {
        int rbase = tile*64;
        __syncthreads();
        if (tid < 64) *(uint4*)&As[tid][0] = agg8b[rbase + tid];
        __syncthreads();
        #pragma unroll
        for (int rt = 0; rt < 4; ++rt) {
            bf16x8 a = {};
            if (lg == 0) a = *(const bf16x8*)&As[rt*16 + lr][0];
            f32x4 acc = {0.f, 0.f, 0.f, 0.f};
            acc = __builtin_amdgcn_mfma_f32_16x16x32_bf16(a, bw.v, acc, 0, 0, 0);
            #pragma unroll
            for (int r = 0; r < 4; ++r) {
                float v = fmaxf(acc[r] + bc, 0.f);
                y[(size_t)(rbase + rt*16 + lg*4 + r)*64 + w*16 + lr] = f2bu(v);
                s += v; q += v*v;
            }
        }
    }
    sm[tid] = s; sq[tid] = q;
    __syncthreads();
    if (tid < 64) {
        int base = (tid >> 4)*64 + (tid & 15);
        atomicAdd(&sums[tid],      sm[base] + sm[base+16] + sm[base+32] + sm[base+48]);
        atomicAdd(&sums[64 + tid], sq[base] + sq[base+16] + sq[base+32] + sq[base+48]);
    }
}

// 64-ch gather with INLINE BatchNorm on y1 reads; writes BN'd x1 into xcat[0:32]
// and the aggregate (bf16) into xcat[32:64]. 4 edges/wave, 4 ch/lane.
__global__ __launch_bounds__(256) void gather64_kernel(const int* __restrict__ rowptr,
                                                       const unsigned int* __restrict__ epack,
                                                       const unsigned int* __restrict__ y1,
                                                       const float* __restrict__ dinv,
                                                       const float* __restrict__ sums,
                                                       const float* __restrict__ g,
                                                       const float* __restrict__ be,
                                                       unsigned int* __restrict__ xcat)
{
    int lane = threadIdx.x & 63;
    int grp = lane >> 4, l = lane & 15;
    int gwave = blockIdx.x*4 + (threadIdx.x >> 6);
    int nwaves = gridDim.x*4;
    float ax[4], bx[4];
    #pragma unroll
    for (int j = 0; j < 4; ++j) {
        int c = 4*l + j;
        float mu  = sums[c] * (1.0f/NT);
        float var = sums[64 + c] * (1.0f/NT) - mu*mu;
        float a = rsqrtf(var + BNEPS) * g[c];
        ax[j] = a; bx[j] = be[c] - mu*a;
    }
    for (int d = gwave; d < NT; d += nwaves) {
        int beg = rowptr[d], end = rowptr[d+1];
        float a0 = 0.f, a1 = 0.f, a2 = 0.f, a3 = 0.f;
        for (int i = beg; i < end; i += 4) {
            int idx = i + grp;
            bool valid = idx < end;
            unsigned int p = epack[valid ? idx : (end - 1)];
            float nrm = valid ? dec15(p) : 0.f;
            uint2 xv = *(const uint2*)&y1[(size_t)(p >> 15)*32 + 2*l];
            a0 = fmaf(nrm, fmaf(ax[0], u2f(xv.x << 16),         bx[0]), a0);
            a1 = fmaf(nrm, fmaf(ax[1], u2f(xv.x & 0xffff0000u), bx[1]), a1);
            a2 = fmaf(nrm, fmaf(ax[2], u2f(xv.y << 16),         bx[2]), a2);
            a3 = fmaf(nrm, fmaf(ax[3], u2f(xv.y & 0xffff0000u), bx[3]), a3);
        }
        a0 += __shfl_xor(a0, 16); a1 += __shfl_xor(a1, 16);
        a2 += __shfl_xor(a2, 16); a3 += __shfl_xor(a3, 16);
        a0 += __shfl_xor(a0, 32); a1 += __shfl_xor(a1, 32);
        a2 += __shfl_xor(a2, 32); a3 += __shfl_xor(a3, 32);
        if (grp == 0) {
            float dv = dinv[d];
            uint2 xd = *(const uint2*)&y1[(size_t)d*32 + 2*l];
            float x0 = fmaf(ax[0], u2f(xd.x << 16),         bx[0]);
            float x1 = fmaf(ax[1], u2f(xd.x & 0xffff0000u), bx[1]);
            float x2 = fmaf(ax[2], u2f(xd.y << 16),         bx[2]);
            float x3 = fmaf(ax[3], u2f(xd.y & 0xffff0000u), bx[3]);
            *(uint2*)&xcat[(size_t)d*64 + 2*l] = make_uint2(pk2(x0, x1), pk2(x2, x3));
            a0 = dv * fmaf(dv, x0, a0);
            a1 = dv * fmaf(dv, x1, a1);
            a2 = dv * fmaf(dv, x2, a2);
            a3 = dv * fmaf(dv, x3, a3);
            *(uint2*)&xcat[(size_t)d*64 + 32 + 2*l] = make_uint2(pk2(a0, a1), pk2(a2, a3));
        }
    }
}

// y2 = relu(agg2 @ w2 + b2) via MFMA -> bf16 (pre-BN); fused BN stats.
// A = xcat cols 32:64 (bf16), 64-row LDS tiles (row stride 72 bf16: 2-way bank).
__global__ __launch_bounds__(256) void gemm64relu_kernel(const unsigned int* __restrict__ xcat,
                                                         const unsigned int* __restrict__ W2g,
                                                         const float* __restrict__ b,
                                                         unsigned short* __restrict__ y,
                                                         float* __restrict__ sums)
{
    __shared__ __align__(16) unsigned short As[64][72];
    __shared__ float sm[256], sq[256];
    const int tid = threadIdx.x;
    const int w = tid >> 6, lane = tid & 63, lr = lane & 15, lg = lane >> 4;
    union { uint4 u; bf16x8 v; } b0, b1;
    b0.u = ((const uint4*)W2g)[(w*2 + 0)*64 + lane];
    b1.u = ((const uint4*)W2g)[(w*2 + 1)*64 + lane];
    float bc = b[w*16 + lr];
    const int srow = tid >> 2, squad = tid & 3;     // staging role
    float s = 0.f, q = 0.f;
    for (int tile = blockIdx.x; tile < NT/64; tile += gridDim.x) {
        int rbase = tile*64;
        __syncthreads();
        {
            const unsigned int* src = &xcat[(size_t)(rbase + srow)*64 + 32 + squad*8];
            unsigned int* dst = (unsigned int*)&As[srow][0] + squad*8;
            *(uint4*)(dst)     = *(const uint4*)(src);
            *(uint4*)(dst + 4) = *(const uint4*)(src + 4);
        }
        __syncthreads();
        #pragma unroll
        for (int rt = 0; rt < 4; ++rt) {
            bf16x8 a0 = *(const bf16x8*)&As[rt*16 + lr][lg*8];
            bf16x8 a1 = *(const bf16x8*)&As[rt*16 + lr][32 + lg*8];
            f32x4 acc = {0.f, 0.f, 0.f, 0.f};
            acc = __builtin_amdgcn_mfma_f32_16x16x32_bf16(a0, b0.v, acc, 0, 0, 0);
            acc = __builtin_amdgcn_mfma_f32_16x16x32_bf16(a1, b1.v, acc, 0, 0, 0);
            #pragma unroll
            for (int r = 0; r < 4; ++r) {
                float v = fmaxf(acc[r] + bc, 0.f);
                y[(size_t)(rbase + rt*16 + lg*4 + r)*64 + w*16 + lr] = f2bu(v);
                s += v; q += v*v;
            }
        }
    }
    sm[tid] = s; sq[tid] = q;
    __syncthreads();
    if (tid < 64) {
        int base = (tid >> 4)*64 + (tid & 15);
        atomicAdd(&sums[tid],      sm[base] + sm[base+16] + sm[base+32] + sm[base+48]);
        atomicAdd(&sums[64 + tid], sq[base] + sq[base+16] + sq[base+32] + sq[base+48]);
    }
}

// ---------------- fused 2-layer 8-step LSTM on MFMA (3 barriers/step) --------
#define LROW 328
__global__ __launch_bounds__(256, 2) void lstm_mfma_kernel(
    const unsigned int* __restrict__ xcat,
    const unsigned int* __restrict__ y2,
    const float* __restrict__ sums2, const float* __restrict__ g2,
    const float* __restrict__ be2,
    const unsigned int* __restrict__ W1f, const unsigned int* __restrict__ W2f,
    const float* __restrict__ bs1, const float* __restrict__ bs2,
    float* __restrict__ out)
{
    __shared__ __align__(16) unsigned short xb[16][LROW];
    const int tid  = threadIdx.x;
    const int w    = tid >> 6, lane = tid & 63;
    const int lr   = lane & 15;
    const int lg   = lane >> 4;
    const int nb0  = blockIdx.x * 16;

    uint4 w1f[4][6], w2f[4][4];
    {
        const uint4* p1 = (const uint4*)W1f;
        #pragma unroll
        for (int nt = 0; nt < 4; ++nt)
            #pragma unroll
            for (int ks = 0; ks < 6; ++ks)
                w1f[nt][ks] = p1[((w*4 + nt)*6 + ks)*64 + lane];
        const uint4* p2 = (const uint4*)W2f;
        #pragma unroll
        for (int nt = 0; nt < 4; ++nt)
            #pragma unroll
            for (int ks = 0; ks < 4; ++ks)
                w2f[nt][ks] = p2[((w*4 + nt)*4 + ks)*64 + lane];
    }
    float b1v[4], b2v[4];
    #pragma unroll
    for (int nt = 0; nt < 4; ++nt) {
        b1v[nt] = bs1[nt*64 + w*16 + lr];
        b2v[nt] = bs2[nt*64 + w*16 + lr];
    }

    const int sn = tid >> 4, k0 = (tid & 15)*8;
    float ax[8], bx[8];
    if (k0 >= 64) {
        #pragma unroll
        for (int j = 0; j < 8; ++j) {
            int c = k0 - 64 + j;
            float mu  = sums2[c] * (1.0f/NT);
            float var = sums2[64 + c] * (1.0f/NT) - mu*mu;
            float a = rsqrtf(var + BNEPS) * g2[c];
            ax[j] = a; bx[j] = be2[c] - mu*a;
        }
    }

    for (int i = tid; i < 16*24; i += 256) {
        int n = i / 24, kk = 128 + (i % 24)*8;
        uint4 z; z.x = z.y = z.z = z.w = 0u;
        *(uint4*)&xb[n][kk] = z;
    }

    auto stage = [&](int step) {
        size_t row = (size_t)(step*NNODES + nb0 + sn);
        uint4 raw;
        if (k0 < 64) {
            raw = *(const uint4*)&xcat[row*64 + (k0 >> 1)];
        } else {
            raw = *(const uint4*)&y2[row*32 + ((k0 - 64) >> 1)];
            unsigned int um[4] = {raw.x, raw.y, raw.z, raw.w};
            #pragma unroll
            for (int m = 0; m < 4; ++m) {
                float v0 = fmaf(ax[2*m],   u2f(um[m] << 16),         bx[2*m]);
                float v1 = fmaf(ax[2*m+1], u2f(um[m] & 0xffff0000u), bx[2*m+1]);
                um[m] = pk2(v0, v1);
            }
            raw.x = um[0]; raw.y = um[1]; raw.z = um[2]; raw.w = um[3];
        }
        *(uint4*)&xb[sn][k0] = raw;
    };
    stage(0);
    float c1[4] = {0.f,0.f,0.f,0.f}, c2[4] = {0.f,0.f,0.f,0.f};

    for (int step = 0; step < 8; ++step) {
        __syncthreads();                    // B_a

        f32x4 acc[4];
        #pragma unroll
        for (int nt = 0; nt < 4; ++nt) { acc[nt][0]=0.f; acc[nt][1]=0.f; acc[nt][2]=0.f; acc[nt][3]=0.f; }
        #pragma unroll
        for (int ks = 0; ks < 6; ++ks) {
            bf16x8 a = *(const bf16x8*)&xb[lr][ks*32 + lg*8];
            #pragma unroll
            for (int nt = 0; nt < 4; ++nt) {
                union { uint4 u; bf16x8 v; } wb; wb.u = w1f[nt][ks];
                acc[nt] = __builtin_amdgcn_mfma_f32_16x16x32_bf16(a, wb.v, acc[nt], 0, 0, 0);
            }
        }
        __syncthreads();                    // B_b

        #pragma unroll
        for (int r = 0; r < 4; ++r) {
            float zi = acc[0][r] + b1v[0];
            float zf = acc[1][r] + b1v[1];
            float zg = acc[2][r] + b1v[2];
            float zo = acc[3][r] + b1v[3];
            float c  = fsig(zf)*c1[r] + fsig(zi)*ftanh(zg);
            c1[r] = c;
            float hv = fsig(zo)*ftanh(c);
            int node = lg*4 + r;
            xb[node][128 + w*16 + lr] = f2bu(hv);
            if (step == 7) out[(size_t)(nb0 + node)*143 + w*16 + lr] = hv;
        }
        if (step < 7) stage(step + 1);
        __syncthreads();                    // B_c

        int rb = 192 + 64*((step+1)&1);
        int wb2 = 192 + 64*(step&1);
        #pragma unroll
        for (int nt = 0; nt < 4; ++nt) { acc[nt][0]=0.f; acc[nt][1]=0.f; acc[nt][2]=0.f; acc[nt][3]=0.f; }
        #pragma unroll
        for (int ks = 0; ks < 2; ++ks) {
            bf16x8 a = *(const bf16x8*)&xb[lr][128 + ks*32 + lg*8];
            #pragma unroll
            for (int nt = 0; nt < 4; ++nt) {
                union { uint4 u; bf16x8 v; } wbv; wbv.u = w2f[nt][ks];
                acc[nt] = __builtin_amdgcn_mfma_f32_16x16x32_bf16(a, wbv.v, acc[nt], 0, 0, 0);
            }
        }
        #pragma unroll
        for (int ks = 0; ks < 2; ++ks) {
            bf16x8 a = *(const bf16x8*)&xb[lr][rb + ks*32 + lg*8];
            #pragma unroll
            for (int nt = 0; nt < 4; ++nt) {
                union { uint4 u; bf16x8 v; } wbv; wbv.u = w2f[nt][2+ks];
                acc[nt] = __builtin_amdgcn_mfma_f32_16x16x32_bf16(a, wbv.v, acc[nt], 0, 0, 0);
            }
        }
        #pragma unroll
        for (int r = 0; r < 4; ++r) {
            float zi = acc[0][r] + b2v[0];
            float zf = acc[1][r] + b2v[1];
            float zg = acc[2][r] + b2v[2];
            float zo = acc[3][r] + b2v[3];
            float c  = fsig(zf)*c2[r] + fsig(zi)*ftanh(zg);
            c2[r] = c;
            float hv = fsig(zo)*ftanh(c);
            int node = lg*4 + r;
            xb[node][wb2 + w*16 + lr] = f2bu(hv);
            if (step == 7) out[(size_t)(nb0 + node)*143 + 64 + w*16 + lr] = hv;
        }
    }
}

__global__ __launch_bounds__(256) void sfeat_kernel(const float* __restrict__ X,
                                                    float* __restrict__ out)
{
    int gid = blockIdx.x*256 + threadIdx.x;
    if (gid >= NNODES*15) return;
    int n = gid/15, i = gid%15;
    float v = (i < 8) ? X[(size_t)n*8 + i]
                      : X[((size_t)(i-7)*NNODES + n)*8 + 7];
    out[(size_t)n*143 + 128 + i] = v;
}

extern "C" void kernel_launch(void* const* d_in, const int* in_sizes, int n_in,
                              void* d_out, int out_size, void* d_ws, size_t ws_size,
                              hipStream_t stream)
{
    (void)in_sizes; (void)n_in; (void)out_size; (void)ws_size;
    const float* X    = (const float*)d_in[0];
    const int*   ei   = (const int*)d_in[1];
    const float* ew   = (const float*)d_in[2];
    const float* w1   = (const float*)d_in[3];
    const float* b1   = (const float*)d_in[4];
    const float* w2   = (const float*)d_in[5];
    const float* b2   = (const float*)d_in[6];
    const float* g1   = (const float*)d_in[7];
    const float* be1  = (const float*)d_in[8];
    const float* g2   = (const float*)d_in[9];
    const float* be2  = (const float*)d_in[10];
    const float* wih1 = (const float*)d_in[11];
    const float* whh1 = (const float*)d_in[12];
    const float* bih1 = (const float*)d_in[13];
    const float* bhh1 = (const float*)d_in[14];
    const float* wih2 = (const float*)d_in[15];
    const float* whh2 = (const float*)d_in[16];
    const float* bih2 = (const float*)d_in[17];
    const float* bhh2 = (const float*)d_in[18];
    float* out = (float*)d_out;
    float* ws  = (float*)d_ws;

    const int* src = ei;
    const int* dst = ei + NE;

    // workspace layout (word offsets)
    float* sums      = ws;                                //  256 [zeroed]
    float* dinv      = ws + 256;                          //  NT
    int*   rowptr    = (int*)(ws + 80256);                //  NT+1 (pad 4)
    int*   binTotal  = (int*)(ws + 160260);               //  625 (pad 640)
    int*   bucketbase= (int*)(ws + 160900);               //  626 (pad 640)
    int*   histmat   = (int*)(ws + 161540);               //  256*640
    int*   offmatT   = (int*)(ws + 325380);               //  625*256
    unsigned char* urank = (unsigned char*)(ws + 485380); //  NE bytes
    uint2* esort     = (uint2*)(ws + 805384);             //  NE*2 w (aliased by y2)
    unsigned int* y2 = (unsigned int*)(ws + 805384);      //  NT*32 w (alias)
    unsigned int* epack = (unsigned int*)(ws + 3365384);  //  NE w
    unsigned int* Xb = (unsigned int*)(ws + 4645384);     //  NT*4
    uint4* agg8b     = (uint4*)(ws + 4965384);            //  NT*4 w (bf16 rows)
    unsigned int* y1 = (unsigned int*)(ws + 5605384);     //  NT*32
    unsigned int* xcat = (unsigned int*)(ws + 8165384);   //  NT*64
    unsigned int* W1f  = (unsigned int*)(ws + 13285384);  //  24576
    unsigned int* W2f  = W1f + 24576;                     //  16384
    float* bs1 = (float*)(W2f + 16384);                   //  256
    float* bs2 = bs1 + 256;                               //  256
    unsigned int* W2g  = (unsigned int*)(bs2 + 256);      //  2048
    unsigned int* W1g  = W2g + 2048;                      //  1024

    hipMemsetAsync(ws, 0, 256 * 4, stream);

    prep_w_kernel<<<174, 256, 0, stream>>>(wih1,whh1,bih1,bhh1,
                                           wih2,whh2,bih2,bhh2,
                                           w1, w2,
                                           W1f,W2f,bs1,bs2,W2g,W1g);
    // deterministic two-level counting sort (no global atomics)
    sortA1_kernel<<<256, 256, 0, stream>>>(dst, histmat);
    sortA2a_kernel<<<NBKT, 256, 0, stream>>>(histmat, offmatT, binTotal);
    sortA2b_kernel<<<1, 1024, 0, stream>>>(binTotal, bucketbase, rowptr);
    sortA3_kernel<<<256, 256, 0, stream>>>(src, dst, ew, offmatT, bucketbase, esort);
    sortB1_kernel<<<NBKT, 256, 0, stream>>>(bucketbase, esort, urank, rowptr, dinv);
    sortB2_kernel<<<NBKT, 256, 0, stream>>>(bucketbase, esort, urank, rowptr, dinv, epack);
    xconv_kernel<<<(NT*4+255)/256, 256, 0, stream>>>(X, Xb);

    // GCN layer 1
    gather8_kernel<<<(NT+255)/256, 256, 0, stream>>>(rowptr, epack, (const uint4*)Xb, dinv, agg8b);
    gemm8relu_kernel<<<320, 256, 0, stream>>>(agg8b, W1g, b1, (unsigned short*)y1, sums);

    // GCN layer 2 (BN1 fused into gather64; BN2 fused into LSTM staging)
    gather64_kernel<<<2048, 256, 0, stream>>>(rowptr, epack, y1, dinv, sums, g1, be1, xcat);
    gemm64relu_kernel<<<320, 256, 0, stream>>>(xcat, W2g, b2, (unsigned short*)y2, sums + 128);

    // fused MFMA LSTM + skip features
    lstm_mfma_kernel<<<NNODES/16, 256, 0, stream>>>(xcat, y2, sums + 128, g2, be2,
                                                    W1f, W2f, bs1, bs2, out);
    sfeat_kernel<<<(NNODES*15+255)/256, 256, 0, stream>>>(X, out);
}